// Round 1
// baseline (3497.599 us; speedup 1.0000x reference)
//
#include <hip/hip_runtime.h>
#include <math.h>

#define Bb 2
#define Tt 2048
#define Cc 1024
#define Hh 16
#define BT 4096
#define FFNd 4096
#define CH 16

__device__ __forceinline__ float sgm(float x){ return 1.0f/(1.0f+expf(-x)); }

template<int MAXM>
__device__ __forceinline__ float redgrp(float v){
  #pragma unroll
  for (int m=1; m<=MAXM; m<<=1) v += __shfl_xor(v, m, 64);
  return v;
}

// ---------------- LayerNorm (per row of C=1024), block=256, 4 elems/thread ----
__global__ __launch_bounds__(256) void ln_kernel(const float* __restrict__ x,
    const float* __restrict__ w, const float* __restrict__ b,
    float* __restrict__ out, float eps) {
  int row = blockIdx.x;
  int tid = threadIdx.x;
  size_t off = (size_t)row*Cc + tid*4;
  float4 v = *(const float4*)(x + off);
  float s = v.x+v.y+v.z+v.w;
  float q = v.x*v.x+v.y*v.y+v.z*v.z+v.w*v.w;
  s = redgrp<32>(s); q = redgrp<32>(q);
  __shared__ float rs_[4], rq_[4];
  int lane = tid & 63, wv = tid >> 6;
  if (lane==0){ rs_[wv]=s; rq_[wv]=q; }
  __syncthreads();
  s = rs_[0]+rs_[1]+rs_[2]+rs_[3];
  q = rq_[0]+rq_[1]+rq_[2]+rq_[3];
  float mu = s*(1.0f/Cc);
  float var = q*(1.0f/Cc) - mu*mu;
  float rn = rsqrtf(var + eps);
  float4 w4 = *(const float4*)(w + tid*4);
  float4 b4 = *(const float4*)(b + tid*4);
  float4 o;
  o.x = (v.x-mu)*rn*w4.x + b4.x;
  o.y = (v.y-mu)*rn*w4.y + b4.y;
  o.z = (v.z-mu)*rn*w4.z + b4.z;
  o.w = (v.w-mu)*rn*w4.w + b4.w;
  *(float4*)(out + off) = o;
}

// ---------------- time-shift mix: out = xn + (prev - xn) * mix ---------------
__global__ __launch_bounds__(256) void mix_kernel(const float* __restrict__ xn,
    const float* __restrict__ mix, float* __restrict__ out) {
  int row = blockIdx.x; int t = row & (Tt-1);
  int c = threadIdx.x*4;
  size_t off = (size_t)row*Cc + c;
  float4 v = *(const float4*)(xn + off);
  float4 p = {0.f,0.f,0.f,0.f};
  if (t) p = *(const float4*)(xn + off - Cc);
  float4 m = *(const float4*)(mix + c);
  float4 o;
  o.x = v.x + (p.x - v.x)*m.x;
  o.y = v.y + (p.y - v.y)*m.y;
  o.z = v.z + (p.z - v.z)*m.z;
  o.w = v.w + (p.w - v.w)*m.w;
  *(float4*)(out + off) = o;
}

// ---------------- f32 GEMM: out[M,N] = A[M,K] @ W[N,K]^T  (+ epilogue) -------
// mode 0: plain   1: out = res + acc   2: out = relu(acc)^2
__global__ __launch_bounds__(256) void gemm_bt(const float* __restrict__ A,
    const float* __restrict__ W, float* __restrict__ out,
    const float* __restrict__ res, int M, int N, int K, int mode) {
  __shared__ float As[16][64];
  __shared__ float Ws[16][64];
  int tid = threadIdx.x;
  int bm = blockIdx.y, bn = blockIdx.x;
  int lrow = tid >> 2, lk = (tid & 3) * 4;
  int tx = tid & 15, ty = tid >> 4;
  const float* Ap = A + (size_t)(bm*64 + lrow)*K + lk;
  const float* Wp = W + (size_t)(bn*64 + lrow)*K + lk;
  float acc[4][4] = {};
  for (int kb = 0; kb < K; kb += 16) {
    float4 av = *(const float4*)(Ap + kb);
    float4 wv = *(const float4*)(Wp + kb);
    __syncthreads();
    As[lk+0][lrow]=av.x; As[lk+1][lrow]=av.y; As[lk+2][lrow]=av.z; As[lk+3][lrow]=av.w;
    Ws[lk+0][lrow]=wv.x; Ws[lk+1][lrow]=wv.y; Ws[lk+2][lrow]=wv.z; Ws[lk+3][lrow]=wv.w;
    __syncthreads();
    #pragma unroll
    for (int k2 = 0; k2 < 16; ++k2) {
      float4 a4 = *(const float4*)&As[k2][ty*4];
      float4 b4 = *(const float4*)&Ws[k2][tx*4];
      float a_[4] = {a4.x,a4.y,a4.z,a4.w};
      float b_[4] = {b4.x,b4.y,b4.z,b4.w};
      #pragma unroll
      for (int i=0;i<4;++i)
        #pragma unroll
        for (int j=0;j<4;++j) acc[i][j] = fmaf(a_[i], b_[j], acc[i][j]);
    }
  }
  #pragma unroll
  for (int i=0;i<4;++i) {
    int row = bm*64 + ty*4 + i;
    size_t ooff = (size_t)row*N + bn*64 + tx*4;
    float v0=acc[i][0], v1=acc[i][1], v2=acc[i][2], v3=acc[i][3];
    if (mode == 1) {
      float4 r4 = *(const float4*)(res + ooff);
      v0+=r4.x; v1+=r4.y; v2+=r4.z; v3+=r4.w;
    } else if (mode == 2) {
      v0=fmaxf(v0,0.f); v1=fmaxf(v1,0.f); v2=fmaxf(v2,0.f); v3=fmaxf(v3,0.f);
      v0*=v0; v1*=v1; v2*=v2; v3*=v3;
    }
    float4 o = {v0,v1,v2,v3};
    *(float4*)(out + ooff) = o;
  }
}

// ---------------- LoRA stage1: out[i,d] = act(sum_k A[i,k] W[k,d]) -----------
__global__ __launch_bounds__(256) void lora1_kernel(const float* __restrict__ A,
    const float* __restrict__ W, float* __restrict__ out, int D, int act) {
  int idx = blockIdx.x*256 + threadIdx.x;
  int i = idx / D, d = idx - i*D;
  const float* ap = A + (size_t)i*Cc;
  const float* wp = W + d;
  float acc = 0.f;
  for (int k=0;k<Cc;k+=4){
    float4 a4 = *(const float4*)(ap + k);
    acc = fmaf(a4.x, wp[(size_t)(k+0)*D], acc);
    acc = fmaf(a4.y, wp[(size_t)(k+1)*D], acc);
    acc = fmaf(a4.z, wp[(size_t)(k+2)*D], acc);
    acc = fmaf(a4.w, wp[(size_t)(k+3)*D], acc);
  }
  if (act==1) acc = tanhf(acc);
  else if (act==2) acc = sgm(acc);
  out[idx] = acc;
}

// ---------------- LoRA stage2: out[i,c] = sum_d T[i,d] W2[d,c] ---------------
__global__ __launch_bounds__(256) void lora2_kernel(const float* __restrict__ Tm,
    const float* __restrict__ W2, float* __restrict__ out, int D) {
  int i0 = blockIdx.x*8;
  int c = blockIdx.y*256 + threadIdx.x;
  float acc[8] = {};
  for (int d=0; d<D; ++d) {
    float wv = W2[(size_t)d*Cc + c];
    #pragma unroll
    for (int r=0;r<8;++r) acc[r] = fmaf(Tm[(size_t)(i0+r)*D + d], wv, acc[r]);
  }
  #pragma unroll
  for (int r=0;r<8;++r) out[(size_t)(i0+r)*Cc + c] = acc[r];
}

// ---------------- prep: decay, k_final, v_final, A=-kk, B=kk*a ---------------
__global__ __launch_bounds__(256) void prep_kernel(
    const float* __restrict__ kraw, const float* __restrict__ dw,
    const float* __restrict__ da, const float* __restrict__ dv,
    const float* __restrict__ vraw, const float* __restrict__ vfirst,
    const float* __restrict__ w0, const float* __restrict__ a0,
    const float* __restrict__ v0, const float* __restrict__ k_k,
    const float* __restrict__ k_a,
    float* __restrict__ decay, float* __restrict__ kfin, float* __restrict__ vfin,
    float* __restrict__ Ak, float* __restrict__ Bk) {
  int row = blockIdx.x; int tid = threadIdx.x; int c = tid*4;
  size_t off = (size_t)row*Cc + c;
  float4 kr = *(const float4*)(kraw+off);
  float4 w4 = *(const float4*)(dw+off);
  float4 A4 = *(const float4*)(da+off);
  float4 V4 = *(const float4*)(dv+off);
  float4 vr = *(const float4*)(vraw+off);
  float4 vf = *(const float4*)(vfirst+off);
  float4 w04 = *(const float4*)(w0+c);
  float4 a04 = *(const float4*)(a0+c);
  float4 v04 = *(const float4*)(v0+c);
  float4 kk4 = *(const float4*)(k_k+c);
  float4 ka4 = *(const float4*)(k_a+c);
  float krl[4]={kr.x,kr.y,kr.z,kr.w};
  float dwl[4]={w4.x,w4.y,w4.z,w4.w};
  float dal[4]={A4.x,A4.y,A4.z,A4.w};
  float dvl[4]={V4.x,V4.y,V4.z,V4.w};
  float vrl[4]={vr.x,vr.y,vr.z,vr.w};
  float vfl[4]={vf.x,vf.y,vf.z,vf.w};
  float w0l[4]={w04.x,w04.y,w04.z,w04.w};
  float a0l[4]={a04.x,a04.y,a04.z,a04.w};
  float v0l[4]={v04.x,v04.y,v04.z,v04.w};
  float kkl[4]={kk4.x,kk4.y,kk4.z,kk4.w};
  float kal[4]={ka4.x,ka4.y,ka4.z,ka4.w};
  float av[4], dec[4], vv[4], kp[4], kf[4];
  float ss = 0.f;
  #pragma unroll
  for (int q=0;q<4;++q){
    av[q] = sgm(a0l[q] + dal[q]);
    dec[q] = 0.60653065971263342f * sgm(w0l[q] + dwl[q]);   // exp(-softplus(-u)-0.5)
    float sv = sgm(v0l[q] + dvl[q]);
    vv[q] = vrl[q] + (vfl[q]-vrl[q])*sv;
    kp[q] = krl[q]*kkl[q];
    ss += kp[q]*kp[q];
    kf[q] = krl[q]*(1.0f + (av[q]-1.0f)*kal[q]);
  }
  ss = redgrp<8>(ss);               // per-head (64 elems = 16 lanes) L2 norm^2
  float inv = 1.0f / fmaxf(sqrtf(ss), 1e-12f);
  float4 o;
  o.x=dec[0];o.y=dec[1];o.z=dec[2];o.w=dec[3];  *(float4*)(decay+off)=o;
  o.x=kf[0]; o.y=kf[1]; o.z=kf[2]; o.w=kf[3];   *(float4*)(kfin+off)=o;
  o.x=vv[0]; o.y=vv[1]; o.z=vv[2]; o.w=vv[3];   *(float4*)(vfin+off)=o;
  o.x=-kp[0]*inv; o.y=-kp[1]*inv; o.z=-kp[2]*inv; o.w=-kp[3]*inv; *(float4*)(Ak+off)=o;
  o.x=kp[0]*inv*av[0]; o.y=kp[1]*inv*av[1]; o.z=kp[2]*inv*av[2]; o.w=kp[3]*inv*av[3];
  *(float4*)(Bk+off)=o;
}

// ---------------- WKV-7 scan: 1 block per (b,h), 256 thr, S 4x4/thread -------
__global__ __launch_bounds__(256) void wkv_kernel(
    const float* __restrict__ decay, const float* __restrict__ Ak,
    const float* __restrict__ Bk, const float* __restrict__ kfin,
    const float* __restrict__ r_, const float* __restrict__ vfin,
    const float* __restrict__ S0, float* __restrict__ y) {
  __shared__ float lds[2][6][CH][64];
  int bh = blockIdx.x; int bb = bh >> 4, h = bh & 15;
  int tid = threadIdx.x;
  int bi = tid >> 4, bj = tid & 15;
  int i0 = bi*4, j0 = bj*4;
  float S[4][4];
  const float* s0p = S0 + (size_t)bh*4096;
  #pragma unroll
  for (int ri=0;ri<4;++ri)
    #pragma unroll
    for (int jl=0;jl<4;++jl) S[ri][jl] = s0p[(i0+ri)*64 + j0+jl];
  const float* bases[6] = {decay, Ak, Bk, kfin, r_, vfin};
  size_t rowbase = (size_t)bb*Tt;
  int st = tid >> 4;           // 0..15 = step within chunk for staging
  int e  = (tid & 15) * 4;     // float offset within 64
  float4 regs[6];
  #pragma unroll
  for (int arr=0; arr<6; ++arr)
    regs[arr] = *(const float4*)(bases[arr] + (rowbase + 0 + st)*Cc + h*64 + e);
  #pragma unroll
  for (int arr=0; arr<6; ++arr)
    *(float4*)&lds[0][arr][st][e] = regs[arr];
  __syncthreads();
  const int NC = Tt/CH;
  for (int ch=0; ch<NC; ++ch) {
    int cur = ch & 1;
    if (ch+1 < NC) {
      #pragma unroll
      for (int arr=0; arr<6; ++arr)
        regs[arr] = *(const float4*)(bases[arr] + (rowbase + (ch+1)*CH + st)*Cc + h*64 + e);
    }
    for (int s=0; s<CH; ++s) {
      const float* pd = &lds[cur][0][s][0];     // array stride = CH*64 floats
      float4 d4 = *(const float4*)(pd + 0*CH*64 + j0);
      float4 a4 = *(const float4*)(pd + 1*CH*64 + j0);
      float4 b4 = *(const float4*)(pd + 2*CH*64 + j0);
      float4 k4 = *(const float4*)(pd + 3*CH*64 + j0);
      float4 r4 = *(const float4*)(pd + 4*CH*64 + j0);
      float4 v4 = *(const float4*)(pd + 5*CH*64 + i0);
      float dd[4]={d4.x,d4.y,d4.z,d4.w};
      float aa[4]={a4.x,a4.y,a4.z,a4.w};
      float bv[4]={b4.x,b4.y,b4.z,b4.w};
      float kv[4]={k4.x,k4.y,k4.z,k4.w};
      float rv[4]={r4.x,r4.y,r4.z,r4.w};
      float vl[4]={v4.x,v4.y,v4.z,v4.w};
      float sa[4], yp[4];
      // decay FIRST (matches reference), then sa from decayed state
      #pragma unroll
      for (int ri=0;ri<4;++ri){
        #pragma unroll
        for (int jl=0;jl<4;++jl) S[ri][jl] *= dd[jl];
        sa[ri] = S[ri][0]*aa[0] + S[ri][1]*aa[1] + S[ri][2]*aa[2] + S[ri][3]*aa[3];
      }
      #pragma unroll
      for (int m=1;m<=8;m<<=1){
        #pragma unroll
        for (int ri=0;ri<4;++ri) sa[ri] += __shfl_xor(sa[ri], m, 64);
      }
      #pragma unroll
      for (int ri=0;ri<4;++ri){
        #pragma unroll
        for (int jl=0;jl<4;++jl){
          float t = fmaf(vl[ri], kv[jl], S[ri][jl]);
          S[ri][jl] = fmaf(sa[ri], bv[jl], t);
        }
        yp[ri] = S[ri][0]*rv[0] + S[ri][1]*rv[1] + S[ri][2]*rv[2] + S[ri][3]*rv[3];
      }
      #pragma unroll
      for (int m=1;m<=8;m<<=1){
        #pragma unroll
        for (int ri=0;ri<4;++ri) yp[ri] += __shfl_xor(yp[ri], m, 64);
      }
      if (bj == 0) {
        float4 o = {yp[0],yp[1],yp[2],yp[3]};
        *(float4*)(y + (rowbase + ch*CH + s)*Cc + h*64 + i0) = o;
      }
    }
    if (ch+1 < NC) {
      int nxt = cur ^ 1;
      #pragma unroll
      for (int arr=0; arr<6; ++arr)
        *(float4*)&lds[nxt][arr][st][e] = regs[arr];
    }
    __syncthreads();
  }
}

// ---------------- GroupNorm(head) + r.k.r_k bonus + *g  ->  Ao ----------------
__global__ __launch_bounds__(256) void gn_kernel(
    const float* __restrict__ y, const float* __restrict__ r_,
    const float* __restrict__ kfin, const float* __restrict__ vfin,
    const float* __restrict__ g_, const float* __restrict__ lnxw,
    const float* __restrict__ lnxb, const float* __restrict__ r_k,
    float* __restrict__ Ao) {
  int row = blockIdx.x; int tid = threadIdx.x; int c = tid*4;
  size_t off = (size_t)row*Cc + c;
  float4 y4 = *(const float4*)(y+off);
  float s = y4.x+y4.y+y4.z+y4.w;
  float q = y4.x*y4.x+y4.y*y4.y+y4.z*y4.z+y4.w*y4.w;
  s = redgrp<8>(s); q = redgrp<8>(q);
  float mu = s*(1.0f/64.0f);
  float var = q*(1.0f/64.0f) - mu*mu;
  float rn = rsqrtf(var + 64e-5f);
  float4 rr = *(const float4*)(r_+off);
  float4 kk = *(const float4*)(kfin+off);
  float4 vv = *(const float4*)(vfin+off);
  float4 gg = *(const float4*)(g_+off);
  int h = tid >> 4; int hs = (tid & 15)*4;
  float4 rk = *(const float4*)(r_k + h*64 + hs);
  float dp = rr.x*kk.x*rk.x + rr.y*kk.y*rk.y + rr.z*kk.z*rk.z + rr.w*kk.w*rk.w;
  dp = redgrp<8>(dp);
  float4 w4 = *(const float4*)(lnxw+c);
  float4 b4 = *(const float4*)(lnxb+c);
  float4 o;
  o.x = (((y4.x-mu)*rn)*w4.x + b4.x + dp*vv.x) * gg.x;
  o.y = (((y4.y-mu)*rn)*w4.y + b4.y + dp*vv.y) * gg.y;
  o.z = (((y4.z-mu)*rn)*w4.z + b4.z + dp*vv.z) * gg.z;
  o.w = (((y4.w-mu)*rn)*w4.w + b4.w + dp*vv.w) * gg.w;
  *(float4*)(Ao + off) = o;
}

__global__ __launch_bounds__(256) void copy_kernel(const float* __restrict__ src,
                                                   float* __restrict__ dst) {
  size_t i = ((size_t)blockIdx.x*256 + threadIdx.x)*4;
  *(float4*)(dst+i) = *(const float4*)(src+i);
}

extern "C" void kernel_launch(void* const* d_in, const int* in_sizes, int n_in,
                              void* d_out, int out_size, void* d_ws, size_t ws_size,
                              hipStream_t stream) {
  const float* x      = (const float*)d_in[0];
  const float* vfirst = (const float*)d_in[1];
  const float* S0     = (const float*)d_in[2];
  const float* ln1w   = (const float*)d_in[3];
  const float* ln1b   = (const float*)d_in[4];
  const float* ln2w   = (const float*)d_in[5];
  const float* ln2b   = (const float*)d_in[6];
  const float* x_r    = (const float*)d_in[7];
  const float* x_w    = (const float*)d_in[8];
  const float* x_k    = (const float*)d_in[9];
  const float* x_v    = (const float*)d_in[10];
  const float* x_a    = (const float*)d_in[11];
  const float* x_g    = (const float*)d_in[12];
  const float* w0     = (const float*)d_in[13];
  const float* w1     = (const float*)d_in[14];
  const float* w2     = (const float*)d_in[15];
  const float* a0     = (const float*)d_in[16];
  const float* a1     = (const float*)d_in[17];
  const float* a2     = (const float*)d_in[18];
  const float* v0     = (const float*)d_in[19];
  const float* v1     = (const float*)d_in[20];
  const float* v2     = (const float*)d_in[21];
  const float* g1     = (const float*)d_in[22];
  const float* g2     = (const float*)d_in[23];
  const float* k_k    = (const float*)d_in[24];
  const float* k_a    = (const float*)d_in[25];
  const float* r_k    = (const float*)d_in[26];
  const float* W_r    = (const float*)d_in[27];
  const float* W_k    = (const float*)d_in[28];
  const float* W_v    = (const float*)d_in[29];
  const float* W_o    = (const float*)d_in[30];
  const float* lnxw   = (const float*)d_in[31];
  const float* lnxb   = (const float*)d_in[32];
  const float* mixk   = (const float*)d_in[33];
  const float* Wkey   = (const float*)d_in[34];
  const float* Wval   = (const float*)d_in[35];
  float* out = (float*)d_out;
  float* ws  = (float*)d_ws;
  const size_t U = (size_t)BT * Cc;   // 4,194,304 floats
  float* u[14];
  for (int i=0;i<14;++i) u[i] = ws + i*U;
  float* t_w = ws + 14*U;
  float* t_a = t_w + (size_t)BT*64;
  float* t_v = t_a + (size_t)BT*64;
  float* t_g = t_v + (size_t)BT*32;

  dim3 b256(256);
  // ---- time-mix ----
  ln_kernel<<<BT, b256, 0, stream>>>(x, ln1w, ln1b, u[0], 1e-5f);
  mix_kernel<<<BT, b256, 0, stream>>>(u[0], x_r, u[1]);
  mix_kernel<<<BT, b256, 0, stream>>>(u[0], x_w, u[2]);
  mix_kernel<<<BT, b256, 0, stream>>>(u[0], x_k, u[3]);
  mix_kernel<<<BT, b256, 0, stream>>>(u[0], x_v, u[4]);
  mix_kernel<<<BT, b256, 0, stream>>>(u[0], x_a, u[5]);
  mix_kernel<<<BT, b256, 0, stream>>>(u[0], x_g, u[6]);
  dim3 gCC(Cc/64, BT/64);
  gemm_bt<<<gCC, b256, 0, stream>>>(u[1], W_r, u[7], nullptr, BT, Cc, Cc, 0);
  gemm_bt<<<gCC, b256, 0, stream>>>(u[3], W_k, u[8], nullptr, BT, Cc, Cc, 0);
  gemm_bt<<<gCC, b256, 0, stream>>>(u[4], W_v, u[9], nullptr, BT, Cc, Cc, 0);
  lora1_kernel<<<BT*64/256, b256, 0, stream>>>(u[2], w1, t_w, 64, 1);
  lora2_kernel<<<dim3(BT/8, Cc/256), b256, 0, stream>>>(t_w, w2, u[10], 64);
  lora1_kernel<<<BT*64/256, b256, 0, stream>>>(u[5], a1, t_a, 64, 0);
  lora2_kernel<<<dim3(BT/8, Cc/256), b256, 0, stream>>>(t_a, a2, u[11], 64);
  lora1_kernel<<<BT*32/256, b256, 0, stream>>>(u[4], v1, t_v, 32, 0);
  lora2_kernel<<<dim3(BT/8, Cc/256), b256, 0, stream>>>(t_v, v2, u[12], 32);
  lora1_kernel<<<BT*160/256, b256, 0, stream>>>(u[6], g1, t_g, 160, 2);
  lora2_kernel<<<dim3(BT/8, Cc/256), b256, 0, stream>>>(t_g, g2, u[13], 160);
  prep_kernel<<<BT, b256, 0, stream>>>(u[8], u[10], u[11], u[12], u[9], vfirst,
      w0, a0, v0, k_k, k_a, u[1], u[2], u[3], u[4], u[5]);
  wkv_kernel<<<Bb*Hh, b256, 0, stream>>>(u[1], u[4], u[5], u[2], u[7], u[3], S0, u[6]);
  gn_kernel<<<BT, b256, 0, stream>>>(u[6], u[7], u[2], u[3], u[13], lnxw, lnxb, r_k, u[0]);
  gemm_bt<<<gCC, b256, 0, stream>>>(u[0], W_o, u[8], x, BT, Cc, Cc, 1);
  // ---- channel-mix ----
  ln_kernel<<<BT, b256, 0, stream>>>(u[8], ln2w, ln2b, u[9], 1e-5f);
  mix_kernel<<<BT, b256, 0, stream>>>(u[9], mixk, u[10]);
  gemm_bt<<<dim3(FFNd/64, BT/64), b256, 0, stream>>>(u[10], Wkey, u[0], nullptr, BT, FFNd, Cc, 2);
  gemm_bt<<<dim3(Cc/64, BT/64), b256, 0, stream>>>(u[0], Wval, out, u[8], BT, Cc, FFNd, 1);
  // ---- v_first passthrough ----
  copy_kernel<<<BT*Cc/1024, b256, 0, stream>>>(vfirst, out + (size_t)BT*Cc);
}

// Round 2
// 2482.654 us; speedup vs baseline: 1.4088x; 1.4088x over previous
//
#include <hip/hip_runtime.h>
#include <math.h>

#define Bb 2
#define Tt 2048
#define Cc 1024
#define Hh 16
#define BT 4096
#define FFNd 4096
#define CH 16

typedef __attribute__((ext_vector_type(8))) short bf16x8;
typedef __attribute__((ext_vector_type(4))) float f32x4;

__device__ __forceinline__ float sgm(float x){ return 1.0f/(1.0f+expf(-x)); }

template<int MAXM>
__device__ __forceinline__ float redgrp(float v){
  #pragma unroll
  for (int m=1; m<=MAXM; m<<=1) v += __shfl_xor(v, m, 64);
  return v;
}

// DPP butterfly add over 16-lane rows (VALU pipe, no LDS-pipe traffic)
template<int CTRL>
__device__ __forceinline__ float dppadd(float v){
  union { float f; int i; } u, r;
  u.f = v;
  r.i = __builtin_amdgcn_update_dpp(u.i, u.i, CTRL, 0xf, 0xf, true);
  return v + r.f;
}
__device__ __forceinline__ float red16(float v){
  v = dppadd<0xB1>(v);    // quad_perm [1,0,3,2]  : xor 1
  v = dppadd<0x4E>(v);    // quad_perm [2,3,0,1]  : xor 2
  v = dppadd<0x141>(v);   // row_half_mirror      : xor 7 (pairs 8-halves)
  v = dppadd<0x140>(v);   // row_mirror           : xor 15 (pairs 16-halves)
  return v;
}

// ---------------- LayerNorm (per row of C=1024), block=256, 4 elems/thread ----
__global__ __launch_bounds__(256) void ln_kernel(const float* __restrict__ x,
    const float* __restrict__ w, const float* __restrict__ b,
    float* __restrict__ out, float eps) {
  int row = blockIdx.x;
  int tid = threadIdx.x;
  size_t off = (size_t)row*Cc + tid*4;
  float4 v = *(const float4*)(x + off);
  float s = v.x+v.y+v.z+v.w;
  float q = v.x*v.x+v.y*v.y+v.z*v.z+v.w*v.w;
  s = redgrp<32>(s); q = redgrp<32>(q);
  __shared__ float rs_[4], rq_[4];
  int lane = tid & 63, wv = tid >> 6;
  if (lane==0){ rs_[wv]=s; rq_[wv]=q; }
  __syncthreads();
  s = rs_[0]+rs_[1]+rs_[2]+rs_[3];
  q = rq_[0]+rq_[1]+rq_[2]+rq_[3];
  float mu = s*(1.0f/Cc);
  float var = q*(1.0f/Cc) - mu*mu;
  float rn = rsqrtf(var + eps);
  float4 w4 = *(const float4*)(w + tid*4);
  float4 b4 = *(const float4*)(b + tid*4);
  float4 o;
  o.x = (v.x-mu)*rn*w4.x + b4.x;
  o.y = (v.y-mu)*rn*w4.y + b4.y;
  o.z = (v.z-mu)*rn*w4.z + b4.z;
  o.w = (v.w-mu)*rn*w4.w + b4.w;
  *(float4*)(out + off) = o;
}

// ---------------- time-shift mix: out = xn + (prev - xn) * mix ---------------
__global__ __launch_bounds__(256) void mix_kernel(const float* __restrict__ xn,
    const float* __restrict__ mix, float* __restrict__ out) {
  int row = blockIdx.x; int t = row & (Tt-1);
  int c = threadIdx.x*4;
  size_t off = (size_t)row*Cc + c;
  float4 v = *(const float4*)(xn + off);
  float4 p = {0.f,0.f,0.f,0.f};
  if (t) p = *(const float4*)(xn + off - Cc);
  float4 m = *(const float4*)(mix + c);
  float4 o;
  o.x = v.x + (p.x - v.x)*m.x;
  o.y = v.y + (p.y - v.y)*m.y;
  o.z = v.z + (p.z - v.z)*m.z;
  o.w = v.w + (p.w - v.w)*m.w;
  *(float4*)(out + off) = o;
}

// ================= bf16 MFMA GEMM: out[M,N] = A[M,K] @ W[N,K]^T ==============
// mode 0: plain   1: out = res + acc   2: out = relu(acc)^2
__device__ __forceinline__ unsigned pack_bf16(float a, float b){
  unsigned ua = __builtin_bit_cast(unsigned, a);
  unsigned ub = __builtin_bit_cast(unsigned, b);
  ua = (ua + 0x7FFFu + ((ua>>16)&1u)) >> 16;
  ub = (ub + 0x7FFFu + ((ub>>16)&1u)) >> 16;
  return ua | (ub<<16);
}

// stage [128 rows][64 k] f32 -> bf16 LDS tile with XOR-swizzled 16B slots
__device__ __forceinline__ void stage_tile(const float* __restrict__ src, int ld,
    int row0, int k0, unsigned short* lds, int tid) {
  int rbase = tid >> 4;            // 0..15
  int kc = (tid & 15) * 4;         // 0,4,...,60
  int slotk = kc >> 3;             // 16B slot index 0..7
  int half8 = (kc & 4) ? 8 : 0;    // 8B half within the slot
  #pragma unroll
  for (int p = 0; p < 8; ++p) {
    int row = rbase + p*16;
    const float* gp = src + (size_t)(row0 + row)*ld + k0 + kc;
    float4 v = *(const float4*)gp;
    uint2 pk;
    pk.x = pack_bf16(v.x, v.y);
    pk.y = pack_bf16(v.z, v.w);
    int slot = slotk ^ (row & 7);
    *(uint2*)((char*)lds + row*128 + (slot<<4) + half8) = pk;
  }
}

__device__ __forceinline__ bf16x8 frag_read(const unsigned short* lds, int row, int ks){
  int slot = ks ^ (row & 7);
  return *(const bf16x8*)((const char*)lds + row*128 + (slot<<4));
}

__global__ __launch_bounds__(256) void gemm_mfma(const float* __restrict__ A,
    const float* __restrict__ W, float* __restrict__ out,
    const float* __restrict__ res, int M, int N, int K, int mode) {
  __shared__ alignas(16) unsigned short As[128*64];
  __shared__ alignas(16) unsigned short Bs[128*64];
  int tid = threadIdx.x;
  int bm = blockIdx.y, bn = blockIdx.x;
  int wave = tid >> 6, lane = tid & 63;
  int wm = wave >> 1, wn = wave & 1;
  int lrow = lane & 15, lk8 = lane >> 4;
  f32x4 zero = {0.f,0.f,0.f,0.f};
  f32x4 acc[4][4];
  #pragma unroll
  for (int i=0;i<4;++i)
    #pragma unroll
    for (int j=0;j<4;++j) acc[i][j] = zero;
  for (int kb = 0; kb < K; kb += 64) {
    __syncthreads();
    stage_tile(A, K, bm*128, kb, As, tid);
    stage_tile(W, K, bn*128, kb, Bs, tid);
    __syncthreads();
    #pragma unroll
    for (int kk = 0; kk < 2; ++kk) {
      bf16x8 af[4], bf_[4];
      #pragma unroll
      for (int i=0;i<4;++i) af[i]  = frag_read(As, wm*64 + i*16 + lrow, kk*4 + lk8);
      #pragma unroll
      for (int j=0;j<4;++j) bf_[j] = frag_read(Bs, wn*64 + j*16 + lrow, kk*4 + lk8);
      #pragma unroll
      for (int i=0;i<4;++i)
        #pragma unroll
        for (int j=0;j<4;++j)
          acc[i][j] = __builtin_amdgcn_mfma_f32_16x16x32_bf16(af[i], bf_[j], acc[i][j], 0, 0, 0);
    }
  }
  int crow = lane >> 4, ccol = lane & 15;
  #pragma unroll
  for (int i=0;i<4;++i){
    #pragma unroll
    for (int j=0;j<4;++j){
      int gr0 = bm*128 + wm*64 + i*16 + crow*4;
      int gc  = bn*128 + wn*64 + j*16 + ccol;
      #pragma unroll
      for (int q=0;q<4;++q){
        float v = acc[i][j][q];
        size_t off = (size_t)(gr0+q)*N + gc;
        if (mode==1) v += res[off];
        else if (mode==2){ v = fmaxf(v, 0.f); v = v*v; }
        out[off] = v;
      }
    }
  }
}

// ---------------- LoRA stage1: out[i,d] = act(sum_k A[i,k] W[k,d]) -----------
__global__ __launch_bounds__(256) void lora1_kernel(const float* __restrict__ A,
    const float* __restrict__ W, float* __restrict__ out, int D, int act) {
  int idx = blockIdx.x*256 + threadIdx.x;
  int i = idx / D, d = idx - i*D;
  const float* ap = A + (size_t)i*Cc;
  const float* wp = W + d;
  float acc = 0.f;
  for (int k=0;k<Cc;k+=4){
    float4 a4 = *(const float4*)(ap + k);
    acc = fmaf(a4.x, wp[(size_t)(k+0)*D], acc);
    acc = fmaf(a4.y, wp[(size_t)(k+1)*D], acc);
    acc = fmaf(a4.z, wp[(size_t)(k+2)*D], acc);
    acc = fmaf(a4.w, wp[(size_t)(k+3)*D], acc);
  }
  if (act==1) acc = tanhf(acc);
  else if (act==2) acc = sgm(acc);
  out[idx] = acc;
}

// ---------------- LoRA stage2: out[i,c] = sum_d T[i,d] W2[d,c] ---------------
__global__ __launch_bounds__(256) void lora2_kernel(const float* __restrict__ Tm,
    const float* __restrict__ W2, float* __restrict__ out, int D) {
  int i0 = blockIdx.x*8;
  int c = blockIdx.y*256 + threadIdx.x;
  float acc[8] = {};
  for (int d=0; d<D; ++d) {
    float wv = W2[(size_t)d*Cc + c];
    #pragma unroll
    for (int r=0;r<8;++r) acc[r] = fmaf(Tm[(size_t)(i0+r)*D + d], wv, acc[r]);
  }
  #pragma unroll
  for (int r=0;r<8;++r) out[(size_t)(i0+r)*Cc + c] = acc[r];
}

// ---------------- prep: decay, k_final, v_final, A=-kk, B=kk*a ---------------
__global__ __launch_bounds__(256) void prep_kernel(
    const float* __restrict__ kraw, const float* __restrict__ dw,
    const float* __restrict__ da, const float* __restrict__ dv,
    const float* __restrict__ vraw, const float* __restrict__ vfirst,
    const float* __restrict__ w0, const float* __restrict__ a0,
    const float* __restrict__ v0, const float* __restrict__ k_k,
    const float* __restrict__ k_a,
    float* __restrict__ decay, float* __restrict__ kfin, float* __restrict__ vfin,
    float* __restrict__ Ak, float* __restrict__ Bk) {
  int row = blockIdx.x; int tid = threadIdx.x; int c = tid*4;
  size_t off = (size_t)row*Cc + c;
  float4 kr = *(const float4*)(kraw+off);
  float4 w4 = *(const float4*)(dw+off);
  float4 A4 = *(const float4*)(da+off);
  float4 V4 = *(const float4*)(dv+off);
  float4 vr = *(const float4*)(vraw+off);
  float4 vf = *(const float4*)(vfirst+off);
  float4 w04 = *(const float4*)(w0+c);
  float4 a04 = *(const float4*)(a0+c);
  float4 v04 = *(const float4*)(v0+c);
  float4 kk4 = *(const float4*)(k_k+c);
  float4 ka4 = *(const float4*)(k_a+c);
  float krl[4]={kr.x,kr.y,kr.z,kr.w};
  float dwl[4]={w4.x,w4.y,w4.z,w4.w};
  float dal[4]={A4.x,A4.y,A4.z,A4.w};
  float dvl[4]={V4.x,V4.y,V4.z,V4.w};
  float vrl[4]={vr.x,vr.y,vr.z,vr.w};
  float vfl[4]={vf.x,vf.y,vf.z,vf.w};
  float w0l[4]={w04.x,w04.y,w04.z,w04.w};
  float a0l[4]={a04.x,a04.y,a04.z,a04.w};
  float v0l[4]={v04.x,v04.y,v04.z,v04.w};
  float kkl[4]={kk4.x,kk4.y,kk4.z,kk4.w};
  float kal[4]={ka4.x,ka4.y,ka4.z,ka4.w};
  float av[4], dec[4], vv[4], kp[4], kf[4];
  float ss = 0.f;
  #pragma unroll
  for (int q=0;q<4;++q){
    av[q] = sgm(a0l[q] + dal[q]);
    dec[q] = 0.60653065971263342f * sgm(w0l[q] + dwl[q]);   // exp(-softplus(-u)-0.5)
    float sv = sgm(v0l[q] + dvl[q]);
    vv[q] = vrl[q] + (vfl[q]-vrl[q])*sv;
    kp[q] = krl[q]*kkl[q];
    ss += kp[q]*kp[q];
    kf[q] = krl[q]*(1.0f + (av[q]-1.0f)*kal[q]);
  }
  ss = redgrp<8>(ss);               // per-head (64 elems = 16 lanes) L2 norm^2
  float inv = 1.0f / fmaxf(sqrtf(ss), 1e-12f);
  float4 o;
  o.x=dec[0];o.y=dec[1];o.z=dec[2];o.w=dec[3];  *(float4*)(decay+off)=o;
  o.x=kf[0]; o.y=kf[1]; o.z=kf[2]; o.w=kf[3];   *(float4*)(kfin+off)=o;
  o.x=vv[0]; o.y=vv[1]; o.z=vv[2]; o.w=vv[3];   *(float4*)(vfin+off)=o;
  o.x=-kp[0]*inv; o.y=-kp[1]*inv; o.z=-kp[2]*inv; o.w=-kp[3]*inv; *(float4*)(Ak+off)=o;
  o.x=kp[0]*inv*av[0]; o.y=kp[1]*inv*av[1]; o.z=kp[2]*inv*av[2]; o.w=kp[3]*inv*av[3];
  *(float4*)(Bk+off)=o;
}

// ---------------- WKV-7 scan: 1 block per (b,h), 256 thr, S 4x4/thread -------
__global__ __launch_bounds__(256) void wkv_kernel(
    const float* __restrict__ decay, const float* __restrict__ Ak,
    const float* __restrict__ Bk, const float* __restrict__ kfin,
    const float* __restrict__ r_, const float* __restrict__ vfin,
    const float* __restrict__ S0, float* __restrict__ y) {
  __shared__ float lds[2][6][CH][64];
  int bh = blockIdx.x; int bb = bh >> 4, h = bh & 15;
  int tid = threadIdx.x;
  int bi = tid >> 4, bj = tid & 15;
  int i0 = bi*4, j0 = bj*4;
  float S[4][4];
  const float* s0p = S0 + (size_t)bh*4096;
  #pragma unroll
  for (int ri=0;ri<4;++ri)
    #pragma unroll
    for (int jl=0;jl<4;++jl) S[ri][jl] = s0p[(i0+ri)*64 + j0+jl];
  const float* bases[6] = {decay, Ak, Bk, kfin, r_, vfin};
  size_t rowbase = (size_t)bb*Tt;
  int st = tid >> 4;           // 0..15 = step within chunk for staging
  int e  = (tid & 15) * 4;     // float offset within 64
  float4 regs[6];
  #pragma unroll
  for (int arr=0; arr<6; ++arr)
    regs[arr] = *(const float4*)(bases[arr] + (rowbase + 0 + st)*Cc + h*64 + e);
  #pragma unroll
  for (int arr=0; arr<6; ++arr)
    *(float4*)&lds[0][arr][st][e] = regs[arr];
  __syncthreads();
  const int NC = Tt/CH;
  for (int ch=0; ch<NC; ++ch) {
    int cur = ch & 1;
    if (ch+1 < NC) {
      #pragma unroll
      for (int arr=0; arr<6; ++arr)
        regs[arr] = *(const float4*)(bases[arr] + (rowbase + (ch+1)*CH + st)*Cc + h*64 + e);
    }
    for (int s=0; s<CH; ++s) {
      const float* pd = &lds[cur][0][s][0];     // array stride = CH*64 floats
      float4 d4 = *(const float4*)(pd + 0*CH*64 + j0);
      float4 a4 = *(const float4*)(pd + 1*CH*64 + j0);
      float4 b4 = *(const float4*)(pd + 2*CH*64 + j0);
      float4 k4 = *(const float4*)(pd + 3*CH*64 + j0);
      float4 r4 = *(const float4*)(pd + 4*CH*64 + j0);
      float4 v4 = *(const float4*)(pd + 5*CH*64 + i0);
      float dd[4]={d4.x,d4.y,d4.z,d4.w};
      float aa[4]={a4.x,a4.y,a4.z,a4.w};
      float bv[4]={b4.x,b4.y,b4.z,b4.w};
      float kv[4]={k4.x,k4.y,k4.z,k4.w};
      float rv[4]={r4.x,r4.y,r4.z,r4.w};
      float vl[4]={v4.x,v4.y,v4.z,v4.w};
      float sa[4], yp[4];
      // decay FIRST (matches reference), then sa from decayed state
      #pragma unroll
      for (int ri=0;ri<4;++ri){
        #pragma unroll
        for (int jl=0;jl<4;++jl) S[ri][jl] *= dd[jl];
        sa[ri] = S[ri][0]*aa[0] + S[ri][1]*aa[1] + S[ri][2]*aa[2] + S[ri][3]*aa[3];
      }
      #pragma unroll
      for (int ri=0;ri<4;++ri) sa[ri] = red16(sa[ri]);   // DPP, VALU pipe
      #pragma unroll
      for (int ri=0;ri<4;++ri){
        #pragma unroll
        for (int jl=0;jl<4;++jl){
          float t = fmaf(vl[ri], kv[jl], S[ri][jl]);
          S[ri][jl] = fmaf(sa[ri], bv[jl], t);
        }
        yp[ri] = S[ri][0]*rv[0] + S[ri][1]*rv[1] + S[ri][2]*rv[2] + S[ri][3]*rv[3];
      }
      #pragma unroll
      for (int ri=0;ri<4;++ri) yp[ri] = red16(yp[ri]);   // DPP, VALU pipe
      if (bj == 0) {
        float4 o = {yp[0],yp[1],yp[2],yp[3]};
        *(float4*)(y + (rowbase + ch*CH + s)*Cc + h*64 + i0) = o;
      }
    }
    if (ch+1 < NC) {
      int nxt = cur ^ 1;
      #pragma unroll
      for (int arr=0; arr<6; ++arr)
        *(float4*)&lds[nxt][arr][st][e] = regs[arr];
    }
    __syncthreads();
  }
}

// ---------------- GroupNorm(head) + r.k.r_k bonus + *g  ->  Ao ----------------
__global__ __launch_bounds__(256) void gn_kernel(
    const float* __restrict__ y, const float* __restrict__ r_,
    const float* __restrict__ kfin, const float* __restrict__ vfin,
    const float* __restrict__ g_, const float* __restrict__ lnxw,
    const float* __restrict__ lnxb, const float* __restrict__ r_k,
    float* __restrict__ Ao) {
  int row = blockIdx.x; int tid = threadIdx.x; int c = tid*4;
  size_t off = (size_t)row*Cc + c;
  float4 y4 = *(const float4*)(y+off);
  float s = y4.x+y4.y+y4.z+y4.w;
  float q = y4.x*y4.x+y4.y*y4.y+y4.z*y4.z+y4.w*y4.w;
  s = redgrp<8>(s); q = redgrp<8>(q);
  float mu = s*(1.0f/64.0f);
  float var = q*(1.0f/64.0f) - mu*mu;
  float rn = rsqrtf(var + 64e-5f);
  float4 rr = *(const float4*)(r_+off);
  float4 kk = *(const float4*)(kfin+off);
  float4 vv = *(const float4*)(vfin+off);
  float4 gg = *(const float4*)(g_+off);
  int h = tid >> 4; int hs = (tid & 15)*4;
  float4 rk = *(const float4*)(r_k + h*64 + hs);
  float dp = rr.x*kk.x*rk.x + rr.y*kk.y*rk.y + rr.z*kk.z*rk.z + rr.w*kk.w*rk.w;
  dp = redgrp<8>(dp);
  float4 w4 = *(const float4*)(lnxw+c);
  float4 b4 = *(const float4*)(lnxb+c);
  float4 o;
  o.x = (((y4.x-mu)*rn)*w4.x + b4.x + dp*vv.x) * gg.x;
  o.y = (((y4.y-mu)*rn)*w4.y + b4.y + dp*vv.y) * gg.y;
  o.z = (((y4.z-mu)*rn)*w4.z + b4.z + dp*vv.z) * gg.z;
  o.w = (((y4.w-mu)*rn)*w4.w + b4.w + dp*vv.w) * gg.w;
  *(float4*)(Ao + off) = o;
}

__global__ __launch_bounds__(256) void copy_kernel(const float* __restrict__ src,
                                                   float* __restrict__ dst) {
  size_t i = ((size_t)blockIdx.x*256 + threadIdx.x)*4;
  *(float4*)(dst+i) = *(const float4*)(src+i);
}

extern "C" void kernel_launch(void* const* d_in, const int* in_sizes, int n_in,
                              void* d_out, int out_size, void* d_ws, size_t ws_size,
                              hipStream_t stream) {
  const float* x      = (const float*)d_in[0];
  const float* vfirst = (const float*)d_in[1];
  const float* S0     = (const float*)d_in[2];
  const float* ln1w   = (const float*)d_in[3];
  const float* ln1b   = (const float*)d_in[4];
  const float* ln2w   = (const float*)d_in[5];
  const float* ln2b   = (const float*)d_in[6];
  const float* x_r    = (const float*)d_in[7];
  const float* x_w    = (const float*)d_in[8];
  const float* x_k    = (const float*)d_in[9];
  const float* x_v    = (const float*)d_in[10];
  const float* x_a    = (const float*)d_in[11];
  const float* x_g    = (const float*)d_in[12];
  const float* w0     = (const float*)d_in[13];
  const float* w1     = (const float*)d_in[14];
  const float* w2     = (const float*)d_in[15];
  const float* a0     = (const float*)d_in[16];
  const float* a1     = (const float*)d_in[17];
  const float* a2     = (const float*)d_in[18];
  const float* v0     = (const float*)d_in[19];
  const float* v1     = (const float*)d_in[20];
  const float* v2     = (const float*)d_in[21];
  const float* g1     = (const float*)d_in[22];
  const float* g2     = (const float*)d_in[23];
  const float* k_k    = (const float*)d_in[24];
  const float* k_a    = (const float*)d_in[25];
  const float* r_k    = (const float*)d_in[26];
  const float* W_r    = (const float*)d_in[27];
  const float* W_k    = (const float*)d_in[28];
  const float* W_v    = (const float*)d_in[29];
  const float* W_o    = (const float*)d_in[30];
  const float* lnxw   = (const float*)d_in[31];
  const float* lnxb   = (const float*)d_in[32];
  const float* mixk   = (const float*)d_in[33];
  const float* Wkey   = (const float*)d_in[34];
  const float* Wval   = (const float*)d_in[35];
  float* out = (float*)d_out;
  float* ws  = (float*)d_ws;
  const size_t U = (size_t)BT * Cc;   // 4,194,304 floats
  float* u[14];
  for (int i=0;i<14;++i) u[i] = ws + i*U;
  float* t_w = ws + 14*U;
  float* t_a = t_w + (size_t)BT*64;
  float* t_v = t_a + (size_t)BT*64;
  float* t_g = t_v + (size_t)BT*32;

  dim3 b256(256);
  // ---- time-mix ----
  ln_kernel<<<BT, b256, 0, stream>>>(x, ln1w, ln1b, u[0], 1e-5f);
  mix_kernel<<<BT, b256, 0, stream>>>(u[0], x_r, u[1]);
  mix_kernel<<<BT, b256, 0, stream>>>(u[0], x_w, u[2]);
  mix_kernel<<<BT, b256, 0, stream>>>(u[0], x_k, u[3]);
  mix_kernel<<<BT, b256, 0, stream>>>(u[0], x_v, u[4]);
  mix_kernel<<<BT, b256, 0, stream>>>(u[0], x_a, u[5]);
  mix_kernel<<<BT, b256, 0, stream>>>(u[0], x_g, u[6]);
  dim3 gCC(Cc/128, BT/128);
  gemm_mfma<<<gCC, b256, 0, stream>>>(u[1], W_r, u[7], nullptr, BT, Cc, Cc, 0);
  gemm_mfma<<<gCC, b256, 0, stream>>>(u[3], W_k, u[8], nullptr, BT, Cc, Cc, 0);
  gemm_mfma<<<gCC, b256, 0, stream>>>(u[4], W_v, u[9], nullptr, BT, Cc, Cc, 0);
  lora1_kernel<<<BT*64/256, b256, 0, stream>>>(u[2], w1, t_w, 64, 1);
  lora2_kernel<<<dim3(BT/8, Cc/256), b256, 0, stream>>>(t_w, w2, u[10], 64);
  lora1_kernel<<<BT*64/256, b256, 0, stream>>>(u[5], a1, t_a, 64, 0);
  lora2_kernel<<<dim3(BT/8, Cc/256), b256, 0, stream>>>(t_a, a2, u[11], 64);
  lora1_kernel<<<BT*32/256, b256, 0, stream>>>(u[4], v1, t_v, 32, 0);
  lora2_kernel<<<dim3(BT/8, Cc/256), b256, 0, stream>>>(t_v, v2, u[12], 32);
  lora1_kernel<<<BT*160/256, b256, 0, stream>>>(u[6], g1, t_g, 160, 2);
  lora2_kernel<<<dim3(BT/8, Cc/256), b256, 0, stream>>>(t_g, g2, u[13], 160);
  prep_kernel<<<BT, b256, 0, stream>>>(u[8], u[10], u[11], u[12], u[9], vfirst,
      w0, a0, v0, k_k, k_a, u[1], u[2], u[3], u[4], u[5]);
  wkv_kernel<<<Bb*Hh, b256, 0, stream>>>(u[1], u[4], u[5], u[2], u[7], u[3], S0, u[6]);
  gn_kernel<<<BT, b256, 0, stream>>>(u[6], u[7], u[2], u[3], u[13], lnxw, lnxb, r_k, u[0]);
  gemm_mfma<<<gCC, b256, 0, stream>>>(u[0], W_o, u[8], x, BT, Cc, Cc, 1);
  // ---- channel-mix ----
  ln_kernel<<<BT, b256, 0, stream>>>(u[8], ln2w, ln2b, u[9], 1e-5f);
  mix_kernel<<<BT, b256, 0, stream>>>(u[9], mixk, u[10]);
  gemm_mfma<<<dim3(FFNd/128, BT/128), b256, 0, stream>>>(u[10], Wkey, u[0], nullptr, BT, FFNd, Cc, 2);
  gemm_mfma<<<dim3(Cc/128, BT/128), b256, 0, stream>>>(u[0], Wval, out, u[8], BT, Cc, FFNd, 1);
  // ---- v_first passthrough ----
  copy_kernel<<<BT*Cc/1024, b256, 0, stream>>>(vfirst, out + (size_t)BT*Cc);
}

// Round 3
// 978.889 us; speedup vs baseline: 3.5730x; 2.5362x over previous
//
#include <hip/hip_runtime.h>
#include <math.h>

#define Bb 2
#define Tt 2048
#define Cc 1024
#define Hh 16
#define BT 4096
#define FFNd 4096
#define CH 16
#define BIGN 3456
#define BIGK 2048
// big-B column layout: r@0 k@1024 v@2048 w@3072 a@3136 vl@3200 g@3232 (end 3392, pad->3456)

typedef __attribute__((ext_vector_type(8))) short bf16x8;
typedef __attribute__((ext_vector_type(4))) float f32x4;
typedef unsigned short u16;

__device__ __forceinline__ float sgm(float x){ return 1.0f/(1.0f+expf(-x)); }

template<int MAXM>
__device__ __forceinline__ float redgrp(float v){
  #pragma unroll
  for (int m=1; m<=MAXM; m<<=1) v += __shfl_xor(v, m, 64);
  return v;
}

template<int CTRL>
__device__ __forceinline__ float dppadd(float v){
  union { float f; int i; } u, r;
  u.f = v;
  r.i = __builtin_amdgcn_update_dpp(u.i, u.i, CTRL, 0xf, 0xf, true);
  return v + r.f;
}
__device__ __forceinline__ float red16(float v){
  v = dppadd<0xB1>(v);
  v = dppadd<0x4E>(v);
  v = dppadd<0x141>(v);
  v = dppadd<0x140>(v);
  return v;
}

__device__ __forceinline__ unsigned pack_bf16(float a, float b){
  unsigned ua = __builtin_bit_cast(unsigned, a);
  unsigned ub = __builtin_bit_cast(unsigned, b);
  ua = (ua + 0x7FFFu + ((ua>>16)&1u)) >> 16;
  ub = (ub + 0x7FFFu + ((ub>>16)&1u)) >> 16;
  return ua | (ub<<16);
}
__device__ __forceinline__ u16 bf16_1(float a){
  unsigned ua = __builtin_bit_cast(unsigned, a);
  return (u16)((ua + 0x7FFFu + ((ua>>16)&1u)) >> 16);
}

__device__ __forceinline__ void gload16(const void* g, void* l){
  __builtin_amdgcn_global_load_lds(
    (const __attribute__((address_space(1))) unsigned int*)g,
    (__attribute__((address_space(3))) unsigned int*)l, 16, 0, 0);
}

// ---------------- f32 -> bf16 convert (weights) -------------------------------
__global__ __launch_bounds__(256) void cvt_kernel(const float* __restrict__ in,
    u16* __restrict__ out) {
  size_t i = (size_t)blockIdx.x*256 + threadIdx.x;
  float4 a = ((const float4*)in)[2*i];
  float4 b = ((const float4*)in)[2*i+1];
  uint4 o = {pack_bf16(a.x,a.y), pack_bf16(a.z,a.w),
             pack_bf16(b.x,b.y), pack_bf16(b.z,b.w)};
  ((uint4*)out)[i] = o;
}

// ---------------- pack square weight into BigB rows: [W | diag(mix)W] --------
__global__ __launch_bounds__(256) void packW_kernel(const float* __restrict__ W,
    const float* __restrict__ mix, u16* __restrict__ out) {
  int n = blockIdx.x;             // 0..1023
  int c0 = threadIdx.x*8;         // 0..2040
  int ks = c0 & 1023;
  const float* src = W + (size_t)n*Cc + ks;
  float4 a = *(const float4*)src;
  float4 b = *(const float4*)(src+4);
  if (c0 >= 1024){
    float4 m0 = *(const float4*)(mix + ks);
    float4 m1 = *(const float4*)(mix + ks + 4);
    a.x*=m0.x; a.y*=m0.y; a.z*=m0.z; a.w*=m0.w;
    b.x*=m1.x; b.y*=m1.y; b.z*=m1.z; b.w*=m1.w;
  }
  uint4 o = {pack_bf16(a.x,a.y), pack_bf16(a.z,a.w),
             pack_bf16(b.x,b.y), pack_bf16(b.z,b.w)};
  *(uint4*)(out + (size_t)n*BIGK + c0) = o;
}

// ---------------- pack lora W1[C,D] (transposed) into BigB rows --------------
__global__ __launch_bounds__(256) void packL_kernel(const float* __restrict__ W1,
    const float* __restrict__ mix, u16* __restrict__ out, int D, int nbase) {
  int d = blockIdx.x;             // 0..D-1
  int k0 = threadIdx.x*8;
  float v[8];
  #pragma unroll
  for (int q=0;q<8;++q){
    int kk = k0+q;
    int ks = kk & 1023;
    float t = W1[(size_t)ks*D + d];
    if (kk >= 1024) t *= mix[ks];
    v[q] = t;
  }
  uint4 o = {pack_bf16(v[0],v[1]), pack_bf16(v[2],v[3]),
             pack_bf16(v[4],v[5]), pack_bf16(v[6],v[7])};
  *(uint4*)(out + (size_t)(nbase+d)*BIGK + k0) = o;
}

// ---------------- fused LN1 -> bigA = [xn | xx] bf16 -------------------------
__global__ __launch_bounds__(256) void lnmix1_kernel(const float* __restrict__ x,
    const float* __restrict__ w, const float* __restrict__ b,
    u16* __restrict__ bigA) {
  int rowg = blockIdx.x; int t = rowg & (Tt-1);
  int tid = threadIdx.x;
  size_t off = (size_t)rowg*Cc + tid*4;
  float4 vc = *(const float4*)(x + off);
  float4 vp = {0.f,0.f,0.f,0.f};
  if (t) vp = *(const float4*)(x + off - Cc);
  float sc = vc.x+vc.y+vc.z+vc.w;
  float qc = vc.x*vc.x+vc.y*vc.y+vc.z*vc.z+vc.w*vc.w;
  float sp = vp.x+vp.y+vp.z+vp.w;
  float qp = vp.x*vp.x+vp.y*vp.y+vp.z*vp.z+vp.w*vp.w;
  sc = redgrp<32>(sc); qc = redgrp<32>(qc);
  sp = redgrp<32>(sp); qp = redgrp<32>(qp);
  __shared__ float rbuf[4][4];
  int lane = tid & 63, wv = tid >> 6;
  if (lane==0){ rbuf[wv][0]=sc; rbuf[wv][1]=qc; rbuf[wv][2]=sp; rbuf[wv][3]=qp; }
  __syncthreads();
  sc = rbuf[0][0]+rbuf[1][0]+rbuf[2][0]+rbuf[3][0];
  qc = rbuf[0][1]+rbuf[1][1]+rbuf[2][1]+rbuf[3][1];
  sp = rbuf[0][2]+rbuf[1][2]+rbuf[2][2]+rbuf[3][2];
  qp = rbuf[0][3]+rbuf[1][3]+rbuf[2][3]+rbuf[3][3];
  float muc = sc*(1.0f/Cc), mup = sp*(1.0f/Cc);
  float rnc = rsqrtf(qc*(1.0f/Cc) - muc*muc + 1e-5f);
  float rnp = rsqrtf(qp*(1.0f/Cc) - mup*mup + 1e-5f);
  float4 w4 = *(const float4*)(w + tid*4);
  float4 b4 = *(const float4*)(b + tid*4);
  float vcl[4]={vc.x,vc.y,vc.z,vc.w};
  float vpl[4]={vp.x,vp.y,vp.z,vp.w};
  float wl[4]={w4.x,w4.y,w4.z,w4.w};
  float bl[4]={b4.x,b4.y,b4.z,b4.w};
  float xnc[4], xx[4];
  #pragma unroll
  for (int q=0;q<4;++q){
    xnc[q] = (vcl[q]-muc)*rnc*wl[q] + bl[q];
    float xnp = t ? ((vpl[q]-mup)*rnp*wl[q] + bl[q]) : 0.0f;
    xx[q] = xnp - xnc[q];
  }
  size_t ab = (size_t)rowg*BIGK + tid*4;
  uint2 p0 = {pack_bf16(xnc[0],xnc[1]), pack_bf16(xnc[2],xnc[3])};
  uint2 p1 = {pack_bf16(xx[0],xx[1]),   pack_bf16(xx[2],xx[3])};
  *(uint2*)(bigA + ab) = p0;
  *(uint2*)(bigA + ab + 1024) = p1;
}

// ---------------- fused LN2 + cmix -> bf16 -----------------------------------
__global__ __launch_bounds__(256) void lnmix2_kernel(const float* __restrict__ x,
    const float* __restrict__ w, const float* __restrict__ b,
    const float* __restrict__ mixk, u16* __restrict__ outb) {
  int rowg = blockIdx.x; int t = rowg & (Tt-1);
  int tid = threadIdx.x;
  size_t off = (size_t)rowg*Cc + tid*4;
  float4 vc = *(const float4*)(x + off);
  float4 vp = {0.f,0.f,0.f,0.f};
  if (t) vp = *(const float4*)(x + off - Cc);
  float sc = vc.x+vc.y+vc.z+vc.w;
  float qc = vc.x*vc.x+vc.y*vc.y+vc.z*vc.z+vc.w*vc.w;
  float sp = vp.x+vp.y+vp.z+vp.w;
  float qp = vp.x*vp.x+vp.y*vp.y+vp.z*vp.z+vp.w*vp.w;
  sc = redgrp<32>(sc); qc = redgrp<32>(qc);
  sp = redgrp<32>(sp); qp = redgrp<32>(qp);
  __shared__ float rbuf[4][4];
  int lane = tid & 63, wv = tid >> 6;
  if (lane==0){ rbuf[wv][0]=sc; rbuf[wv][1]=qc; rbuf[wv][2]=sp; rbuf[wv][3]=qp; }
  __syncthreads();
  sc = rbuf[0][0]+rbuf[1][0]+rbuf[2][0]+rbuf[3][0];
  qc = rbuf[0][1]+rbuf[1][1]+rbuf[2][1]+rbuf[3][1];
  sp = rbuf[0][2]+rbuf[1][2]+rbuf[2][2]+rbuf[3][2];
  qp = rbuf[0][3]+rbuf[1][3]+rbuf[2][3]+rbuf[3][3];
  float muc = sc*(1.0f/Cc), mup = sp*(1.0f/Cc);
  float rnc = rsqrtf(qc*(1.0f/Cc) - muc*muc + 1e-5f);
  float rnp = rsqrtf(qp*(1.0f/Cc) - mup*mup + 1e-5f);
  float4 w4 = *(const float4*)(w + tid*4);
  float4 b4 = *(const float4*)(b + tid*4);
  float4 m = *(const float4*)(mixk + tid*4);
  float vcl[4]={vc.x,vc.y,vc.z,vc.w};
  float vpl[4]={vp.x,vp.y,vp.z,vp.w};
  float wl[4]={w4.x,w4.y,w4.z,w4.w};
  float bl[4]={b4.x,b4.y,b4.z,b4.w};
  float ml[4]={m.x,m.y,m.z,m.w};
  float o[4];
  #pragma unroll
  for (int q=0;q<4;++q){
    float xnc = (vcl[q]-muc)*rnc*wl[q] + bl[q];
    float xnp = t ? ((vpl[q]-mup)*rnp*wl[q] + bl[q]) : 0.0f;
    o[q] = xnc + (xnp - xnc)*ml[q];
  }
  uint2 p = {pack_bf16(o[0],o[1]), pack_bf16(o[2],o[3])};
  *(uint2*)(outb + off) = p;
}

// ================= bf16 GEMM (m97 structure): out = A[M,K] @ W[N,K]^T ========
// MODE 0: f32 out   1: f32 out = res + acc   2: bf16 out = relu(acc)^2
template<int MODE>
__global__ __launch_bounds__(256) void gemm_bf16(const u16* __restrict__ A,
    const u16* __restrict__ W, void* __restrict__ outv,
    const float* __restrict__ res, int M, int N, int K) {
  __shared__ u16 As[2][128*64];
  __shared__ u16 Bs[2][128*64];
  int tid = threadIdx.x;
  int bm = blockIdx.y, bn = blockIdx.x;
  int wave = tid >> 6, lane = tid & 63;
  int wm = wave >> 1, wn = wave & 1;
  int srow = wave*32 + (lane>>3);
  int scol = (lane&7)*8;
  const u16* Ag = A + (size_t)(bm*128 + srow)*K + scol;
  const u16* Wg = W + (size_t)(bn*128 + srow)*K + scol;
  int nt = K >> 6;
  f32x4 acc[4][4];
  f32x4 zero = {0.f,0.f,0.f,0.f};
  #pragma unroll
  for (int i=0;i<4;++i)
    #pragma unroll
    for (int j=0;j<4;++j) acc[i][j] = zero;

  #define STAGE(buf, t) { \
    const u16* Ag2 = Ag + (size_t)(t)*64; \
    const u16* Wg2 = Wg + (size_t)(t)*64; \
    _Pragma("unroll") \
    for (int i_=0;i_<4;++i_){ \
      gload16(Ag2 + (size_t)i_*8*K, &As[buf][(wave*32+i_*8)*64]); \
      gload16(Wg2 + (size_t)i_*8*K, &Bs[buf][(wave*32+i_*8)*64]); \
    } }

  STAGE(0, 0);
  asm volatile("s_waitcnt vmcnt(0)" ::: "memory");
  __syncthreads();
  int lrow = lane & 15, lk8 = lane >> 4;
  for (int t = 0; t < nt; ++t) {
    int cur = t & 1;
    if (t+1 < nt) STAGE(cur^1, t+1);
    #pragma unroll
    for (int kk2 = 0; kk2 < 2; ++kk2) {
      bf16x8 af[4], bfr[4];
      #pragma unroll
      for (int i=0;i<4;++i)
        af[i] = *(const bf16x8*)&As[cur][(wm*64 + i*16 + lrow)*64 + kk2*32 + lk8*8];
      #pragma unroll
      for (int j=0;j<4;++j)
        bfr[j] = *(const bf16x8*)&Bs[cur][(wn*64 + j*16 + lrow)*64 + kk2*32 + lk8*8];
      #pragma unroll
      for (int i=0;i<4;++i)
        #pragma unroll
        for (int j=0;j<4;++j)
          acc[i][j] = __builtin_amdgcn_mfma_f32_16x16x32_bf16(af[i], bfr[j], acc[i][j], 0, 0, 0);
    }
    if (t+1 < nt) { asm volatile("s_waitcnt vmcnt(0)" ::: "memory"); }
    __syncthreads();
  }
  #undef STAGE
  float* outf = (float*)outv;
  u16* outb = (u16*)outv;
  int crow4 = (lane>>4)*4, ccol = lane & 15;
  #pragma unroll
  for (int i=0;i<4;++i){
    #pragma unroll
    for (int j=0;j<4;++j){
      int gr = bm*128 + wm*64 + i*16 + crow4;
      int gc = bn*128 + wn*64 + j*16 + ccol;
      #pragma unroll
      for (int q=0;q<4;++q){
        float v = acc[i][j][q];
        size_t o = (size_t)(gr+q)*N + gc;
        if (MODE==1) { v += res[o]; outf[o] = v; }
        else if (MODE==2) { v = fmaxf(v, 0.f); outb[o] = bf16_1(v*v); }
        else outf[o] = v;
      }
    }
  }
}

// ---------------- activation pass over lora columns of bigOut ----------------
__global__ __launch_bounds__(256) void act_kernel(float* __restrict__ m) {
  int idx = blockIdx.x*256 + threadIdx.x;      // BT*320
  int i = idx / 320, cc = idx - i*320;
  size_t o = (size_t)i*BIGN + 3072 + cc;
  float v = m[o];
  if (cc < 64) v = tanhf(v);
  else if (cc >= 160) v = sgm(v);
  m[o] = v;
}

// ---------------- LoRA stage2: out[i,c] = sum_d T[i,d] W2[d,c] ---------------
__global__ __launch_bounds__(256) void lora2_kernel(const float* __restrict__ Tm,
    const float* __restrict__ W2, float* __restrict__ out, int D) {
  int i0 = blockIdx.x*8;
  int c = blockIdx.y*256 + threadIdx.x;
  float acc[8] = {};
  for (int d=0; d<D; ++d) {
    float wv = W2[(size_t)d*Cc + c];
    #pragma unroll
    for (int r=0;r<8;++r) acc[r] = fmaf(Tm[(size_t)(i0+r)*BIGN + d], wv, acc[r]);
  }
  #pragma unroll
  for (int r=0;r<8;++r) out[(size_t)(i0+r)*Cc + c] = acc[r];
}

// ---------------- prep (k/v read from bigOut views, ld=BIGN) -----------------
__global__ __launch_bounds__(256) void prep_kernel(
    const float* __restrict__ kraw, const float* __restrict__ dw,
    const float* __restrict__ da, const float* __restrict__ dv,
    const float* __restrict__ vraw, const float* __restrict__ vfirst,
    const float* __restrict__ w0, const float* __restrict__ a0,
    const float* __restrict__ v0, const float* __restrict__ k_k,
    const float* __restrict__ k_a,
    float* __restrict__ decay, float* __restrict__ kfin, float* __restrict__ vfin,
    float* __restrict__ Ak, float* __restrict__ Bk) {
  int row = blockIdx.x; int tid = threadIdx.x; int c = tid*4;
  size_t off = (size_t)row*Cc + c;
  size_t offw = (size_t)row*BIGN + c;
  float4 kr = *(const float4*)(kraw+offw);
  float4 vr = *(const float4*)(vraw+offw);
  float4 w4 = *(const float4*)(dw+off);
  float4 A4 = *(const float4*)(da+off);
  float4 V4 = *(const float4*)(dv+off);
  float4 vf = *(const float4*)(vfirst+off);
  float4 w04 = *(const float4*)(w0+c);
  float4 a04 = *(const float4*)(a0+c);
  float4 v04 = *(const float4*)(v0+c);
  float4 kk4 = *(const float4*)(k_k+c);
  float4 ka4 = *(const float4*)(k_a+c);
  float krl[4]={kr.x,kr.y,kr.z,kr.w};
  float dwl[4]={w4.x,w4.y,w4.z,w4.w};
  float dal[4]={A4.x,A4.y,A4.z,A4.w};
  float dvl[4]={V4.x,V4.y,V4.z,V4.w};
  float vrl[4]={vr.x,vr.y,vr.z,vr.w};
  float vfl[4]={vf.x,vf.y,vf.z,vf.w};
  float w0l[4]={w04.x,w04.y,w04.z,w04.w};
  float a0l[4]={a04.x,a04.y,a04.z,a04.w};
  float v0l[4]={v04.x,v04.y,v04.z,v04.w};
  float kkl[4]={kk4.x,kk4.y,kk4.z,kk4.w};
  float kal[4]={ka4.x,ka4.y,ka4.z,ka4.w};
  float av[4], dec[4], vv[4], kp[4], kf[4];
  float ss = 0.f;
  #pragma unroll
  for (int q=0;q<4;++q){
    av[q] = sgm(a0l[q] + dal[q]);
    dec[q] = 0.60653065971263342f * sgm(w0l[q] + dwl[q]);   // exp(-softplus(-u)-0.5)
    float sv = sgm(v0l[q] + dvl[q]);
    vv[q] = vrl[q] + (vfl[q]-vrl[q])*sv;
    kp[q] = krl[q]*kkl[q];
    ss += kp[q]*kp[q];
    kf[q] = krl[q]*(1.0f + (av[q]-1.0f)*kal[q]);
  }
  ss = redgrp<8>(ss);
  float inv = 1.0f / fmaxf(sqrtf(ss), 1e-12f);
  float4 o;
  o.x=dec[0];o.y=dec[1];o.z=dec[2];o.w=dec[3];  *(float4*)(decay+off)=o;
  o.x=kf[0]; o.y=kf[1]; o.z=kf[2]; o.w=kf[3];   *(float4*)(kfin+off)=o;
  o.x=vv[0]; o.y=vv[1]; o.z=vv[2]; o.w=vv[3];   *(float4*)(vfin+off)=o;
  o.x=-kp[0]*inv; o.y=-kp[1]*inv; o.z=-kp[2]*inv; o.w=-kp[3]*inv; *(float4*)(Ak+off)=o;
  o.x=kp[0]*inv*av[0]; o.y=kp[1]*inv*av[1]; o.z=kp[2]*inv*av[2]; o.w=kp[3]*inv*av[3];
  *(float4*)(Bk+off)=o;
}

// ---------------- WKV-7 scan: row-split. 128 blocks (32 bh x 4 splits) -------
__global__ __launch_bounds__(256) void wkv_kernel(
    const float* __restrict__ decay, const float* __restrict__ Ak,
    const float* __restrict__ Bk, const float* __restrict__ kfin,
    const float* __restrict__ r_, const float* __restrict__ vfin,
    const float* __restrict__ S0, float* __restrict__ y) {
  __shared__ float lds[2][6][CH][64];
  int bid = blockIdx.x;
  int bh = bid & 31, sp = bid >> 5;
  int bb = bh >> 4, h = bh & 15;
  int tid = threadIdx.x;
  int bi = tid >> 4, bj = tid & 15;
  int row = sp*16 + bi;
  int j0 = bj*4;
  float S[4];
  {
    const float* s0p = S0 + (size_t)bh*4096 + row*64 + j0;
    S[0]=s0p[0]; S[1]=s0p[1]; S[2]=s0p[2]; S[3]=s0p[3];
  }
  const float* bases[6] = {decay, Ak, Bk, kfin, r_, vfin};
  const size_t lda[6] = {Cc, Cc, Cc, Cc, BIGN, Cc};   // r comes from bigOut
  size_t rowbase = (size_t)bb*Tt;
  int st = tid >> 4, e = (tid & 15)*4;
  float4 regs[6];
  #pragma unroll
  for (int arr=0; arr<6; ++arr)
    regs[arr] = *(const float4*)(bases[arr] + (rowbase + st)*lda[arr] + h*64 + e);
  #pragma unroll
  for (int arr=0; arr<6; ++arr)
    *(float4*)&lds[0][arr][st][e] = regs[arr];
  __syncthreads();
  const int NC = Tt/CH;
  for (int ch=0; ch<NC; ++ch) {
    int cur = ch & 1;
    if (ch+1 < NC) {
      #pragma unroll
      for (int arr=0; arr<6; ++arr)
        regs[arr] = *(const float4*)(bases[arr] + (rowbase + (ch+1)*CH + st)*lda[arr] + h*64 + e);
    }
    float4 cd = *(const float4*)&lds[cur][0][0][j0];
    float4 ca = *(const float4*)&lds[cur][1][0][j0];
    float4 cb = *(const float4*)&lds[cur][2][0][j0];
    float4 ck = *(const float4*)&lds[cur][3][0][j0];
    float4 cr = *(const float4*)&lds[cur][4][0][j0];
    float  cv = lds[cur][5][0][row];
    #pragma unroll
    for (int s=0; s<CH; ++s) {
      float4 nd, na, nb, nk, nr; float nv;
      if (s+1 < CH) {
        nd = *(const float4*)&lds[cur][0][s+1][j0];
        na = *(const float4*)&lds[cur][1][s+1][j0];
        nb = *(const float4*)&lds[cur][2][s+1][j0];
        nk = *(const float4*)&lds[cur][3][s+1][j0];
        nr = *(const float4*)&lds[cur][4][s+1][j0];
        nv = lds[cur][5][s+1][row];
      }
      S[0]*=cd.x; S[1]*=cd.y; S[2]*=cd.z; S[3]*=cd.w;
      float sa = S[0]*ca.x;
      sa = fmaf(S[1], ca.y, sa);
      sa = fmaf(S[2], ca.z, sa);
      sa = fmaf(S[3], ca.w, sa);
      sa = red16(sa);
      S[0] = fmaf(cv, ck.x, S[0]); S[0] = fmaf(sa, cb.x, S[0]);
      S[1] = fmaf(cv, ck.y, S[1]); S[1] = fmaf(sa, cb.y, S[1]);
      S[2] = fmaf(cv, ck.z, S[2]); S[2] = fmaf(sa, cb.z, S[2]);
      S[3] = fmaf(cv, ck.w, S[3]); S[3] = fmaf(sa, cb.w, S[3]);
      float yp = S[0]*cr.x;
      yp = fmaf(S[1], cr.y, yp);
      yp = fmaf(S[2], cr.z, yp);
      yp = fmaf(S[3], cr.w, yp);
      yp = red16(yp);
      if (bj == 0)
        y[(rowbase + ch*CH + s)*Cc + h*64 + row] = yp;
      if (s+1 < CH) { cd=nd; ca=na; cb=nb; ck=nk; cr=nr; cv=nv; }
    }
    if (ch+1 < NC) {
      int nxt = cur ^ 1;
      #pragma unroll
      for (int arr=0; arr<6; ++arr)
        *(float4*)&lds[nxt][arr][st][e] = regs[arr];
    }
    __syncthreads();
  }
}

// ---------------- GroupNorm(head) + r.k.r_k bonus + *g -> bf16 ---------------
__global__ __launch_bounds__(256) void gn_kernel(
    const float* __restrict__ y, const float* __restrict__ r_,
    const float* __restrict__ kfin, const float* __restrict__ vfin,
    const float* __restrict__ g_, const float* __restrict__ lnxw,
    const float* __restrict__ lnxb, const float* __restrict__ r_k,
    u16* __restrict__ Ao) {
  int row = blockIdx.x; int tid = threadIdx.x; int c = tid*4;
  size_t off = (size_t)row*Cc + c;
  float4 y4 = *(const float4*)(y+off);
  float s = y4.x+y4.y+y4.z+y4.w;
  float q = y4.x*y4.x+y4.y*y4.y+y4.z*y4.z+y4.w*y4.w;
  s = redgrp<8>(s); q = redgrp<8>(q);
  float mu = s*(1.0f/64.0f);
  float var = q*(1.0f/64.0f) - mu*mu;
  float rn = rsqrtf(var + 64e-5f);
  float4 rr = *(const float4*)(r_ + (size_t)row*BIGN + c);
  float4 kk = *(const float4*)(kfin+off);
  float4 vv = *(const float4*)(vfin+off);
  float4 gg = *(const float4*)(g_+off);
  int h = tid >> 4; int hs = (tid & 15)*4;
  float4 rk = *(const float4*)(r_k + h*64 + hs);
  float dp = rr.x*kk.x*rk.x + rr.y*kk.y*rk.y + rr.z*kk.z*rk.z + rr.w*kk.w*rk.w;
  dp = redgrp<8>(dp);
  float4 w4 = *(const float4*)(lnxw+c);
  float4 b4 = *(const float4*)(lnxb+c);
  float o0 = (((y4.x-mu)*rn)*w4.x + b4.x + dp*vv.x) * gg.x;
  float o1 = (((y4.y-mu)*rn)*w4.y + b4.y + dp*vv.y) * gg.y;
  float o2 = (((y4.z-mu)*rn)*w4.z + b4.z + dp*vv.z) * gg.z;
  float o3 = (((y4.w-mu)*rn)*w4.w + b4.w + dp*vv.w) * gg.w;
  uint2 p = {pack_bf16(o0,o1), pack_bf16(o2,o3)};
  *(uint2*)(Ao + off) = p;
}

__global__ __launch_bounds__(256) void copy_kernel(const float* __restrict__ src,
                                                   float* __restrict__ dst) {
  size_t i = ((size_t)blockIdx.x*256 + threadIdx.x)*4;
  *(float4*)(dst+i) = *(const float4*)(src+i);
}

extern "C" void kernel_launch(void* const* d_in, const int* in_sizes, int n_in,
                              void* d_out, int out_size, void* d_ws, size_t ws_size,
                              hipStream_t stream) {
  const float* x      = (const float*)d_in[0];
  const float* vfirst = (const float*)d_in[1];
  const float* S0     = (const float*)d_in[2];
  const float* ln1w   = (const float*)d_in[3];
  const float* ln1b   = (const float*)d_in[4];
  const float* ln2w   = (const float*)d_in[5];
  const float* ln2b   = (const float*)d_in[6];
  const float* x_r    = (const float*)d_in[7];
  const float* x_w    = (const float*)d_in[8];
  const float* x_k    = (const float*)d_in[9];
  const float* x_v    = (const float*)d_in[10];
  const float* x_a    = (const float*)d_in[11];
  const float* x_g    = (const float*)d_in[12];
  const float* w0     = (const float*)d_in[13];
  const float* w1     = (const float*)d_in[14];
  const float* w2     = (const float*)d_in[15];
  const float* a0     = (const float*)d_in[16];
  const float* a1     = (const float*)d_in[17];
  const float* a2     = (const float*)d_in[18];
  const float* v0     = (const float*)d_in[19];
  const float* v1     = (const float*)d_in[20];
  const float* v2     = (const float*)d_in[21];
  const float* g1     = (const float*)d_in[22];
  const float* g2     = (const float*)d_in[23];
  const float* k_k    = (const float*)d_in[24];
  const float* k_a    = (const float*)d_in[25];
  const float* r_k    = (const float*)d_in[26];
  const float* W_r    = (const float*)d_in[27];
  const float* W_k    = (const float*)d_in[28];
  const float* W_v    = (const float*)d_in[29];
  const float* W_o    = (const float*)d_in[30];
  const float* lnxw   = (const float*)d_in[31];
  const float* lnxb   = (const float*)d_in[32];
  const float* mixk   = (const float*)d_in[33];
  const float* Wkey   = (const float*)d_in[34];
  const float* Wval   = (const float*)d_in[35];
  float* out = (float*)d_out;
  float* ws  = (float*)d_ws;
  const size_t U = (size_t)BT * Cc;
  float* u[14];
  for (int i=0;i<14;++i) u[i] = ws + i*U;

  // layout:
  // u0 = bigA bf16 [4096][2048]          [lnmix1 .. bigGEMM]; then Bk f32 [prep .. wkv]
  // u1 = BigB bf16 [3456][2048]          [pack .. bigGEMM]  ; then y f32  [wkv .. gn]
  // u2..u5 = bigOut f32 [4096][3456]     [bigGEMM .. gn]    ; u2-u3 then midb bf16
  // u6 = dw [lora2..prep], then gnb bf16 [gn..gemm_o]
  // u7 = da [lora2..prep], then Wob bf16 [cvt..gemm_o]
  // u8 = dv [lora2..prep], then xo f32   [gemm_o..gemm_val]
  // u9 = g  [lora2..gn],   then Wkeyb    [cvt..gemm_key]
  // u10 = decay [prep..wkv], then cmb bf16 [lnmix2..gemm_key]
  // u11 = kfin [prep..gn]
  // u12 = vfin [prep..gn]
  // u13 = Ak [prep..wkv], then Wvalb bf16 [cvt..gemm_val]
  u16* bigA  = (u16*)u[0];
  u16* BigB  = (u16*)u[1];
  float* bigOut = u[2];
  float* Bk  = u[0];
  float* y_  = u[1];
  u16* gnb   = (u16*)u[6];
  u16* Wob   = (u16*)u[7];
  float* xo  = u[8];
  u16* Wkeyb = (u16*)u[9];
  u16* cmb   = (u16*)u[10];
  u16* Wvalb = (u16*)u[13];
  u16* midb  = (u16*)u[2];

  dim3 b256(256);
  // pack BigB: [W | diag(mix)W] rows + transposed loras
  packW_kernel<<<Cc, b256, 0, stream>>>(W_r, x_r, BigB + (size_t)0*BIGK);
  packW_kernel<<<Cc, b256, 0, stream>>>(W_k, x_k, BigB + (size_t)1024*BIGK);
  packW_kernel<<<Cc, b256, 0, stream>>>(W_v, x_v, BigB + (size_t)2048*BIGK);
  packL_kernel<<<64,  b256, 0, stream>>>(w1, x_w, BigB, 64,  3072);
  packL_kernel<<<64,  b256, 0, stream>>>(a1, x_a, BigB, 64,  3136);
  packL_kernel<<<32,  b256, 0, stream>>>(v1, x_v, BigB, 32,  3200);
  packL_kernel<<<160, b256, 0, stream>>>(g1, x_g, BigB, 160, 3232);
  // LN1 -> [xn | xx]
  lnmix1_kernel<<<BT, b256, 0, stream>>>(x, ln1w, ln1b, bigA);
  // one big GEMM: r|k|v|loras
  gemm_bf16<0><<<dim3(BIGN/128, BT/128), b256, 0, stream>>>(bigA, BigB, bigOut, nullptr, BT, BIGN, BIGK);
  // activations on lora columns
  act_kernel<<<BT*320/256, b256, 0, stream>>>(bigOut);
  // lora stage2
  lora2_kernel<<<dim3(BT/8, Cc/256), b256, 0, stream>>>(bigOut+3072, w2, u[6], 64);
  lora2_kernel<<<dim3(BT/8, Cc/256), b256, 0, stream>>>(bigOut+3136, a2, u[7], 64);
  lora2_kernel<<<dim3(BT/8, Cc/256), b256, 0, stream>>>(bigOut+3200, v2, u[8], 32);
  lora2_kernel<<<dim3(BT/8, Cc/256), b256, 0, stream>>>(bigOut+3232, g2, u[9], 160);
  // prep
  prep_kernel<<<BT, b256, 0, stream>>>(bigOut+1024, u[6], u[7], u[8], bigOut+2048, vfirst,
      w0, a0, v0, k_k, k_a, u[10], u[11], u[12], u[13], Bk);
  // wkv scan -> y
  wkv_kernel<<<Bb*Hh*4, b256, 0, stream>>>(u[10], u[13], Bk, u[11], bigOut, u[12], S0, y_);
  // W_o -> bf16 (u7; da dead)
  cvt_kernel<<<Cc*Cc/2048, b256, 0, stream>>>(W_o, Wob);
  // groupnorm + bonus + *g -> gnb (u6; dw dead)
  gn_kernel<<<BT, b256, 0, stream>>>(y_, bigOut, u[11], u[12], u[9], lnxw, lnxb, r_k, gnb);
  // W_key -> bf16 (u9; g dead after gn)
  cvt_kernel<<<FFNd*Cc/2048, b256, 0, stream>>>(Wkey, Wkeyb);
  // output projection + residual -> xo (u8; dv dead)
  gemm_bf16<1><<<dim3(Cc/128, BT/128), b256, 0, stream>>>(gnb, Wob, xo, x, BT, Cc, Cc);
  // LN2 + cmix -> cmb (u10; decay dead)
  lnmix2_kernel<<<BT, b256, 0, stream>>>(xo, ln2w, ln2b, mixk, cmb);
  // W_val -> bf16 (u13; Ak dead)
  cvt_kernel<<<Cc*FFNd/2048, b256, 0, stream>>>(Wval, Wvalb);
  // FFN key: relu^2 -> bf16 mid (u2-u3; bigOut dead after gn)
  gemm_bf16<2><<<dim3(FFNd/128, BT/128), b256, 0, stream>>>(cmb, Wkeyb, midb, nullptr, BT, FFNd, Cc);
  // FFN val + residual -> out
  gemm_bf16<1><<<dim3(Cc/128, BT/128), b256, 0, stream>>>(midb, Wvalb, out, xo, BT, Cc, FFNd);
  // v_first passthrough
  copy_kernel<<<BT*Cc/1024, b256, 0, stream>>>(vfirst, out + (size_t)BT*Cc);
}

// Round 4
// 861.288 us; speedup vs baseline: 4.0609x; 1.1365x over previous
//
#include <hip/hip_runtime.h>
#include <math.h>

#define Bb 2
#define Tt 2048
#define Cc 1024
#define Hh 16
#define BT 4096
#define FFNd 4096
#define CH 16
#define BIGN 3456
#define BIGK 2048
// big-B column layout: r@0 k@1024 v@2048 w@3072 a@3136 vl@3200 g@3232 (end 3392, pad->3456)

typedef __attribute__((ext_vector_type(8))) short bf16x8;
typedef __attribute__((ext_vector_type(4))) float f32x4;
typedef unsigned short u16;

__device__ __forceinline__ float sgm(float x){ return 1.0f/(1.0f+expf(-x)); }

template<int MAXM>
__device__ __forceinline__ float redgrp(float v){
  #pragma unroll
  for (int m=1; m<=MAXM; m<<=1) v += __shfl_xor(v, m, 64);
  return v;
}

template<int CTRL>
__device__ __forceinline__ float dppadd(float v){
  union { float f; int i; } u, r;
  u.f = v;
  r.i = __builtin_amdgcn_update_dpp(u.i, u.i, CTRL, 0xf, 0xf, true);
  return v + r.f;
}
__device__ __forceinline__ float red16(float v){
  v = dppadd<0xB1>(v);
  v = dppadd<0x4E>(v);
  v = dppadd<0x141>(v);
  v = dppadd<0x140>(v);
  return v;
}

__device__ __forceinline__ unsigned pack_bf16(float a, float b){
  unsigned ua = __builtin_bit_cast(unsigned, a);
  unsigned ub = __builtin_bit_cast(unsigned, b);
  ua = (ua + 0x7FFFu + ((ua>>16)&1u)) >> 16;
  ub = (ub + 0x7FFFu + ((ub>>16)&1u)) >> 16;
  return ua | (ub<<16);
}
__device__ __forceinline__ u16 bf16_1(float a){
  unsigned ua = __builtin_bit_cast(unsigned, a);
  return (u16)((ua + 0x7FFFu + ((ua>>16)&1u)) >> 16);
}

__device__ __forceinline__ void gload16(const void* g, void* l){
  __builtin_amdgcn_global_load_lds(
    (const __attribute__((address_space(1))) unsigned int*)g,
    (__attribute__((address_space(3))) unsigned int*)l, 16, 0, 0);
}

// ---------------- f32 -> bf16 convert (weights) -------------------------------
__global__ __launch_bounds__(256) void cvt_kernel(const float* __restrict__ in,
    u16* __restrict__ out) {
  size_t i = (size_t)blockIdx.x*256 + threadIdx.x;
  float4 a = ((const float4*)in)[2*i];
  float4 b = ((const float4*)in)[2*i+1];
  uint4 o = {pack_bf16(a.x,a.y), pack_bf16(a.z,a.w),
             pack_bf16(b.x,b.y), pack_bf16(b.z,b.w)};
  ((uint4*)out)[i] = o;
}

// ---------------- pack square weights into BigB rows: [W | diag(mix)W] -------
__global__ __launch_bounds__(256) void packW_kernel(const float* __restrict__ Wr,
    const float* __restrict__ Wk, const float* __restrict__ Wv,
    const float* __restrict__ xr, const float* __restrict__ xk,
    const float* __restrict__ xv, u16* __restrict__ out) {
  int which = blockIdx.y;
  const float* W   = which==0 ? Wr : (which==1 ? Wk : Wv);
  const float* mix = which==0 ? xr : (which==1 ? xk : xv);
  u16* o = out + (size_t)which*1024*BIGK;
  int n = blockIdx.x;             // 0..1023
  int c0 = threadIdx.x*8;         // 0..2040
  int ks = c0 & 1023;
  const float* src = W + (size_t)n*Cc + ks;
  float4 a = *(const float4*)src;
  float4 b = *(const float4*)(src+4);
  if (c0 >= 1024){
    float4 m0 = *(const float4*)(mix + ks);
    float4 m1 = *(const float4*)(mix + ks + 4);
    a.x*=m0.x; a.y*=m0.y; a.z*=m0.z; a.w*=m0.w;
    b.x*=m1.x; b.y*=m1.y; b.z*=m1.z; b.w*=m1.w;
  }
  uint4 ov = {pack_bf16(a.x,a.y), pack_bf16(a.z,a.w),
              pack_bf16(b.x,b.y), pack_bf16(b.z,b.w)};
  *(uint4*)(o + (size_t)n*BIGK + c0) = ov;
}

// ---------------- pack lora W1[C,D] (transposed) into BigB rows --------------
__global__ __launch_bounds__(256) void packL_kernel(const float* __restrict__ w1,
    const float* __restrict__ a1, const float* __restrict__ v1,
    const float* __restrict__ g1, const float* __restrict__ x_w,
    const float* __restrict__ x_a, const float* __restrict__ x_v,
    const float* __restrict__ x_g, u16* __restrict__ out) {
  int bid = blockIdx.x;           // 0..319
  const float* W1; const float* mix; int D, d, nbase;
  if (bid < 64)       { W1=w1; mix=x_w; D=64;  d=bid;     nbase=3072; }
  else if (bid < 128) { W1=a1; mix=x_a; D=64;  d=bid-64;  nbase=3136; }
  else if (bid < 160) { W1=v1; mix=x_v; D=32;  d=bid-128; nbase=3200; }
  else                { W1=g1; mix=x_g; D=160; d=bid-160; nbase=3232; }
  int k0 = threadIdx.x*8;
  float v[8];
  #pragma unroll
  for (int q=0;q<8;++q){
    int kk = k0+q;
    int ks = kk & 1023;
    float t = W1[(size_t)ks*D + d];
    if (kk >= 1024) t *= mix[ks];
    v[q] = t;
  }
  uint4 o = {pack_bf16(v[0],v[1]), pack_bf16(v[2],v[3]),
             pack_bf16(v[4],v[5]), pack_bf16(v[6],v[7])};
  *(uint4*)(out + (size_t)(nbase+d)*BIGK + k0) = o;
}

// ---------------- fused LN1 -> bigA = [xn | xx] bf16 -------------------------
__global__ __launch_bounds__(256) void lnmix1_kernel(const float* __restrict__ x,
    const float* __restrict__ w, const float* __restrict__ b,
    u16* __restrict__ bigA) {
  int rowg = blockIdx.x; int t = rowg & (Tt-1);
  int tid = threadIdx.x;
  size_t off = (size_t)rowg*Cc + tid*4;
  float4 vc = *(const float4*)(x + off);
  float4 vp = {0.f,0.f,0.f,0.f};
  if (t) vp = *(const float4*)(x + off - Cc);
  float sc = vc.x+vc.y+vc.z+vc.w;
  float qc = vc.x*vc.x+vc.y*vc.y+vc.z*vc.z+vc.w*vc.w;
  float sp = vp.x+vp.y+vp.z+vp.w;
  float qp = vp.x*vp.x+vp.y*vp.y+vp.z*vp.z+vp.w*vp.w;
  sc = redgrp<32>(sc); qc = redgrp<32>(qc);
  sp = redgrp<32>(sp); qp = redgrp<32>(qp);
  __shared__ float rbuf[4][4];
  int lane = tid & 63, wv = tid >> 6;
  if (lane==0){ rbuf[wv][0]=sc; rbuf[wv][1]=qc; rbuf[wv][2]=sp; rbuf[wv][3]=qp; }
  __syncthreads();
  sc = rbuf[0][0]+rbuf[1][0]+rbuf[2][0]+rbuf[3][0];
  qc = rbuf[0][1]+rbuf[1][1]+rbuf[2][1]+rbuf[3][1];
  sp = rbuf[0][2]+rbuf[1][2]+rbuf[2][2]+rbuf[3][2];
  qp = rbuf[0][3]+rbuf[1][3]+rbuf[2][3]+rbuf[3][3];
  float muc = sc*(1.0f/Cc), mup = sp*(1.0f/Cc);
  float rnc = rsqrtf(qc*(1.0f/Cc) - muc*muc + 1e-5f);
  float rnp = rsqrtf(qp*(1.0f/Cc) - mup*mup + 1e-5f);
  float4 w4 = *(const float4*)(w + tid*4);
  float4 b4 = *(const float4*)(b + tid*4);
  float vcl[4]={vc.x,vc.y,vc.z,vc.w};
  float vpl[4]={vp.x,vp.y,vp.z,vp.w};
  float wl[4]={w4.x,w4.y,w4.z,w4.w};
  float bl[4]={b4.x,b4.y,b4.z,b4.w};
  float xnc[4], xx[4];
  #pragma unroll
  for (int q=0;q<4;++q){
    xnc[q] = (vcl[q]-muc)*rnc*wl[q] + bl[q];
    float xnp = t ? ((vpl[q]-mup)*rnp*wl[q] + bl[q]) : 0.0f;
    xx[q] = xnp - xnc[q];
  }
  size_t ab = (size_t)rowg*BIGK + tid*4;
  uint2 p0 = {pack_bf16(xnc[0],xnc[1]), pack_bf16(xnc[2],xnc[3])};
  uint2 p1 = {pack_bf16(xx[0],xx[1]),   pack_bf16(xx[2],xx[3])};
  *(uint2*)(bigA + ab) = p0;
  *(uint2*)(bigA + ab + 1024) = p1;
}

// ---------------- fused LN2 + cmix -> bf16 -----------------------------------
__global__ __launch_bounds__(256) void lnmix2_kernel(const float* __restrict__ x,
    const float* __restrict__ w, const float* __restrict__ b,
    const float* __restrict__ mixk, u16* __restrict__ outb) {
  int rowg = blockIdx.x; int t = rowg & (Tt-1);
  int tid = threadIdx.x;
  size_t off = (size_t)rowg*Cc + tid*4;
  float4 vc = *(const float4*)(x + off);
  float4 vp = {0.f,0.f,0.f,0.f};
  if (t) vp = *(const float4*)(x + off - Cc);
  float sc = vc.x+vc.y+vc.z+vc.w;
  float qc = vc.x*vc.x+vc.y*vc.y+vc.z*vc.z+vc.w*vc.w;
  float sp = vp.x+vp.y+vp.z+vp.w;
  float qp = vp.x*vp.x+vp.y*vp.y+vp.z*vp.z+vp.w*vp.w;
  sc = redgrp<32>(sc); qc = redgrp<32>(qc);
  sp = redgrp<32>(sp); qp = redgrp<32>(qp);
  __shared__ float rbuf[4][4];
  int lane = tid & 63, wv = tid >> 6;
  if (lane==0){ rbuf[wv][0]=sc; rbuf[wv][1]=qc; rbuf[wv][2]=sp; rbuf[wv][3]=qp; }
  __syncthreads();
  sc = rbuf[0][0]+rbuf[1][0]+rbuf[2][0]+rbuf[3][0];
  qc = rbuf[0][1]+rbuf[1][1]+rbuf[2][1]+rbuf[3][1];
  sp = rbuf[0][2]+rbuf[1][2]+rbuf[2][2]+rbuf[3][2];
  qp = rbuf[0][3]+rbuf[1][3]+rbuf[2][3]+rbuf[3][3];
  float muc = sc*(1.0f/Cc), mup = sp*(1.0f/Cc);
  float rnc = rsqrtf(qc*(1.0f/Cc) - muc*muc + 1e-5f);
  float rnp = rsqrtf(qp*(1.0f/Cc) - mup*mup + 1e-5f);
  float4 w4 = *(const float4*)(w + tid*4);
  float4 b4 = *(const float4*)(b + tid*4);
  float4 m = *(const float4*)(mixk + tid*4);
  float vcl[4]={vc.x,vc.y,vc.z,vc.w};
  float vpl[4]={vp.x,vp.y,vp.z,vp.w};
  float wl[4]={w4.x,w4.y,w4.z,w4.w};
  float bl[4]={b4.x,b4.y,b4.z,b4.w};
  float ml[4]={m.x,m.y,m.z,m.w};
  float o[4];
  #pragma unroll
  for (int q=0;q<4;++q){
    float xnc = (vcl[q]-muc)*rnc*wl[q] + bl[q];
    float xnp = t ? ((vpl[q]-mup)*rnp*wl[q] + bl[q]) : 0.0f;
    o[q] = xnc + (xnp - xnc)*ml[q];
  }
  uint2 p = {pack_bf16(o[0],o[1]), pack_bf16(o[2],o[3])};
  *(uint2*)(outb + off) = p;
}

// ================= bf16 GEMM (m97 structure): out = A[M,K] @ W[N,K]^T ========
// MODE 0: f32 out   1: f32 out = res + acc   2: bf16 out = relu(acc)^2
template<int MODE>
__global__ __launch_bounds__(256) void gemm_bf16(const u16* __restrict__ A,
    const u16* __restrict__ W, void* __restrict__ outv,
    const float* __restrict__ res, int M, int N, int K) {
  __shared__ u16 As[2][128*64];
  __shared__ u16 Bs[2][128*64];
  int tid = threadIdx.x;
  int bm = blockIdx.y, bn = blockIdx.x;
  int wave = tid >> 6, lane = tid & 63;
  int wm = wave >> 1, wn = wave & 1;
  int srow = wave*32 + (lane>>3);
  int scol = (lane&7)*8;
  const u16* Ag = A + (size_t)(bm*128 + srow)*K + scol;
  const u16* Wg = W + (size_t)(bn*128 + srow)*K + scol;
  int nt = K >> 6;
  f32x4 acc[4][4];
  f32x4 zero = {0.f,0.f,0.f,0.f};
  #pragma unroll
  for (int i=0;i<4;++i)
    #pragma unroll
    for (int j=0;j<4;++j) acc[i][j] = zero;

  #define STAGE(buf, t) { \
    const u16* Ag2 = Ag + (size_t)(t)*64; \
    const u16* Wg2 = Wg + (size_t)(t)*64; \
    _Pragma("unroll") \
    for (int i_=0;i_<4;++i_){ \
      gload16(Ag2 + (size_t)i_*8*K, &As[buf][(wave*32+i_*8)*64]); \
      gload16(Wg2 + (size_t)i_*8*K, &Bs[buf][(wave*32+i_*8)*64]); \
    } }

  STAGE(0, 0);
  asm volatile("s_waitcnt vmcnt(0)" ::: "memory");
  __syncthreads();
  int lrow = lane & 15, lk8 = lane >> 4;
  for (int t = 0; t < nt; ++t) {
    int cur = t & 1;
    if (t+1 < nt) STAGE(cur^1, t+1);
    #pragma unroll
    for (int kk2 = 0; kk2 < 2; ++kk2) {
      bf16x8 af[4], bfr[4];
      #pragma unroll
      for (int i=0;i<4;++i)
        af[i] = *(const bf16x8*)&As[cur][(wm*64 + i*16 + lrow)*64 + kk2*32 + lk8*8];
      #pragma unroll
      for (int j=0;j<4;++j)
        bfr[j] = *(const bf16x8*)&Bs[cur][(wn*64 + j*16 + lrow)*64 + kk2*32 + lk8*8];
      #pragma unroll
      for (int i=0;i<4;++i)
        #pragma unroll
        for (int j=0;j<4;++j)
          acc[i][j] = __builtin_amdgcn_mfma_f32_16x16x32_bf16(af[i], bfr[j], acc[i][j], 0, 0, 0);
    }
    if (t+1 < nt) { asm volatile("s_waitcnt vmcnt(0)" ::: "memory"); }
    __syncthreads();
  }
  #undef STAGE
  float* outf = (float*)outv;
  u16* outb = (u16*)outv;
  int crow4 = (lane>>4)*4, ccol = lane & 15;
  #pragma unroll
  for (int i=0;i<4;++i){
    #pragma unroll
    for (int j=0;j<4;++j){
      int gr = bm*128 + wm*64 + i*16 + crow4;
      int gc = bn*128 + wn*64 + j*16 + ccol;
      #pragma unroll
      for (int q=0;q<4;++q){
        float v = acc[i][j][q];
        size_t o = (size_t)(gr+q)*N + gc;
        if (MODE==1) { v += res[o]; outf[o] = v; }
        else if (MODE==2) { v = fmaxf(v, 0.f); outb[o] = bf16_1(v*v); }
        else outf[o] = v;
      }
    }
  }
}

// ---------------- activation pass over lora columns of bigOut ----------------
__global__ __launch_bounds__(256) void act_kernel(float* __restrict__ m) {
  int idx = blockIdx.x*256 + threadIdx.x;      // BT*320
  int i = idx / 320, cc = idx - i*320;
  size_t o = (size_t)i*BIGN + 3072 + cc;
  float v = m[o];
  if (cc < 64) v = tanhf(v);
  else if (cc >= 160) v = sgm(v);
  m[o] = v;
}

// ---------------- LoRA stage2: out[i,c] = sum_d T[i,d] W2[d,c] ---------------
__global__ __launch_bounds__(256) void lora2_kernel(const float* __restrict__ Tm,
    const float* __restrict__ W2, float* __restrict__ out, int D) {
  int i0 = blockIdx.x*8;
  int c = blockIdx.y*256 + threadIdx.x;
  float acc[8] = {};
  for (int d=0; d<D; ++d) {
    float wv = W2[(size_t)d*Cc + c];
    #pragma unroll
    for (int r=0;r<8;++r) acc[r] = fmaf(Tm[(size_t)(i0+r)*BIGN + d], wv, acc[r]);
  }
  #pragma unroll
  for (int r=0;r<8;++r) out[(size_t)(i0+r)*Cc + c] = acc[r];
}

// ---------------- prep (k/v read from bigOut views, ld=BIGN) -----------------
__global__ __launch_bounds__(256) void prep_kernel(
    const float* __restrict__ kraw, const float* __restrict__ dw,
    const float* __restrict__ da, const float* __restrict__ dv,
    const float* __restrict__ vraw, const float* __restrict__ vfirst,
    const float* __restrict__ w0, const float* __restrict__ a0,
    const float* __restrict__ v0, const float* __restrict__ k_k,
    const float* __restrict__ k_a,
    float* __restrict__ decay, float* __restrict__ kfin, float* __restrict__ vfin,
    float* __restrict__ Ak, float* __restrict__ Bk) {
  int row = blockIdx.x; int tid = threadIdx.x; int c = tid*4;
  size_t off = (size_t)row*Cc + c;
  size_t offw = (size_t)row*BIGN + c;
  float4 kr = *(const float4*)(kraw+offw);
  float4 vr = *(const float4*)(vraw+offw);
  float4 w4 = *(const float4*)(dw+off);
  float4 A4 = *(const float4*)(da+off);
  float4 V4 = *(const float4*)(dv+off);
  float4 vf = *(const float4*)(vfirst+off);
  float4 w04 = *(const float4*)(w0+c);
  float4 a04 = *(const float4*)(a0+c);
  float4 v04 = *(const float4*)(v0+c);
  float4 kk4 = *(const float4*)(k_k+c);
  float4 ka4 = *(const float4*)(k_a+c);
  float krl[4]={kr.x,kr.y,kr.z,kr.w};
  float dwl[4]={w4.x,w4.y,w4.z,w4.w};
  float dal[4]={A4.x,A4.y,A4.z,A4.w};
  float dvl[4]={V4.x,V4.y,V4.z,V4.w};
  float vrl[4]={vr.x,vr.y,vr.z,vr.w};
  float vfl[4]={vf.x,vf.y,vf.z,vf.w};
  float w0l[4]={w04.x,w04.y,w04.z,w04.w};
  float a0l[4]={a04.x,a04.y,a04.z,a04.w};
  float v0l[4]={v04.x,v04.y,v04.z,v04.w};
  float kkl[4]={kk4.x,kk4.y,kk4.z,kk4.w};
  float kal[4]={ka4.x,ka4.y,ka4.z,ka4.w};
  float av[4], dec[4], vv[4], kp[4], kf[4];
  float ss = 0.f;
  #pragma unroll
  for (int q=0;q<4;++q){
    av[q] = sgm(a0l[q] + dal[q]);
    dec[q] = 0.60653065971263342f * sgm(w0l[q] + dwl[q]);   // exp(-softplus(-u)-0.5)
    float sv = sgm(v0l[q] + dvl[q]);
    vv[q] = vrl[q] + (vfl[q]-vrl[q])*sv;
    kp[q] = krl[q]*kkl[q];
    ss += kp[q]*kp[q];
    kf[q] = krl[q]*(1.0f + (av[q]-1.0f)*kal[q]);
  }
  ss = redgrp<8>(ss);
  float inv = 1.0f / fmaxf(sqrtf(ss), 1e-12f);
  float4 o;
  o.x=dec[0];o.y=dec[1];o.z=dec[2];o.w=dec[3];  *(float4*)(decay+off)=o;
  o.x=kf[0]; o.y=kf[1]; o.z=kf[2]; o.w=kf[3];   *(float4*)(kfin+off)=o;
  o.x=vv[0]; o.y=vv[1]; o.z=vv[2]; o.w=vv[3];   *(float4*)(vfin+off)=o;
  o.x=-kp[0]*inv; o.y=-kp[1]*inv; o.z=-kp[2]*inv; o.w=-kp[3]*inv; *(float4*)(Ak+off)=o;
  o.x=kp[0]*inv*av[0]; o.y=kp[1]*inv*av[1]; o.z=kp[2]*inv*av[2]; o.w=kp[3]*inv*av[3];
  *(float4*)(Bk+off)=o;
}

// ------ WKV-7 scan: 256 blocks (32 bh x 8 splits, XCD-grouped), 128 thr ------
__global__ __launch_bounds__(128) void wkv_kernel(
    const float* __restrict__ decay, const float* __restrict__ Ak,
    const float* __restrict__ Bk, const float* __restrict__ kfin,
    const float* __restrict__ r_, const float* __restrict__ vfin,
    const float* __restrict__ S0, float* __restrict__ y) {
  __shared__ float lds[2][6][CH][64];
  int bid = blockIdx.x;
  // XCD-grouped: blocks with same (bid&7) land on one XCD; give each XCD 4 bh x 8 sp
  int c8 = bid & 7, idx = bid >> 3;
  int bh = c8*4 + (idx & 3);
  int sp = idx >> 2;                 // 0..7
  int bb = bh >> 4, h = bh & 15;
  int tid = threadIdx.x;
  int wave = tid >> 6, lane = tid & 63;
  int bi = lane >> 4, bj = lane & 15;
  int row = sp*8 + wave*4 + bi;      // 0..63
  int j0 = bj*4;
  float S[4];
  {
    const float* s0p = S0 + (size_t)bh*4096 + row*64 + j0;
    S[0]=s0p[0]; S[1]=s0p[1]; S[2]=s0p[2]; S[3]=s0p[3];
  }
  size_t rowbase = (size_t)bb*Tt;
  int lhi = lane >> 4, llo4 = (lane & 15)*4;

  // one array's 16 steps: 4 x gload16; LDS dest = uniform base + lane*16
  #define WST1(buf, chn, arr, base, ldv) { \
    const float* gp_ = (base) + (size_t)((rowbase + (size_t)(chn)*CH + lhi))*(ldv) + h*64 + llo4; \
    _Pragma("unroll") \
    for (int p_=0; p_<4; ++p_) \
      gload16(gp_ + (size_t)p_*4*(ldv), &lds[buf][arr][p_*4][0]); }
  #define WSTAGE(buf, chn) { \
    if (wave == 0) { \
      WST1(buf, chn, 0, decay, Cc); WST1(buf, chn, 1, Ak, Cc); WST1(buf, chn, 2, Bk, Cc); \
    } else { \
      WST1(buf, chn, 3, kfin, Cc); WST1(buf, chn, 4, r_, BIGN); WST1(buf, chn, 5, vfin, Cc); \
    } }

  WSTAGE(0, 0);
  asm volatile("s_waitcnt vmcnt(0)" ::: "memory");
  __syncthreads();
  const int NC = Tt/CH;
  for (int ch=0; ch<NC; ++ch) {
    int cur = ch & 1;
    if (ch+1 < NC) WSTAGE(cur^1, ch+1);
    float4 cd = *(const float4*)&lds[cur][0][0][j0];
    float4 ca = *(const float4*)&lds[cur][1][0][j0];
    float4 cb = *(const float4*)&lds[cur][2][0][j0];
    float4 ck = *(const float4*)&lds[cur][3][0][j0];
    float4 cr = *(const float4*)&lds[cur][4][0][j0];
    float  cv = lds[cur][5][0][row];
    #pragma unroll
    for (int s=0; s<CH; ++s) {
      float4 nd, na, nb, nk, nr; float nv;
      if (s+1 < CH) {
        nd = *(const float4*)&lds[cur][0][s+1][j0];
        na = *(const float4*)&lds[cur][1][s+1][j0];
        nb = *(const float4*)&lds[cur][2][s+1][j0];
        nk = *(const float4*)&lds[cur][3][s+1][j0];
        nr = *(const float4*)&lds[cur][4][s+1][j0];
        nv = lds[cur][5][s+1][row];
      }
      S[0]*=cd.x; S[1]*=cd.y; S[2]*=cd.z; S[3]*=cd.w;
      float sa = S[0]*ca.x;
      sa = fmaf(S[1], ca.y, sa);
      sa = fmaf(S[2], ca.z, sa);
      sa = fmaf(S[3], ca.w, sa);
      sa = red16(sa);
      S[0] = fmaf(cv, ck.x, S[0]); S[0] = fmaf(sa, cb.x, S[0]);
      S[1] = fmaf(cv, ck.y, S[1]); S[1] = fmaf(sa, cb.y, S[1]);
      S[2] = fmaf(cv, ck.z, S[2]); S[2] = fmaf(sa, cb.z, S[2]);
      S[3] = fmaf(cv, ck.w, S[3]); S[3] = fmaf(sa, cb.w, S[3]);
      float yp = S[0]*cr.x;
      yp = fmaf(S[1], cr.y, yp);
      yp = fmaf(S[2], cr.z, yp);
      yp = fmaf(S[3], cr.w, yp);
      yp = red16(yp);
      if (bj == 0)
        y[(rowbase + ch*CH + s)*Cc + h*64 + row] = yp;
      if (s+1 < CH) { cd=nd; ca=na; cb=nb; ck=nk; cr=nr; cv=nv; }
    }
    if (ch+1 < NC) { asm volatile("s_waitcnt vmcnt(0)" ::: "memory"); }
    __syncthreads();
  }
  #undef WSTAGE
  #undef WST1
}

// ---------------- GroupNorm(head) + r.k.r_k bonus + *g -> bf16 ---------------
__global__ __launch_bounds__(256) void gn_kernel(
    const float* __restrict__ y, const float* __restrict__ r_,
    const float* __restrict__ kfin, const float* __restrict__ vfin,
    const float* __restrict__ g_, const float* __restrict__ lnxw,
    const float* __restrict__ lnxb, const float* __restrict__ r_k,
    u16* __restrict__ Ao) {
  int row = blockIdx.x; int tid = threadIdx.x; int c = tid*4;
  size_t off = (size_t)row*Cc + c;
  float4 y4 = *(const float4*)(y+off);
  float s = y4.x+y4.y+y4.z+y4.w;
  float q = y4.x*y4.x+y4.y*y4.y+y4.z*y4.z+y4.w*y4.w;
  s = redgrp<8>(s); q = redgrp<8>(q);
  float mu = s*(1.0f/64.0f);
  float var = q*(1.0f/64.0f) - mu*mu;
  float rn = rsqrtf(var + 64e-5f);
  float4 rr = *(const float4*)(r_ + (size_t)row*BIGN + c);
  float4 kk = *(const float4*)(kfin+off);
  float4 vv = *(const float4*)(vfin+off);
  float4 gg = *(const float4*)(g_+off);
  int h = tid >> 4; int hs = (tid & 15)*4;
  float4 rk = *(const float4*)(r_k + h*64 + hs);
  float dp = rr.x*kk.x*rk.x + rr.y*kk.y*rk.y + rr.z*kk.z*rk.z + rr.w*kk.w*rk.w;
  dp = redgrp<8>(dp);
  float4 w4 = *(const float4*)(lnxw+c);
  float4 b4 = *(const float4*)(lnxb+c);
  float o0 = (((y4.x-mu)*rn)*w4.x + b4.x + dp*vv.x) * gg.x;
  float o1 = (((y4.y-mu)*rn)*w4.y + b4.y + dp*vv.y) * gg.y;
  float o2 = (((y4.z-mu)*rn)*w4.z + b4.z + dp*vv.z) * gg.z;
  float o3 = (((y4.w-mu)*rn)*w4.w + b4.w + dp*vv.w) * gg.w;
  uint2 p = {pack_bf16(o0,o1), pack_bf16(o2,o3)};
  *(uint2*)(Ao + off) = p;
}

__global__ __launch_bounds__(256) void copy_kernel(const float* __restrict__ src,
                                                   float* __restrict__ dst) {
  size_t i = ((size_t)blockIdx.x*256 + threadIdx.x)*4;
  *(float4*)(dst+i) = *(const float4*)(src+i);
}

extern "C" void kernel_launch(void* const* d_in, const int* in_sizes, int n_in,
                              void* d_out, int out_size, void* d_ws, size_t ws_size,
                              hipStream_t stream) {
  const float* x      = (const float*)d_in[0];
  const float* vfirst = (const float*)d_in[1];
  const float* S0     = (const float*)d_in[2];
  const float* ln1w   = (const float*)d_in[3];
  const float* ln1b   = (const float*)d_in[4];
  const float* ln2w   = (const float*)d_in[5];
  const float* ln2b   = (const float*)d_in[6];
  const float* x_r    = (const float*)d_in[7];
  const float* x_w    = (const float*)d_in[8];
  const float* x_k    = (const float*)d_in[9];
  const float* x_v    = (const float*)d_in[10];
  const float* x_a    = (const float*)d_in[11];
  const float* x_g    = (const float*)d_in[12];
  const float* w0     = (const float*)d_in[13];
  const float* w1     = (const float*)d_in[14];
  const float* w2     = (const float*)d_in[15];
  const float* a0     = (const float*)d_in[16];
  const float* a1     = (const float*)d_in[17];
  const float* a2     = (const float*)d_in[18];
  const float* v0     = (const float*)d_in[19];
  const float* v1     = (const float*)d_in[20];
  const float* v2     = (const float*)d_in[21];
  const float* g1     = (const float*)d_in[22];
  const float* g2     = (const float*)d_in[23];
  const float* k_k    = (const float*)d_in[24];
  const float* k_a    = (const float*)d_in[25];
  const float* r_k    = (const float*)d_in[26];
  const float* W_r    = (const float*)d_in[27];
  const float* W_k    = (const float*)d_in[28];
  const float* W_v    = (const float*)d_in[29];
  const float* W_o    = (const float*)d_in[30];
  const float* lnxw   = (const float*)d_in[31];
  const float* lnxb   = (const float*)d_in[32];
  const float* mixk   = (const float*)d_in[33];
  const float* Wkey   = (const float*)d_in[34];
  const float* Wval   = (const float*)d_in[35];
  float* out = (float*)d_out;
  float* ws  = (float*)d_ws;
  const size_t U = (size_t)BT * Cc;
  float* u[14];
  for (int i=0;i<14;++i) u[i] = ws + i*U;

  u16* bigA  = (u16*)u[0];
  u16* BigB  = (u16*)u[1];
  float* bigOut = u[2];
  float* Bk  = u[0];
  float* y_  = u[1];
  u16* gnb   = (u16*)u[6];
  u16* Wob   = (u16*)u[7];
  float* xo  = u[8];
  u16* Wkeyb = (u16*)u[9];
  u16* cmb   = (u16*)u[10];
  u16* Wvalb = (u16*)u[13];
  u16* midb  = (u16*)u[2];

  dim3 b256(256);
  packW_kernel<<<dim3(Cc,3), b256, 0, stream>>>(W_r, W_k, W_v, x_r, x_k, x_v, BigB);
  packL_kernel<<<320, b256, 0, stream>>>(w1, a1, v1, g1, x_w, x_a, x_v, x_g, BigB);
  lnmix1_kernel<<<BT, b256, 0, stream>>>(x, ln1w, ln1b, bigA);
  gemm_bf16<0><<<dim3(BIGN/128, BT/128), b256, 0, stream>>>(bigA, BigB, bigOut, nullptr, BT, BIGN, BIGK);
  act_kernel<<<BT*320/256, b256, 0, stream>>>(bigOut);
  lora2_kernel<<<dim3(BT/8, Cc/256), b256, 0, stream>>>(bigOut+3072, w2, u[6], 64);
  lora2_kernel<<<dim3(BT/8, Cc/256), b256, 0, stream>>>(bigOut+3136, a2, u[7], 64);
  lora2_kernel<<<dim3(BT/8, Cc/256), b256, 0, stream>>>(bigOut+3200, v2, u[8], 32);
  lora2_kernel<<<dim3(BT/8, Cc/256), b256, 0, stream>>>(bigOut+3232, g2, u[9], 160);
  prep_kernel<<<BT, b256, 0, stream>>>(bigOut+1024, u[6], u[7], u[8], bigOut+2048, vfirst,
      w0, a0, v0, k_k, k_a, u[10], u[11], u[12], u[13], Bk);
  wkv_kernel<<<256, dim3(128), 0, stream>>>(u[10], u[13], Bk, u[11], bigOut, u[12], S0, y_);
  cvt_kernel<<<Cc*Cc/2048, b256, 0, stream>>>(W_o, Wob);
  gn_kernel<<<BT, b256, 0, stream>>>(y_, bigOut, u[11], u[12], u[9], lnxw, lnxb, r_k, gnb);
  cvt_kernel<<<FFNd*Cc/2048, b256, 0, stream>>>(Wkey, Wkeyb);
  gemm_bf16<1><<<dim3(Cc/128, BT/128), b256, 0, stream>>>(gnb, Wob, xo, x, BT, Cc, Cc);
  lnmix2_kernel<<<BT, b256, 0, stream>>>(xo, ln2w, ln2b, mixk, cmb);
  cvt_kernel<<<Cc*FFNd/2048, b256, 0, stream>>>(Wval, Wvalb);
  gemm_bf16<2><<<dim3(FFNd/128, BT/128), b256, 0, stream>>>(cmb, Wkeyb, midb, nullptr, BT, FFNd, Cc);
  gemm_bf16<1><<<dim3(Cc/128, BT/128), b256, 0, stream>>>(midb, Wvalb, out, xo, BT, Cc, FFNd);
  copy_kernel<<<BT*Cc/1024, b256, 0, stream>>>(vfirst, out + (size_t)BT*Cc);
}

// Round 5
// 716.025 us; speedup vs baseline: 4.8847x; 1.2029x over previous
//
#include <hip/hip_runtime.h>
#include <math.h>

#define Bb 2
#define Tt 2048
#define Cc 1024
#define Hh 16
#define BT 4096
#define FFNd 4096
#define CH 16
#define BIGN 3456
#define BIGK 2048
#define LORAK 320
#define BIGW 4096
// big-B column layout: r@0 k@1024 v@2048 w@3072 a@3136 vl@3200 g@3232 (end 3392, pad->3456)
// dwdavg column layout: dw@0 da@1024 dv@2048 g@3072  (ld 4096)

typedef __attribute__((ext_vector_type(8))) short bf16x8;
typedef __attribute__((ext_vector_type(4))) float f32x4;
typedef unsigned short u16;

__device__ __forceinline__ float sgm(float x){ return 1.0f/(1.0f+expf(-x)); }

template<int MAXM>
__device__ __forceinline__ float redgrp(float v){
  #pragma unroll
  for (int m=1; m<=MAXM; m<<=1) v += __shfl_xor(v, m, 64);
  return v;
}

template<int CTRL>
__device__ __forceinline__ float dppadd(float v){
  union { float f; int i; } u, r;
  u.f = v;
  r.i = __builtin_amdgcn_update_dpp(u.i, u.i, CTRL, 0xf, 0xf, true);
  return v + r.f;
}
__device__ __forceinline__ float red16(float v){
  v = dppadd<0xB1>(v);
  v = dppadd<0x4E>(v);
  v = dppadd<0x141>(v);
  v = dppadd<0x140>(v);
  return v;
}

__device__ __forceinline__ unsigned pack_bf16(float a, float b){
  unsigned ua = __builtin_bit_cast(unsigned, a);
  unsigned ub = __builtin_bit_cast(unsigned, b);
  ua = (ua + 0x7FFFu + ((ua>>16)&1u)) >> 16;
  ub = (ub + 0x7FFFu + ((ub>>16)&1u)) >> 16;
  return ua | (ub<<16);
}
__device__ __forceinline__ u16 bf16_1(float a){
  unsigned ua = __builtin_bit_cast(unsigned, a);
  return (u16)((ua + 0x7FFFu + ((ua>>16)&1u)) >> 16);
}

__device__ __forceinline__ void gload16(const void* g, void* l){
  __builtin_amdgcn_global_load_lds(
    (const __attribute__((address_space(1))) unsigned int*)g,
    (__attribute__((address_space(3))) unsigned int*)l, 16, 0, 0);
}

// ---------------- f32 -> bf16 convert (weights) -------------------------------
__global__ __launch_bounds__(256) void cvt_kernel(const float* __restrict__ in,
    u16* __restrict__ out) {
  size_t i = (size_t)blockIdx.x*256 + threadIdx.x;
  float4 a = ((const float4*)in)[2*i];
  float4 b = ((const float4*)in)[2*i+1];
  uint4 o = {pack_bf16(a.x,a.y), pack_bf16(a.z,a.w),
             pack_bf16(b.x,b.y), pack_bf16(b.z,b.w)};
  ((uint4*)out)[i] = o;
}

// ---------------- pack square weights into BigB rows: [W | diag(mix)W] -------
__global__ __launch_bounds__(256) void packW_kernel(const float* __restrict__ Wr,
    const float* __restrict__ Wk, const float* __restrict__ Wv,
    const float* __restrict__ xr, const float* __restrict__ xk,
    const float* __restrict__ xv, u16* __restrict__ out) {
  int which = blockIdx.y;
  const float* W   = which==0 ? Wr : (which==1 ? Wk : Wv);
  const float* mix = which==0 ? xr : (which==1 ? xk : xv);
  u16* o = out + (size_t)which*1024*BIGK;
  int n = blockIdx.x;             // 0..1023
  int c0 = threadIdx.x*8;         // 0..2040
  int ks = c0 & 1023;
  const float* src = W + (size_t)n*Cc + ks;
  float4 a = *(const float4*)src;
  float4 b = *(const float4*)(src+4);
  if (c0 >= 1024){
    float4 m0 = *(const float4*)(mix + ks);
    float4 m1 = *(const float4*)(mix + ks + 4);
    a.x*=m0.x; a.y*=m0.y; a.z*=m0.z; a.w*=m0.w;
    b.x*=m1.x; b.y*=m1.y; b.z*=m1.z; b.w*=m1.w;
  }
  uint4 ov = {pack_bf16(a.x,a.y), pack_bf16(a.z,a.w),
              pack_bf16(b.x,b.y), pack_bf16(b.z,b.w)};
  *(uint4*)(o + (size_t)n*BIGK + c0) = ov;
}

// ---------------- pack lora W1[C,D] (transposed) into BigB rows --------------
__global__ __launch_bounds__(256) void packL_kernel(const float* __restrict__ w1,
    const float* __restrict__ a1, const float* __restrict__ v1,
    const float* __restrict__ g1, const float* __restrict__ x_w,
    const float* __restrict__ x_a, const float* __restrict__ x_v,
    const float* __restrict__ x_g, u16* __restrict__ out) {
  int bid = blockIdx.x;           // 0..319
  const float* W1; const float* mix; int D, d, nbase;
  if (bid < 64)       { W1=w1; mix=x_w; D=64;  d=bid;     nbase=3072; }
  else if (bid < 128) { W1=a1; mix=x_a; D=64;  d=bid-64;  nbase=3136; }
  else if (bid < 160) { W1=v1; mix=x_v; D=32;  d=bid-128; nbase=3200; }
  else                { W1=g1; mix=x_g; D=160; d=bid-160; nbase=3232; }
  int k0 = threadIdx.x*8;
  float v[8];
  #pragma unroll
  for (int q=0;q<8;++q){
    int kk = k0+q;
    int ks = kk & 1023;
    float t = W1[(size_t)ks*D + d];
    if (kk >= 1024) t *= mix[ks];
    v[q] = t;
  }
  uint4 o = {pack_bf16(v[0],v[1]), pack_bf16(v[2],v[3]),
             pack_bf16(v[4],v[5]), pack_bf16(v[6],v[7])};
  *(uint4*)(out + (size_t)(nbase+d)*BIGK + k0) = o;
}

// --------- pack block-diagonal W2: out[n][k] bf16, n in [0,4096) k in [0,320)
__global__ __launch_bounds__(320) void packW2_kernel(const float* __restrict__ w2,
    const float* __restrict__ a2, const float* __restrict__ v2,
    const float* __restrict__ g2, u16* __restrict__ out) {
  int n = blockIdx.x; int k = threadIdx.x;
  int which = n >> 10, col = n & 1023;
  float v = 0.f;
  if (which==0)      { if (k < 64)              v = w2[(size_t)k*Cc + col]; }
  else if (which==1) { if (k >= 64 && k < 128)  v = a2[(size_t)(k-64)*Cc + col]; }
  else if (which==2) { if (k >= 128 && k < 160) v = v2[(size_t)(k-128)*Cc + col]; }
  else               { if (k >= 160)            v = g2[(size_t)(k-160)*Cc + col]; }
  out[(size_t)n*LORAK + k] = bf16_1(v);
}

// --------- act + cvt lora columns of bigOut -> loraAct bf16 [4096][320] ------
__global__ __launch_bounds__(320) void actcvt_kernel(const float* __restrict__ m,
    u16* __restrict__ loraAct) {
  int i = blockIdx.x; int cc = threadIdx.x;
  float v = m[(size_t)i*BIGN + 3072 + cc];
  if (cc < 64) v = tanhf(v);
  else if (cc >= 160) v = sgm(v);
  loraAct[(size_t)i*LORAK + cc] = bf16_1(v);
}

// ---------------- fused LN1 -> bigA = [xn | xx] bf16 -------------------------
__global__ __launch_bounds__(256) void lnmix1_kernel(const float* __restrict__ x,
    const float* __restrict__ w, const float* __restrict__ b,
    u16* __restrict__ bigA) {
  int rowg = blockIdx.x; int t = rowg & (Tt-1);
  int tid = threadIdx.x;
  size_t off = (size_t)rowg*Cc + tid*4;
  float4 vc = *(const float4*)(x + off);
  float4 vp = {0.f,0.f,0.f,0.f};
  if (t) vp = *(const float4*)(x + off - Cc);
  float sc = vc.x+vc.y+vc.z+vc.w;
  float qc = vc.x*vc.x+vc.y*vc.y+vc.z*vc.z+vc.w*vc.w;
  float sp = vp.x+vp.y+vp.z+vp.w;
  float qp = vp.x*vp.x+vp.y*vp.y+vp.z*vp.z+vp.w*vp.w;
  sc = redgrp<32>(sc); qc = redgrp<32>(qc);
  sp = redgrp<32>(sp); qp = redgrp<32>(qp);
  __shared__ float rbuf[4][4];
  int lane = tid & 63, wv = tid >> 6;
  if (lane==0){ rbuf[wv][0]=sc; rbuf[wv][1]=qc; rbuf[wv][2]=sp; rbuf[wv][3]=qp; }
  __syncthreads();
  sc = rbuf[0][0]+rbuf[1][0]+rbuf[2][0]+rbuf[3][0];
  qc = rbuf[0][1]+rbuf[1][1]+rbuf[2][1]+rbuf[3][1];
  sp = rbuf[0][2]+rbuf[1][2]+rbuf[2][2]+rbuf[3][2];
  qp = rbuf[0][3]+rbuf[1][3]+rbuf[2][3]+rbuf[3][3];
  float muc = sc*(1.0f/Cc), mup = sp*(1.0f/Cc);
  float rnc = rsqrtf(qc*(1.0f/Cc) - muc*muc + 1e-5f);
  float rnp = rsqrtf(qp*(1.0f/Cc) - mup*mup + 1e-5f);
  float4 w4 = *(const float4*)(w + tid*4);
  float4 b4 = *(const float4*)(b + tid*4);
  float vcl[4]={vc.x,vc.y,vc.z,vc.w};
  float vpl[4]={vp.x,vp.y,vp.z,vp.w};
  float wl[4]={w4.x,w4.y,w4.z,w4.w};
  float bl[4]={b4.x,b4.y,b4.z,b4.w};
  float xnc[4], xx[4];
  #pragma unroll
  for (int q=0;q<4;++q){
    xnc[q] = (vcl[q]-muc)*rnc*wl[q] + bl[q];
    float xnp = t ? ((vpl[q]-mup)*rnp*wl[q] + bl[q]) : 0.0f;
    xx[q] = xnp - xnc[q];
  }
  size_t ab = (size_t)rowg*BIGK + tid*4;
  uint2 p0 = {pack_bf16(xnc[0],xnc[1]), pack_bf16(xnc[2],xnc[3])};
  uint2 p1 = {pack_bf16(xx[0],xx[1]),   pack_bf16(xx[2],xx[3])};
  *(uint2*)(bigA + ab) = p0;
  *(uint2*)(bigA + ab + 1024) = p1;
}

// ---------------- fused LN2 + cmix -> bf16 -----------------------------------
__global__ __launch_bounds__(256) void lnmix2_kernel(const float* __restrict__ x,
    const float* __restrict__ w, const float* __restrict__ b,
    const float* __restrict__ mixk, u16* __restrict__ outb) {
  int rowg = blockIdx.x; int t = rowg & (Tt-1);
  int tid = threadIdx.x;
  size_t off = (size_t)rowg*Cc + tid*4;
  float4 vc = *(const float4*)(x + off);
  float4 vp = {0.f,0.f,0.f,0.f};
  if (t) vp = *(const float4*)(x + off - Cc);
  float sc = vc.x+vc.y+vc.z+vc.w;
  float qc = vc.x*vc.x+vc.y*vc.y+vc.z*vc.z+vc.w*vc.w;
  float sp = vp.x+vp.y+vp.z+vp.w;
  float qp = vp.x*vp.x+vp.y*vp.y+vp.z*vp.z+vp.w*vp.w;
  sc = redgrp<32>(sc); qc = redgrp<32>(qc);
  sp = redgrp<32>(sp); qp = redgrp<32>(qp);
  __shared__ float rbuf[4][4];
  int lane = tid & 63, wv = tid >> 6;
  if (lane==0){ rbuf[wv][0]=sc; rbuf[wv][1]=qc; rbuf[wv][2]=sp; rbuf[wv][3]=qp; }
  __syncthreads();
  sc = rbuf[0][0]+rbuf[1][0]+rbuf[2][0]+rbuf[3][0];
  qc = rbuf[0][1]+rbuf[1][1]+rbuf[2][1]+rbuf[3][1];
  sp = rbuf[0][2]+rbuf[1][2]+rbuf[2][2]+rbuf[3][2];
  qp = rbuf[0][3]+rbuf[1][3]+rbuf[2][3]+rbuf[3][3];
  float muc = sc*(1.0f/Cc), mup = sp*(1.0f/Cc);
  float rnc = rsqrtf(qc*(1.0f/Cc) - muc*muc + 1e-5f);
  float rnp = rsqrtf(qp*(1.0f/Cc) - mup*mup + 1e-5f);
  float4 w4 = *(const float4*)(w + tid*4);
  float4 b4 = *(const float4*)(b + tid*4);
  float4 m = *(const float4*)(mixk + tid*4);
  float vcl[4]={vc.x,vc.y,vc.z,vc.w};
  float vpl[4]={vp.x,vp.y,vp.z,vp.w};
  float wl[4]={w4.x,w4.y,w4.z,w4.w};
  float bl[4]={b4.x,b4.y,b4.z,b4.w};
  float ml[4]={m.x,m.y,m.z,m.w};
  float o[4];
  #pragma unroll
  for (int q=0;q<4;++q){
    float xnc = (vcl[q]-muc)*rnc*wl[q] + bl[q];
    float xnp = t ? ((vpl[q]-mup)*rnp*wl[q] + bl[q]) : 0.0f;
    o[q] = xnc + (xnp - xnc)*ml[q];
  }
  uint2 p = {pack_bf16(o[0],o[1]), pack_bf16(o[2],o[3])};
  *(uint2*)(outb + off) = p;
}

// ================= bf16 GEMM (m97 structure): out = A[M,K] @ W[N,K]^T ========
// MODE 0: f32 out   1: f32 out = res + acc   2: bf16 out = relu(acc)^2
template<int MODE>
__global__ __launch_bounds__(256) void gemm_bf16(const u16* __restrict__ A,
    const u16* __restrict__ W, void* __restrict__ outv,
    const float* __restrict__ res, int M, int N, int K) {
  __shared__ u16 As[2][128*64];
  __shared__ u16 Bs[2][128*64];
  int tid = threadIdx.x;
  int bm = blockIdx.y, bn = blockIdx.x;
  int wave = tid >> 6, lane = tid & 63;
  int wm = wave >> 1, wn = wave & 1;
  int srow = wave*32 + (lane>>3);
  int scol = (lane&7)*8;
  const u16* Ag = A + (size_t)(bm*128 + srow)*K + scol;
  const u16* Wg = W + (size_t)(bn*128 + srow)*K + scol;
  int nt = K >> 6;
  f32x4 acc[4][4];
  f32x4 zero = {0.f,0.f,0.f,0.f};
  #pragma unroll
  for (int i=0;i<4;++i)
    #pragma unroll
    for (int j=0;j<4;++j) acc[i][j] = zero;

  #define STAGE(buf, t) { \
    const u16* Ag2 = Ag + (size_t)(t)*64; \
    const u16* Wg2 = Wg + (size_t)(t)*64; \
    _Pragma("unroll") \
    for (int i_=0;i_<4;++i_){ \
      gload16(Ag2 + (size_t)i_*8*K, &As[buf][(wave*32+i_*8)*64]); \
      gload16(Wg2 + (size_t)i_*8*K, &Bs[buf][(wave*32+i_*8)*64]); \
    } }

  STAGE(0, 0);
  asm volatile("s_waitcnt vmcnt(0)" ::: "memory");
  __syncthreads();
  int lrow = lane & 15, lk8 = lane >> 4;
  for (int t = 0; t < nt; ++t) {
    int cur = t & 1;
    if (t+1 < nt) STAGE(cur^1, t+1);
    #pragma unroll
    for (int kk2 = 0; kk2 < 2; ++kk2) {
      bf16x8 af[4], bfr[4];
      #pragma unroll
      for (int i=0;i<4;++i)
        af[i] = *(const bf16x8*)&As[cur][(wm*64 + i*16 + lrow)*64 + kk2*32 + lk8*8];
      #pragma unroll
      for (int j=0;j<4;++j)
        bfr[j] = *(const bf16x8*)&Bs[cur][(wn*64 + j*16 + lrow)*64 + kk2*32 + lk8*8];
      #pragma unroll
      for (int i=0;i<4;++i)
        #pragma unroll
        for (int j=0;j<4;++j)
          acc[i][j] = __builtin_amdgcn_mfma_f32_16x16x32_bf16(af[i], bfr[j], acc[i][j], 0, 0, 0);
    }
    if (t+1 < nt) { asm volatile("s_waitcnt vmcnt(0)" ::: "memory"); }
    __syncthreads();
  }
  #undef STAGE
  float* outf = (float*)outv;
  u16* outb = (u16*)outv;
  int crow4 = (lane>>4)*4, ccol = lane & 15;
  #pragma unroll
  for (int i=0;i<4;++i){
    #pragma unroll
    for (int j=0;j<4;++j){
      int gr = bm*128 + wm*64 + i*16 + crow4;
      int gc = bn*128 + wn*64 + j*16 + ccol;
      #pragma unroll
      for (int q=0;q<4;++q){
        float v = acc[i][j][q];
        size_t o = (size_t)(gr+q)*N + gc;
        if (MODE==1) { v += res[o]; outf[o] = v; }
        else if (MODE==2) { v = fmaxf(v, 0.f); outb[o] = bf16_1(v*v); }
        else outf[o] = v;
      }
    }
  }
}

// ---------------- prep: dw/da/dv from dwdavg (ld 4096), k/v from bigOut ------
__global__ __launch_bounds__(256) void prep_kernel(
    const float* __restrict__ kraw, const float* __restrict__ dw,
    const float* __restrict__ da, const float* __restrict__ dv,
    const float* __restrict__ vraw, const float* __restrict__ vfirst,
    const float* __restrict__ w0, const float* __restrict__ a0,
    const float* __restrict__ v0, const float* __restrict__ k_k,
    const float* __restrict__ k_a,
    float* __restrict__ decay, float* __restrict__ kfin, float* __restrict__ vfin,
    float* __restrict__ Ak, float* __restrict__ Bk) {
  int row = blockIdx.x; int tid = threadIdx.x; int c = tid*4;
  size_t off = (size_t)row*Cc + c;
  size_t offw = (size_t)row*BIGN + c;
  size_t offd = (size_t)row*BIGW + c;
  float4 kr = *(const float4*)(kraw+offw);
  float4 vr = *(const float4*)(vraw+offw);
  float4 w4 = *(const float4*)(dw+offd);
  float4 A4 = *(const float4*)(da+offd);
  float4 V4 = *(const float4*)(dv+offd);
  float4 vf = *(const float4*)(vfirst+off);
  float4 w04 = *(const float4*)(w0+c);
  float4 a04 = *(const float4*)(a0+c);
  float4 v04 = *(const float4*)(v0+c);
  float4 kk4 = *(const float4*)(k_k+c);
  float4 ka4 = *(const float4*)(k_a+c);
  float krl[4]={kr.x,kr.y,kr.z,kr.w};
  float dwl[4]={w4.x,w4.y,w4.z,w4.w};
  float dal[4]={A4.x,A4.y,A4.z,A4.w};
  float dvl[4]={V4.x,V4.y,V4.z,V4.w};
  float vrl[4]={vr.x,vr.y,vr.z,vr.w};
  float vfl[4]={vf.x,vf.y,vf.z,vf.w};
  float w0l[4]={w04.x,w04.y,w04.z,w04.w};
  float a0l[4]={a04.x,a04.y,a04.z,a04.w};
  float v0l[4]={v04.x,v04.y,v04.z,v04.w};
  float kkl[4]={kk4.x,kk4.y,kk4.z,kk4.w};
  float kal[4]={ka4.x,ka4.y,ka4.z,ka4.w};
  float av[4], dec[4], vv[4], kp[4], kf[4];
  float ss = 0.f;
  #pragma unroll
  for (int q=0;q<4;++q){
    av[q] = sgm(a0l[q] + dal[q]);
    dec[q] = 0.60653065971263342f * sgm(w0l[q] + dwl[q]);   // exp(-softplus(-u)-0.5)
    float sv = sgm(v0l[q] + dvl[q]);
    vv[q] = vrl[q] + (vfl[q]-vrl[q])*sv;
    kp[q] = krl[q]*kkl[q];
    ss += kp[q]*kp[q];
    kf[q] = krl[q]*(1.0f + (av[q]-1.0f)*kal[q]);
  }
  ss = redgrp<8>(ss);
  float inv = 1.0f / fmaxf(sqrtf(ss), 1e-12f);
  float4 o;
  o.x=dec[0];o.y=dec[1];o.z=dec[2];o.w=dec[3];  *(float4*)(decay+off)=o;
  o.x=kf[0]; o.y=kf[1]; o.z=kf[2]; o.w=kf[3];   *(float4*)(kfin+off)=o;
  o.x=vv[0]; o.y=vv[1]; o.z=vv[2]; o.w=vv[3];   *(float4*)(vfin+off)=o;
  o.x=-kp[0]*inv; o.y=-kp[1]*inv; o.z=-kp[2]*inv; o.w=-kp[3]*inv; *(float4*)(Ak+off)=o;
  o.x=kp[0]*inv*av[0]; o.y=kp[1]*inv*av[1]; o.z=kp[2]*inv*av[2]; o.w=kp[3]*inv*av[3];
  *(float4*)(Bk+off)=o;
}

// ------ WKV-7 scan: 512 blocks (32 bh x 16 splits, XCD-grouped), 64 thr ------
__global__ __launch_bounds__(64) void wkv_kernel(
    const float* __restrict__ decay, const float* __restrict__ Ak,
    const float* __restrict__ Bk, const float* __restrict__ kfin,
    const float* __restrict__ r_, const float* __restrict__ vfin,
    const float* __restrict__ S0, float* __restrict__ y) {
  __shared__ float lds[2][6][CH][64];
  int bid = blockIdx.x;
  // XCD-grouped: bid&7 = XCD; each XCD gets 4 bh x 16 splits
  int c8 = bid & 7, idx = bid >> 3;   // idx 0..63
  int bh = c8*4 + (idx & 3);
  int sp = idx >> 2;                  // 0..15
  int bb = bh >> 4, h = bh & 15;
  int lane = threadIdx.x;             // 0..63
  int bi = lane >> 4, bj = lane & 15;
  int row = sp*4 + bi;                // 0..63
  int j0 = bj*4;
  float S[4];
  {
    const float* s0p = S0 + (size_t)bh*4096 + row*64 + j0;
    S[0]=s0p[0]; S[1]=s0p[1]; S[2]=s0p[2]; S[3]=s0p[3];
  }
  size_t rowbase = (size_t)bb*Tt;
  int lhi = lane >> 4, llo4 = (lane & 15)*4;

  // one array's 16 steps: 4 x gload16; LDS dest = uniform base + lane*16
  #define WST1(buf, chn, arr, base, ldv) { \
    const float* gp_ = (base) + (size_t)((rowbase + (size_t)(chn)*CH + lhi))*(ldv) + h*64 + llo4; \
    _Pragma("unroll") \
    for (int p_=0; p_<4; ++p_) \
      gload16(gp_ + (size_t)p_*4*(ldv), &lds[buf][arr][p_*4][0]); }
  #define WSTAGE(buf, chn) { \
    WST1(buf, chn, 0, decay, Cc); WST1(buf, chn, 1, Ak, Cc); WST1(buf, chn, 2, Bk, Cc); \
    WST1(buf, chn, 3, kfin, Cc); WST1(buf, chn, 4, r_, BIGN); WST1(buf, chn, 5, vfin, Cc); }

  WSTAGE(0, 0);
  asm volatile("s_waitcnt vmcnt(0)" ::: "memory");
  __syncthreads();
  const int NC = Tt/CH;
  for (int ch=0; ch<NC; ++ch) {
    int cur = ch & 1;
    if (ch+1 < NC) WSTAGE(cur^1, ch+1);
    float4 cd = *(const float4*)&lds[cur][0][0][j0];
    float4 ca = *(const float4*)&lds[cur][1][0][j0];
    float4 cb = *(const float4*)&lds[cur][2][0][j0];
    float4 ck = *(const float4*)&lds[cur][3][0][j0];
    float4 cr = *(const float4*)&lds[cur][4][0][j0];
    float  cv = lds[cur][5][0][row];
    #pragma unroll
    for (int s=0; s<CH; ++s) {
      float4 nd, na, nb, nk, nr; float nv;
      if (s+1 < CH) {
        nd = *(const float4*)&lds[cur][0][s+1][j0];
        na = *(const float4*)&lds[cur][1][s+1][j0];
        nb = *(const float4*)&lds[cur][2][s+1][j0];
        nk = *(const float4*)&lds[cur][3][s+1][j0];
        nr = *(const float4*)&lds[cur][4][s+1][j0];
        nv = lds[cur][5][s+1][row];
      }
      S[0]*=cd.x; S[1]*=cd.y; S[2]*=cd.z; S[3]*=cd.w;
      float sa = S[0]*ca.x;
      sa = fmaf(S[1], ca.y, sa);
      sa = fmaf(S[2], ca.z, sa);
      sa = fmaf(S[3], ca.w, sa);
      sa = red16(sa);
      S[0] = fmaf(cv, ck.x, S[0]); S[0] = fmaf(sa, cb.x, S[0]);
      S[1] = fmaf(cv, ck.y, S[1]); S[1] = fmaf(sa, cb.y, S[1]);
      S[2] = fmaf(cv, ck.z, S[2]); S[2] = fmaf(sa, cb.z, S[2]);
      S[3] = fmaf(cv, ck.w, S[3]); S[3] = fmaf(sa, cb.w, S[3]);
      float yp = S[0]*cr.x;
      yp = fmaf(S[1], cr.y, yp);
      yp = fmaf(S[2], cr.z, yp);
      yp = fmaf(S[3], cr.w, yp);
      yp = red16(yp);
      if (bj == 0)
        y[(rowbase + ch*CH + s)*Cc + h*64 + row] = yp;
      if (s+1 < CH) { cd=nd; ca=na; cb=nb; ck=nk; cr=nr; cv=nv; }
    }
    if (ch+1 < NC) { asm volatile("s_waitcnt vmcnt(0)" ::: "memory"); }
    __syncthreads();
  }
  #undef WSTAGE
  #undef WST1
}

// ---------------- GroupNorm(head) + r.k.r_k bonus + *g -> bf16 ---------------
__global__ __launch_bounds__(256) void gn_kernel(
    const float* __restrict__ y, const float* __restrict__ r_,
    const float* __restrict__ kfin, const float* __restrict__ vfin,
    const float* __restrict__ g_, const float* __restrict__ lnxw,
    const float* __restrict__ lnxb, const float* __restrict__ r_k,
    u16* __restrict__ Ao) {
  int row = blockIdx.x; int tid = threadIdx.x; int c = tid*4;
  size_t off = (size_t)row*Cc + c;
  float4 y4 = *(const float4*)(y+off);
  float s = y4.x+y4.y+y4.z+y4.w;
  float q = y4.x*y4.x+y4.y*y4.y+y4.z*y4.z+y4.w*y4.w;
  s = redgrp<8>(s); q = redgrp<8>(q);
  float mu = s*(1.0f/64.0f);
  float var = q*(1.0f/64.0f) - mu*mu;
  float rn = rsqrtf(var + 64e-5f);
  float4 rr = *(const float4*)(r_ + (size_t)row*BIGN + c);
  float4 kk = *(const float4*)(kfin+off);
  float4 vv = *(const float4*)(vfin+off);
  float4 gg = *(const float4*)(g_ + (size_t)row*BIGW + c);
  int h = tid >> 4; int hs = (tid & 15)*4;
  float4 rk = *(const float4*)(r_k + h*64 + hs);
  float dp = rr.x*kk.x*rk.x + rr.y*kk.y*rk.y + rr.z*kk.z*rk.z + rr.w*kk.w*rk.w;
  dp = redgrp<8>(dp);
  float4 w4 = *(const float4*)(lnxw+c);
  float4 b4 = *(const float4*)(lnxb+c);
  float o0 = (((y4.x-mu)*rn)*w4.x + b4.x + dp*vv.x) * gg.x;
  float o1 = (((y4.y-mu)*rn)*w4.y + b4.y + dp*vv.y) * gg.y;
  float o2 = (((y4.z-mu)*rn)*w4.z + b4.z + dp*vv.z) * gg.z;
  float o3 = (((y4.w-mu)*rn)*w4.w + b4.w + dp*vv.w) * gg.w;
  uint2 p = {pack_bf16(o0,o1), pack_bf16(o2,o3)};
  *(uint2*)(Ao + off) = p;
}

__global__ __launch_bounds__(256) void copy_kernel(const float* __restrict__ src,
                                                   float* __restrict__ dst) {
  size_t i = ((size_t)blockIdx.x*256 + threadIdx.x)*4;
  *(float4*)(dst+i) = *(const float4*)(src+i);
}

extern "C" void kernel_launch(void* const* d_in, const int* in_sizes, int n_in,
                              void* d_out, int out_size, void* d_ws, size_t ws_size,
                              hipStream_t stream) {
  const float* x      = (const float*)d_in[0];
  const float* vfirst = (const float*)d_in[1];
  const float* S0     = (const float*)d_in[2];
  const float* ln1w   = (const float*)d_in[3];
  const float* ln1b   = (const float*)d_in[4];
  const float* ln2w   = (const float*)d_in[5];
  const float* ln2b   = (const float*)d_in[6];
  const float* x_r    = (const float*)d_in[7];
  const float* x_w    = (const float*)d_in[8];
  const float* x_k    = (const float*)d_in[9];
  const float* x_v    = (const float*)d_in[10];
  const float* x_a    = (const float*)d_in[11];
  const float* x_g    = (const float*)d_in[12];
  const float* w0     = (const float*)d_in[13];
  const float* w1     = (const float*)d_in[14];
  const float* w2     = (const float*)d_in[15];
  const float* a0     = (const float*)d_in[16];
  const float* a1     = (const float*)d_in[17];
  const float* a2     = (const float*)d_in[18];
  const float* v0     = (const float*)d_in[19];
  const float* v1     = (const float*)d_in[20];
  const float* v2     = (const float*)d_in[21];
  const float* g1     = (const float*)d_in[22];
  const float* g2     = (const float*)d_in[23];
  const float* k_k    = (const float*)d_in[24];
  const float* k_a    = (const float*)d_in[25];
  const float* r_k    = (const float*)d_in[26];
  const float* W_r    = (const float*)d_in[27];
  const float* W_k    = (const float*)d_in[28];
  const float* W_v    = (const float*)d_in[29];
  const float* W_o    = (const float*)d_in[30];
  const float* lnxw   = (const float*)d_in[31];
  const float* lnxb   = (const float*)d_in[32];
  const float* mixk   = (const float*)d_in[33];
  const float* Wkey   = (const float*)d_in[34];
  const float* Wval   = (const float*)d_in[35];
  float* out = (float*)d_out;
  float* ws  = (float*)d_ws;
  const size_t U = (size_t)BT * Cc;
  float* u[14];
  for (int i=0;i<14;++i) u[i] = ws + i*U;

  // lifetimes:
  // u0: bigA bf16 -> Bk f32 -> xo f32
  // u1: BigB bf16 -> y f32
  // u2..u5: bigOut f32 [4096][3456]  -> (u2,u3) midb bf16
  // u6..u9: dwdavg f32 [4096][4096]  -> u6 Wkeyb, u7 cmb, u8 Wvalb
  // u10: W2blk bf16 -> decay f32 -> gnb bf16
  // u11: loraAct bf16 -> kfin f32
  // u12: vfin f32
  // u13: Ak f32 -> Wob bf16
  u16* bigA   = (u16*)u[0];
  u16* BigB   = (u16*)u[1];
  float* bigOut = u[2];
  float* dwdavg = u[6];
  u16* W2blk  = (u16*)u[10];
  u16* loraAct= (u16*)u[11];
  float* Bk   = u[0];
  float* y_   = u[1];
  u16* gnb    = (u16*)u[10];
  u16* Wob    = (u16*)u[13];
  float* xo   = u[0];
  u16* Wkeyb  = (u16*)u[6];
  u16* cmb    = (u16*)u[7];
  u16* Wvalb  = (u16*)u[8];
  u16* midb   = (u16*)u[2];

  dim3 b256(256);
  packW_kernel<<<dim3(Cc,3), b256, 0, stream>>>(W_r, W_k, W_v, x_r, x_k, x_v, BigB);
  packL_kernel<<<320, b256, 0, stream>>>(w1, a1, v1, g1, x_w, x_a, x_v, x_g, BigB);
  packW2_kernel<<<BIGW, dim3(320), 0, stream>>>(w2, a2, v2, g2, W2blk);
  lnmix1_kernel<<<BT, b256, 0, stream>>>(x, ln1w, ln1b, bigA);
  gemm_bf16<0><<<dim3(BIGN/128, BT/128), b256, 0, stream>>>(bigA, BigB, bigOut, nullptr, BT, BIGN, BIGK);
  actcvt_kernel<<<BT, dim3(320), 0, stream>>>(bigOut, loraAct);
  gemm_bf16<0><<<dim3(BIGW/128, BT/128), b256, 0, stream>>>(loraAct, W2blk, dwdavg, nullptr, BT, BIGW, LORAK);
  prep_kernel<<<BT, b256, 0, stream>>>(bigOut+1024, dwdavg, dwdavg+1024, dwdavg+2048,
      bigOut+2048, vfirst, w0, a0, v0, k_k, k_a, u[10], u[11], u[12], u[13], Bk);
  wkv_kernel<<<512, dim3(64), 0, stream>>>(u[10], u[13], Bk, u[11], bigOut, u[12], S0, y_);
  cvt_kernel<<<Cc*Cc/2048, b256, 0, stream>>>(W_o, Wob);
  gn_kernel<<<BT, b256, 0, stream>>>(y_, bigOut, u[11], u[12], dwdavg+3072, lnxw, lnxb, r_k, gnb);
  gemm_bf16<1><<<dim3(Cc/128, BT/128), b256, 0, stream>>>(gnb, Wob, xo, x, BT, Cc, Cc);
  lnmix2_kernel<<<BT, b256, 0, stream>>>(xo, ln2w, ln2b, mixk, cmb);
  cvt_kernel<<<FFNd*Cc/2048, b256, 0, stream>>>(Wkey, Wkeyb);
  gemm_bf16<2><<<dim3(FFNd/128, BT/128), b256, 0, stream>>>(cmb, Wkeyb, midb, nullptr, BT, FFNd, Cc);
  cvt_kernel<<<Cc*FFNd/2048, b256, 0, stream>>>(Wval, Wvalb);
  gemm_bf16<1><<<dim3(Cc/128, BT/128), b256, 0, stream>>>(midb, Wvalb, out, xo, BT, Cc, FFNd);
  copy_kernel<<<BT*Cc/1024, b256, 0, stream>>>(vfirst, out + (size_t)BT*Cc);
}

// Round 6
// 713.361 us; speedup vs baseline: 4.9030x; 1.0037x over previous
//
#include <hip/hip_runtime.h>
#include <math.h>

#define Bb 2
#define Tt 2048
#define Cc 1024
#define Hh 16
#define BT 4096
#define FFNd 4096
#define CH 16
#define BIGN 3456
#define BIGK 2048
#define LORAK 320
#define BIGW 4096
// big-B column layout: r@0 k@1024 v@2048 w@3072 a@3136 vl@3200 g@3232 (end 3392, pad->3456)
// dwdavg column layout: dw@0 da@1024 dv@2048 g@3072  (ld 4096)

typedef __attribute__((ext_vector_type(8))) short bf16x8;
typedef __attribute__((ext_vector_type(4))) float f32x4;
typedef unsigned short u16;

__device__ __forceinline__ float sgm(float x){ return 1.0f/(1.0f+expf(-x)); }

template<int MAXM>
__device__ __forceinline__ float redgrp(float v){
  #pragma unroll
  for (int m=1; m<=MAXM; m<<=1) v += __shfl_xor(v, m, 64);
  return v;
}

template<int CTRL>
__device__ __forceinline__ float dppadd(float v){
  union { float f; int i; } u, r;
  u.f = v;
  r.i = __builtin_amdgcn_update_dpp(u.i, u.i, CTRL, 0xf, 0xf, true);
  return v + r.f;
}
__device__ __forceinline__ float red16(float v){
  v = dppadd<0xB1>(v);
  v = dppadd<0x4E>(v);
  v = dppadd<0x141>(v);
  v = dppadd<0x140>(v);
  return v;
}

__device__ __forceinline__ unsigned pack_bf16(float a, float b){
  unsigned ua = __builtin_bit_cast(unsigned, a);
  unsigned ub = __builtin_bit_cast(unsigned, b);
  ua = (ua + 0x7FFFu + ((ua>>16)&1u)) >> 16;
  ub = (ub + 0x7FFFu + ((ub>>16)&1u)) >> 16;
  return ua | (ub<<16);
}
__device__ __forceinline__ u16 bf16_1(float a){
  unsigned ua = __builtin_bit_cast(unsigned, a);
  return (u16)((ua + 0x7FFFu + ((ua>>16)&1u)) >> 16);
}

__device__ __forceinline__ void gload16(const void* g, void* l){
  __builtin_amdgcn_global_load_lds(
    (const __attribute__((address_space(1))) unsigned int*)g,
    (__attribute__((address_space(3))) unsigned int*)l, 16, 0, 0);
}

// ---------------- f32 -> bf16 convert (weights) -------------------------------
__global__ __launch_bounds__(256) void cvt_kernel(const float* __restrict__ in,
    u16* __restrict__ out) {
  size_t i = (size_t)blockIdx.x*256 + threadIdx.x;
  float4 a = ((const float4*)in)[2*i];
  float4 b = ((const float4*)in)[2*i+1];
  uint4 o = {pack_bf16(a.x,a.y), pack_bf16(a.z,a.w),
             pack_bf16(b.x,b.y), pack_bf16(b.z,b.w)};
  ((uint4*)out)[i] = o;
}

// ---------------- pack square weights into BigB rows: [W | diag(mix)W] -------
__global__ __launch_bounds__(256) void packW_kernel(const float* __restrict__ Wr,
    const float* __restrict__ Wk, const float* __restrict__ Wv,
    const float* __restrict__ xr, const float* __restrict__ xk,
    const float* __restrict__ xv, u16* __restrict__ out) {
  int which = blockIdx.y;
  const float* W   = which==0 ? Wr : (which==1 ? Wk : Wv);
  const float* mix = which==0 ? xr : (which==1 ? xk : xv);
  u16* o = out + (size_t)which*1024*BIGK;
  int n = blockIdx.x;             // 0..1023
  int c0 = threadIdx.x*8;         // 0..2040
  int ks = c0 & 1023;
  const float* src = W + (size_t)n*Cc + ks;
  float4 a = *(const float4*)src;
  float4 b = *(const float4*)(src+4);
  if (c0 >= 1024){
    float4 m0 = *(const float4*)(mix + ks);
    float4 m1 = *(const float4*)(mix + ks + 4);
    a.x*=m0.x; a.y*=m0.y; a.z*=m0.z; a.w*=m0.w;
    b.x*=m1.x; b.y*=m1.y; b.z*=m1.z; b.w*=m1.w;
  }
  uint4 ov = {pack_bf16(a.x,a.y), pack_bf16(a.z,a.w),
              pack_bf16(b.x,b.y), pack_bf16(b.z,b.w)};
  *(uint4*)(o + (size_t)n*BIGK + c0) = ov;
}

// ---------------- pack lora W1[C,D] (transposed) into BigB rows --------------
__global__ __launch_bounds__(256) void packL_kernel(const float* __restrict__ w1,
    const float* __restrict__ a1, const float* __restrict__ v1,
    const float* __restrict__ g1, const float* __restrict__ x_w,
    const float* __restrict__ x_a, const float* __restrict__ x_v,
    const float* __restrict__ x_g, u16* __restrict__ out) {
  int bid = blockIdx.x;           // 0..319
  const float* W1; const float* mix; int D, d, nbase;
  if (bid < 64)       { W1=w1; mix=x_w; D=64;  d=bid;     nbase=3072; }
  else if (bid < 128) { W1=a1; mix=x_a; D=64;  d=bid-64;  nbase=3136; }
  else if (bid < 160) { W1=v1; mix=x_v; D=32;  d=bid-128; nbase=3200; }
  else                { W1=g1; mix=x_g; D=160; d=bid-160; nbase=3232; }
  int k0 = threadIdx.x*8;
  float v[8];
  #pragma unroll
  for (int q=0;q<8;++q){
    int kk = k0+q;
    int ks = kk & 1023;
    float t = W1[(size_t)ks*D + d];
    if (kk >= 1024) t *= mix[ks];
    v[q] = t;
  }
  uint4 o = {pack_bf16(v[0],v[1]), pack_bf16(v[2],v[3]),
             pack_bf16(v[4],v[5]), pack_bf16(v[6],v[7])};
  *(uint4*)(out + (size_t)(nbase+d)*BIGK + k0) = o;
}

// --------- pack block-diagonal W2: out[n][k] bf16, n in [0,4096) k in [0,320)
__global__ __launch_bounds__(320) void packW2_kernel(const float* __restrict__ w2,
    const float* __restrict__ a2, const float* __restrict__ v2,
    const float* __restrict__ g2, u16* __restrict__ out) {
  int n = blockIdx.x; int k = threadIdx.x;
  int which = n >> 10, col = n & 1023;
  float v = 0.f;
  if (which==0)      { if (k < 64)              v = w2[(size_t)k*Cc + col]; }
  else if (which==1) { if (k >= 64 && k < 128)  v = a2[(size_t)(k-64)*Cc + col]; }
  else if (which==2) { if (k >= 128 && k < 160) v = v2[(size_t)(k-128)*Cc + col]; }
  else               { if (k >= 160)            v = g2[(size_t)(k-160)*Cc + col]; }
  out[(size_t)n*LORAK + k] = bf16_1(v);
}

// --------- act + cvt lora columns of bigOut -> loraAct bf16 [4096][320] ------
__global__ __launch_bounds__(320) void actcvt_kernel(const float* __restrict__ m,
    u16* __restrict__ loraAct) {
  int i = blockIdx.x; int cc = threadIdx.x;
  float v = m[(size_t)i*BIGN + 3072 + cc];
  if (cc < 64) v = tanhf(v);
  else if (cc >= 160) v = sgm(v);
  loraAct[(size_t)i*LORAK + cc] = bf16_1(v);
}

// ---------------- fused LN1 -> bigA = [xn | xx] bf16 -------------------------
__global__ __launch_bounds__(256) void lnmix1_kernel(const float* __restrict__ x,
    const float* __restrict__ w, const float* __restrict__ b,
    u16* __restrict__ bigA) {
  int rowg = blockIdx.x; int t = rowg & (Tt-1);
  int tid = threadIdx.x;
  size_t off = (size_t)rowg*Cc + tid*4;
  float4 vc = *(const float4*)(x + off);
  float4 vp = {0.f,0.f,0.f,0.f};
  if (t) vp = *(const float4*)(x + off - Cc);
  float sc = vc.x+vc.y+vc.z+vc.w;
  float qc = vc.x*vc.x+vc.y*vc.y+vc.z*vc.z+vc.w*vc.w;
  float sp = vp.x+vp.y+vp.z+vp.w;
  float qp = vp.x*vp.x+vp.y*vp.y+vp.z*vp.z+vp.w*vp.w;
  sc = redgrp<32>(sc); qc = redgrp<32>(qc);
  sp = redgrp<32>(sp); qp = redgrp<32>(qp);
  __shared__ float rbuf[4][4];
  int lane = tid & 63, wv = tid >> 6;
  if (lane==0){ rbuf[wv][0]=sc; rbuf[wv][1]=qc; rbuf[wv][2]=sp; rbuf[wv][3]=qp; }
  __syncthreads();
  sc = rbuf[0][0]+rbuf[1][0]+rbuf[2][0]+rbuf[3][0];
  qc = rbuf[0][1]+rbuf[1][1]+rbuf[2][1]+rbuf[3][1];
  sp = rbuf[0][2]+rbuf[1][2]+rbuf[2][2]+rbuf[3][2];
  qp = rbuf[0][3]+rbuf[1][3]+rbuf[2][3]+rbuf[3][3];
  float muc = sc*(1.0f/Cc), mup = sp*(1.0f/Cc);
  float rnc = rsqrtf(qc*(1.0f/Cc) - muc*muc + 1e-5f);
  float rnp = rsqrtf(qp*(1.0f/Cc) - mup*mup + 1e-5f);
  float4 w4 = *(const float4*)(w + tid*4);
  float4 b4 = *(const float4*)(b + tid*4);
  float vcl[4]={vc.x,vc.y,vc.z,vc.w};
  float vpl[4]={vp.x,vp.y,vp.z,vp.w};
  float wl[4]={w4.x,w4.y,w4.z,w4.w};
  float bl[4]={b4.x,b4.y,b4.z,b4.w};
  float xnc[4], xx[4];
  #pragma unroll
  for (int q=0;q<4;++q){
    xnc[q] = (vcl[q]-muc)*rnc*wl[q] + bl[q];
    float xnp = t ? ((vpl[q]-mup)*rnp*wl[q] + bl[q]) : 0.0f;
    xx[q] = xnp - xnc[q];
  }
  size_t ab = (size_t)rowg*BIGK + tid*4;
  uint2 p0 = {pack_bf16(xnc[0],xnc[1]), pack_bf16(xnc[2],xnc[3])};
  uint2 p1 = {pack_bf16(xx[0],xx[1]),   pack_bf16(xx[2],xx[3])};
  *(uint2*)(bigA + ab) = p0;
  *(uint2*)(bigA + ab + 1024) = p1;
}

// ---------------- fused LN2 + cmix -> bf16 -----------------------------------
__global__ __launch_bounds__(256) void lnmix2_kernel(const float* __restrict__ x,
    const float* __restrict__ w, const float* __restrict__ b,
    const float* __restrict__ mixk, u16* __restrict__ outb) {
  int rowg = blockIdx.x; int t = rowg & (Tt-1);
  int tid = threadIdx.x;
  size_t off = (size_t)rowg*Cc + tid*4;
  float4 vc = *(const float4*)(x + off);
  float4 vp = {0.f,0.f,0.f,0.f};
  if (t) vp = *(const float4*)(x + off - Cc);
  float sc = vc.x+vc.y+vc.z+vc.w;
  float qc = vc.x*vc.x+vc.y*vc.y+vc.z*vc.z+vc.w*vc.w;
  float sp = vp.x+vp.y+vp.z+vp.w;
  float qp = vp.x*vp.x+vp.y*vp.y+vp.z*vp.z+vp.w*vp.w;
  sc = redgrp<32>(sc); qc = redgrp<32>(qc);
  sp = redgrp<32>(sp); qp = redgrp<32>(qp);
  __shared__ float rbuf[4][4];
  int lane = tid & 63, wv = tid >> 6;
  if (lane==0){ rbuf[wv][0]=sc; rbuf[wv][1]=qc; rbuf[wv][2]=sp; rbuf[wv][3]=qp; }
  __syncthreads();
  sc = rbuf[0][0]+rbuf[1][0]+rbuf[2][0]+rbuf[3][0];
  qc = rbuf[0][1]+rbuf[1][1]+rbuf[2][1]+rbuf[3][1];
  sp = rbuf[0][2]+rbuf[1][2]+rbuf[2][2]+rbuf[3][2];
  qp = rbuf[0][3]+rbuf[1][3]+rbuf[2][3]+rbuf[3][3];
  float muc = sc*(1.0f/Cc), mup = sp*(1.0f/Cc);
  float rnc = rsqrtf(qc*(1.0f/Cc) - muc*muc + 1e-5f);
  float rnp = rsqrtf(qp*(1.0f/Cc) - mup*mup + 1e-5f);
  float4 w4 = *(const float4*)(w + tid*4);
  float4 b4 = *(const float4*)(b + tid*4);
  float4 m = *(const float4*)(mixk + tid*4);
  float vcl[4]={vc.x,vc.y,vc.z,vc.w};
  float vpl[4]={vp.x,vp.y,vp.z,vp.w};
  float wl[4]={w4.x,w4.y,w4.z,w4.w};
  float bl[4]={b4.x,b4.y,b4.z,b4.w};
  float ml[4]={m.x,m.y,m.z,m.w};
  float o[4];
  #pragma unroll
  for (int q=0;q<4;++q){
    float xnc = (vcl[q]-muc)*rnc*wl[q] + bl[q];
    float xnp = t ? ((vpl[q]-mup)*rnp*wl[q] + bl[q]) : 0.0f;
    o[q] = xnc + (xnp - xnc)*ml[q];
  }
  uint2 p = {pack_bf16(o[0],o[1]), pack_bf16(o[2],o[3])};
  *(uint2*)(outb + off) = p;
}

// ================= bf16 GEMM (m97 structure): out = A[M,K] @ W[N,K]^T ========
// MODE 0: f32 out   1: f32 out = res + acc   2: bf16 out = relu(acc)^2
template<int MODE>
__global__ __launch_bounds__(256) void gemm_bf16(const u16* __restrict__ A,
    const u16* __restrict__ W, void* __restrict__ outv,
    const float* __restrict__ res, int M, int N, int K) {
  __shared__ u16 As[2][128*64];
  __shared__ u16 Bs[2][128*64];
  int tid = threadIdx.x;
  int bm = blockIdx.y, bn = blockIdx.x;
  int wave = tid >> 6, lane = tid & 63;
  int wm = wave >> 1, wn = wave & 1;
  int srow = wave*32 + (lane>>3);
  int scol = (lane&7)*8;
  const u16* Ag = A + (size_t)(bm*128 + srow)*K + scol;
  const u16* Wg = W + (size_t)(bn*128 + srow)*K + scol;
  int nt = K >> 6;
  f32x4 acc[4][4];
  f32x4 zero = {0.f,0.f,0.f,0.f};
  #pragma unroll
  for (int i=0;i<4;++i)
    #pragma unroll
    for (int j=0;j<4;++j) acc[i][j] = zero;

  #define STAGE(buf, t) { \
    const u16* Ag2 = Ag + (size_t)(t)*64; \
    const u16* Wg2 = Wg + (size_t)(t)*64; \
    _Pragma("unroll") \
    for (int i_=0;i_<4;++i_){ \
      gload16(Ag2 + (size_t)i_*8*K, &As[buf][(wave*32+i_*8)*64]); \
      gload16(Wg2 + (size_t)i_*8*K, &Bs[buf][(wave*32+i_*8)*64]); \
    } }

  STAGE(0, 0);
  asm volatile("s_waitcnt vmcnt(0)" ::: "memory");
  __syncthreads();
  int lrow = lane & 15, lk8 = lane >> 4;
  for (int t = 0; t < nt; ++t) {
    int cur = t & 1;
    if (t+1 < nt) STAGE(cur^1, t+1);
    #pragma unroll
    for (int kk2 = 0; kk2 < 2; ++kk2) {
      bf16x8 af[4], bfr[4];
      #pragma unroll
      for (int i=0;i<4;++i)
        af[i] = *(const bf16x8*)&As[cur][(wm*64 + i*16 + lrow)*64 + kk2*32 + lk8*8];
      #pragma unroll
      for (int j=0;j<4;++j)
        bfr[j] = *(const bf16x8*)&Bs[cur][(wn*64 + j*16 + lrow)*64 + kk2*32 + lk8*8];
      #pragma unroll
      for (int i=0;i<4;++i)
        #pragma unroll
        for (int j=0;j<4;++j)
          acc[i][j] = __builtin_amdgcn_mfma_f32_16x16x32_bf16(af[i], bfr[j], acc[i][j], 0, 0, 0);
    }
    if (t+1 < nt) { asm volatile("s_waitcnt vmcnt(0)" ::: "memory"); }
    __syncthreads();
  }
  #undef STAGE
  float* outf = (float*)outv;
  u16* outb = (u16*)outv;
  int crow4 = (lane>>4)*4, ccol = lane & 15;
  #pragma unroll
  for (int i=0;i<4;++i){
    #pragma unroll
    for (int j=0;j<4;++j){
      int gr = bm*128 + wm*64 + i*16 + crow4;
      int gc = bn*128 + wn*64 + j*16 + ccol;
      #pragma unroll
      for (int q=0;q<4;++q){
        float v = acc[i][j][q];
        size_t o = (size_t)(gr+q)*N + gc;
        if (MODE==1) { v += res[o]; outf[o] = v; }
        else if (MODE==2) { v = fmaxf(v, 0.f); outb[o] = bf16_1(v*v); }
        else outf[o] = v;
      }
    }
  }
}

// ---------------- prep: dw/da/dv from dwdavg (ld 4096), k/v from bigOut ------
__global__ __launch_bounds__(256) void prep_kernel(
    const float* __restrict__ kraw, const float* __restrict__ dw,
    const float* __restrict__ da, const float* __restrict__ dv,
    const float* __restrict__ vraw, const float* __restrict__ vfirst,
    const float* __restrict__ w0, const float* __restrict__ a0,
    const float* __restrict__ v0, const float* __restrict__ k_k,
    const float* __restrict__ k_a,
    float* __restrict__ decay, float* __restrict__ kfin, float* __restrict__ vfin,
    float* __restrict__ Ak, float* __restrict__ Bk) {
  int row = blockIdx.x; int tid = threadIdx.x; int c = tid*4;
  size_t off = (size_t)row*Cc + c;
  size_t offw = (size_t)row*BIGN + c;
  size_t offd = (size_t)row*BIGW + c;
  float4 kr = *(const float4*)(kraw+offw);
  float4 vr = *(const float4*)(vraw+offw);
  float4 w4 = *(const float4*)(dw+offd);
  float4 A4 = *(const float4*)(da+offd);
  float4 V4 = *(const float4*)(dv+offd);
  float4 vf = *(const float4*)(vfirst+off);
  float4 w04 = *(const float4*)(w0+c);
  float4 a04 = *(const float4*)(a0+c);
  float4 v04 = *(const float4*)(v0+c);
  float4 kk4 = *(const float4*)(k_k+c);
  float4 ka4 = *(const float4*)(k_a+c);
  float krl[4]={kr.x,kr.y,kr.z,kr.w};
  float dwl[4]={w4.x,w4.y,w4.z,w4.w};
  float dal[4]={A4.x,A4.y,A4.z,A4.w};
  float dvl[4]={V4.x,V4.y,V4.z,V4.w};
  float vrl[4]={vr.x,vr.y,vr.z,vr.w};
  float vfl[4]={vf.x,vf.y,vf.z,vf.w};
  float w0l[4]={w04.x,w04.y,w04.z,w04.w};
  float a0l[4]={a04.x,a04.y,a04.z,a04.w};
  float v0l[4]={v04.x,v04.y,v04.z,v04.w};
  float kkl[4]={kk4.x,kk4.y,kk4.z,kk4.w};
  float kal[4]={ka4.x,ka4.y,ka4.z,ka4.w};
  float av[4], dec[4], vv[4], kp[4], kf[4];
  float ss = 0.f;
  #pragma unroll
  for (int q=0;q<4;++q){
    av[q] = sgm(a0l[q] + dal[q]);
    dec[q] = 0.60653065971263342f * sgm(w0l[q] + dwl[q]);   // exp(-softplus(-u)-0.5)
    float sv = sgm(v0l[q] + dvl[q]);
    vv[q] = vrl[q] + (vfl[q]-vrl[q])*sv;
    kp[q] = krl[q]*kkl[q];
    ss += kp[q]*kp[q];
    kf[q] = krl[q]*(1.0f + (av[q]-1.0f)*kal[q]);
  }
  ss = redgrp<8>(ss);
  float inv = 1.0f / fmaxf(sqrtf(ss), 1e-12f);
  float4 o;
  o.x=dec[0];o.y=dec[1];o.z=dec[2];o.w=dec[3];  *(float4*)(decay+off)=o;
  o.x=kf[0]; o.y=kf[1]; o.z=kf[2]; o.w=kf[3];   *(float4*)(kfin+off)=o;
  o.x=vv[0]; o.y=vv[1]; o.z=vv[2]; o.w=vv[3];   *(float4*)(vfin+off)=o;
  o.x=-kp[0]*inv; o.y=-kp[1]*inv; o.z=-kp[2]*inv; o.w=-kp[3]*inv; *(float4*)(Ak+off)=o;
  o.x=kp[0]*inv*av[0]; o.y=kp[1]*inv*av[1]; o.z=kp[2]*inv*av[2]; o.w=kp[3]*inv*av[3];
  *(float4*)(Bk+off)=o;
}

// ------ WKV-7 scan: 512 blocks (32 bh x 16 splits, XCD-grouped), 64 thr ------
// Pair-unrolled chunks (compile-time LDS buffer) + fully-unrolled 16-step loop
// with even/odd register sets: no per-step register copies, partial lgkm waits.
__global__ __launch_bounds__(64) void wkv_kernel(
    const float* __restrict__ decay, const float* __restrict__ Ak,
    const float* __restrict__ Bk, const float* __restrict__ kfin,
    const float* __restrict__ r_, const float* __restrict__ vfin,
    const float* __restrict__ S0, float* __restrict__ y) {
  __shared__ float lds[2][6][CH][64];
  int bid = blockIdx.x;
  int c8 = bid & 7, idx = bid >> 3;   // idx 0..63
  int bh = c8*4 + (idx & 3);
  int sp = idx >> 2;                  // 0..15
  int bb = bh >> 4, h = bh & 15;
  int lane = threadIdx.x;             // 0..63
  int bi = lane >> 4, bj = lane & 15;
  int row = sp*4 + bi;                // 0..63
  int j0 = bj*4;
  float S[4];
  {
    const float* s0p = S0 + (size_t)bh*4096 + row*64 + j0;
    S[0]=s0p[0]; S[1]=s0p[1]; S[2]=s0p[2]; S[3]=s0p[3];
  }
  size_t rowbase = (size_t)bb*Tt;
  int lhi = lane >> 4, llo4 = (lane & 15)*4;

  #define WST1(buf, chn, arr, base, ldv) { \
    const float* gp_ = (base) + (size_t)((rowbase + (size_t)(chn)*CH + lhi))*(ldv) + h*64 + llo4; \
    _Pragma("unroll") \
    for (int p_=0; p_<4; ++p_) \
      gload16(gp_ + (size_t)p_*4*(ldv), &lds[buf][arr][p_*4][0]); }
  #define WSTAGE(buf, chn) { \
    WST1(buf, chn, 0, decay, Cc); WST1(buf, chn, 1, Ak, Cc); WST1(buf, chn, 2, Bk, Cc); \
    WST1(buf, chn, 3, kfin, Cc); WST1(buf, chn, 4, r_, BIGN); WST1(buf, chn, 5, vfin, Cc); }

  struct StepV { float4 d, a, b, k, r; float v; };
  #define RD(buf, s, dst) { \
    const float* bp_ = &lds[buf][0][s][0]; \
    dst.d = *(const float4*)(bp_ + 0*CH*64 + j0); \
    dst.a = *(const float4*)(bp_ + 1*CH*64 + j0); \
    dst.b = *(const float4*)(bp_ + 2*CH*64 + j0); \
    dst.k = *(const float4*)(bp_ + 3*CH*64 + j0); \
    dst.r = *(const float4*)(bp_ + 4*CH*64 + j0); \
    dst.v = bp_[5*CH*64 + row]; }
  #define STEP(e, tt) { \
    S[0]*=e.d.x; S[1]*=e.d.y; S[2]*=e.d.z; S[3]*=e.d.w; \
    float sa_ = fmaf(S[0], e.a.x, S[1]*e.a.y) + fmaf(S[2], e.a.z, S[3]*e.a.w); \
    sa_ = red16(sa_); \
    S[0]=fmaf(e.v,e.k.x,S[0]); S[1]=fmaf(e.v,e.k.y,S[1]); \
    S[2]=fmaf(e.v,e.k.z,S[2]); S[3]=fmaf(e.v,e.k.w,S[3]); \
    S[0]=fmaf(sa_,e.b.x,S[0]); S[1]=fmaf(sa_,e.b.y,S[1]); \
    S[2]=fmaf(sa_,e.b.z,S[2]); S[3]=fmaf(sa_,e.b.w,S[3]); \
    float yp_ = fmaf(S[0], e.r.x, S[1]*e.r.y) + fmaf(S[2], e.r.z, S[3]*e.r.w); \
    yp_ = red16(yp_); \
    if (bj == 0) y[(rowbase + (tt))*Cc + h*64 + row] = yp_; }
  #define PHASE(buf, chn) { \
    if ((chn)+1 < NC) WSTAGE((buf)^1, (chn)+1); \
    StepV e0; RD(buf, 0, e0); \
    _Pragma("unroll") \
    for (int s = 0; s < CH; ++s) { \
      StepV o_; \
      if (s+1 < CH) { RD(buf, s+1, o_); } \
      STEP(e0, (size_t)(chn)*CH + s); \
      if (s+1 < CH) e0 = o_; \
    } \
    asm volatile("s_waitcnt vmcnt(0)" ::: "memory"); \
    __syncthreads(); }

  const int NC = Tt/CH;
  WSTAGE(0, 0);
  asm volatile("s_waitcnt vmcnt(0)" ::: "memory");
  __syncthreads();
  for (int chp = 0; chp < NC; chp += 2) {
    PHASE(0, chp);
    PHASE(1, chp+1);
  }
  #undef PHASE
  #undef STEP
  #undef RD
  #undef WSTAGE
  #undef WST1
}

// ---------------- GroupNorm(head) + r.k.r_k bonus + *g -> bf16 ---------------
__global__ __launch_bounds__(256) void gn_kernel(
    const float* __restrict__ y, const float* __restrict__ r_,
    const float* __restrict__ kfin, const float* __restrict__ vfin,
    const float* __restrict__ g_, const float* __restrict__ lnxw,
    const float* __restrict__ lnxb, const float* __restrict__ r_k,
    u16* __restrict__ Ao) {
  int row = blockIdx.x; int tid = threadIdx.x; int c = tid*4;
  size_t off = (size_t)row*Cc + c;
  float4 y4 = *(const float4*)(y+off);
  float s = y4.x+y4.y+y4.z+y4.w;
  float q = y4.x*y4.x+y4.y*y4.y+y4.z*y4.z+y4.w*y4.w;
  s = redgrp<8>(s); q = redgrp<8>(q);
  float mu = s*(1.0f/64.0f);
  float var = q*(1.0f/64.0f) - mu*mu;
  float rn = rsqrtf(var + 64e-5f);
  float4 rr = *(const float4*)(r_ + (size_t)row*BIGN + c);
  float4 kk = *(const float4*)(kfin+off);
  float4 vv = *(const float4*)(vfin+off);
  float4 gg = *(const float4*)(g_ + (size_t)row*BIGW + c);
  int h = tid >> 4; int hs = (tid & 15)*4;
  float4 rk = *(const float4*)(r_k + h*64 + hs);
  float dp = rr.x*kk.x*rk.x + rr.y*kk.y*rk.y + rr.z*kk.z*rk.z + rr.w*kk.w*rk.w;
  dp = redgrp<8>(dp);
  float4 w4 = *(const float4*)(lnxw+c);
  float4 b4 = *(const float4*)(lnxb+c);
  float o0 = (((y4.x-mu)*rn)*w4.x + b4.x + dp*vv.x) * gg.x;
  float o1 = (((y4.y-mu)*rn)*w4.y + b4.y + dp*vv.y) * gg.y;
  float o2 = (((y4.z-mu)*rn)*w4.z + b4.z + dp*vv.z) * gg.z;
  float o3 = (((y4.w-mu)*rn)*w4.w + b4.w + dp*vv.w) * gg.w;
  uint2 p = {pack_bf16(o0,o1), pack_bf16(o2,o3)};
  *(uint2*)(Ao + off) = p;
}

__global__ __launch_bounds__(256) void copy_kernel(const float* __restrict__ src,
                                                   float* __restrict__ dst) {
  size_t i = ((size_t)blockIdx.x*256 + threadIdx.x)*4;
  *(float4*)(dst+i) = *(const float4*)(src+i);
}

extern "C" void kernel_launch(void* const* d_in, const int* in_sizes, int n_in,
                              void* d_out, int out_size, void* d_ws, size_t ws_size,
                              hipStream_t stream) {
  const float* x      = (const float*)d_in[0];
  const float* vfirst = (const float*)d_in[1];
  const float* S0     = (const float*)d_in[2];
  const float* ln1w   = (const float*)d_in[3];
  const float* ln1b   = (const float*)d_in[4];
  const float* ln2w   = (const float*)d_in[5];
  const float* ln2b   = (const float*)d_in[6];
  const float* x_r    = (const float*)d_in[7];
  const float* x_w    = (const float*)d_in[8];
  const float* x_k    = (const float*)d_in[9];
  const float* x_v    = (const float*)d_in[10];
  const float* x_a    = (const float*)d_in[11];
  const float* x_g    = (const float*)d_in[12];
  const float* w0     = (const float*)d_in[13];
  const float* w1     = (const float*)d_in[14];
  const float* w2     = (const float*)d_in[15];
  const float* a0     = (const float*)d_in[16];
  const float* a1     = (const float*)d_in[17];
  const float* a2     = (const float*)d_in[18];
  const float* v0     = (const float*)d_in[19];
  const float* v1     = (const float*)d_in[20];
  const float* v2     = (const float*)d_in[21];
  const float* g1     = (const float*)d_in[22];
  const float* g2     = (const float*)d_in[23];
  const float* k_k    = (const float*)d_in[24];
  const float* k_a    = (const float*)d_in[25];
  const float* r_k    = (const float*)d_in[26];
  const float* W_r    = (const float*)d_in[27];
  const float* W_k    = (const float*)d_in[28];
  const float* W_v    = (const float*)d_in[29];
  const float* W_o    = (const float*)d_in[30];
  const float* lnxw   = (const float*)d_in[31];
  const float* lnxb   = (const float*)d_in[32];
  const float* mixk   = (const float*)d_in[33];
  const float* Wkey   = (const float*)d_in[34];
  const float* Wval   = (const float*)d_in[35];
  float* out = (float*)d_out;
  float* ws  = (float*)d_ws;
  const size_t U = (size_t)BT * Cc;
  float* u[14];
  for (int i=0;i<14;++i) u[i] = ws + i*U;

  u16* bigA   = (u16*)u[0];
  u16* BigB   = (u16*)u[1];
  float* bigOut = u[2];
  float* dwdavg = u[6];
  u16* W2blk  = (u16*)u[10];
  u16* loraAct= (u16*)u[11];
  float* Bk   = u[0];
  float* y_   = u[1];
  u16* gnb    = (u16*)u[10];
  u16* Wob    = (u16*)u[13];
  float* xo   = u[0];
  u16* Wkeyb  = (u16*)u[6];
  u16* cmb    = (u16*)u[7];
  u16* Wvalb  = (u16*)u[8];
  u16* midb   = (u16*)u[2];

  dim3 b256(256);
  packW_kernel<<<dim3(Cc,3), b256, 0, stream>>>(W_r, W_k, W_v, x_r, x_k, x_v, BigB);
  packL_kernel<<<320, b256, 0, stream>>>(w1, a1, v1, g1, x_w, x_a, x_v, x_g, BigB);
  packW2_kernel<<<BIGW, dim3(320), 0, stream>>>(w2, a2, v2, g2, W2blk);
  lnmix1_kernel<<<BT, b256, 0, stream>>>(x, ln1w, ln1b, bigA);
  gemm_bf16<0><<<dim3(BIGN/128, BT/128), b256, 0, stream>>>(bigA, BigB, bigOut, nullptr, BT, BIGN, BIGK);
  actcvt_kernel<<<BT, dim3(320), 0, stream>>>(bigOut, loraAct);
  gemm_bf16<0><<<dim3(BIGW/128, BT/128), b256, 0, stream>>>(loraAct, W2blk, dwdavg, nullptr, BT, BIGW, LORAK);
  prep_kernel<<<BT, b256, 0, stream>>>(bigOut+1024, dwdavg, dwdavg+1024, dwdavg+2048,
      bigOut+2048, vfirst, w0, a0, v0, k_k, k_a, u[10], u[11], u[12], u[13], Bk);
  wkv_kernel<<<512, dim3(64), 0, stream>>>(u[10], u[13], Bk, u[11], bigOut, u[12], S0, y_);
  cvt_kernel<<<Cc*Cc/2048, b256, 0, stream>>>(W_o, Wob);
  gn_kernel<<<BT, b256, 0, stream>>>(y_, bigOut, u[11], u[12], dwdavg+3072, lnxw, lnxb, r_k, gnb);
  gemm_bf16<1><<<dim3(Cc/128, BT/128), b256, 0, stream>>>(gnb, Wob, xo, x, BT, Cc, Cc);
  lnmix2_kernel<<<BT, b256, 0, stream>>>(xo, ln2w, ln2b, mixk, cmb);
  cvt_kernel<<<FFNd*Cc/2048, b256, 0, stream>>>(Wkey, Wkeyb);
  gemm_bf16<2><<<dim3(FFNd/128, BT/128), b256, 0, stream>>>(cmb, Wkeyb, midb, nullptr, BT, FFNd, Cc);
  cvt_kernel<<<Cc*FFNd/2048, b256, 0, stream>>>(Wval, Wvalb);
  gemm_bf16<1><<<dim3(Cc/128, BT/128), b256, 0, stream>>>(midb, Wvalb, out, xo, BT, Cc, FFNd);
  copy_kernel<<<BT*Cc/1024, b256, 0, stream>>>(vfirst, out + (size_t)BT*Cc);
}

// Round 7
// 481.891 us; speedup vs baseline: 7.2581x; 1.4803x over previous
//
#include <hip/hip_runtime.h>
#include <math.h>

#define Bb 2
#define Tt 2048
#define Cc 1024
#define Hh 16
#define BT 4096
#define FFNd 4096
#define CH 16
#define CL 128
#define WU 64
#define BIGN 3456
#define BIGK 2048
#define LORAK 320
#define BIGW 4096
// big-B column layout: r@0 k@1024 v@2048 w@3072 a@3136 vl@3200 g@3232 (end 3392, pad->3456)
// dwdavg column layout: dw@0 da@1024 dv@2048 g@3072  (ld 4096)

typedef __attribute__((ext_vector_type(8))) short bf16x8;
typedef __attribute__((ext_vector_type(4))) float f32x4;
typedef unsigned short u16;

__device__ __forceinline__ float sgm(float x){ return 1.0f/(1.0f+expf(-x)); }

template<int MAXM>
__device__ __forceinline__ float redgrp(float v){
  #pragma unroll
  for (int m=1; m<=MAXM; m<<=1) v += __shfl_xor(v, m, 64);
  return v;
}

template<int CTRL>
__device__ __forceinline__ float dppadd(float v){
  union { float f; int i; } u, r;
  u.f = v;
  r.i = __builtin_amdgcn_update_dpp(u.i, u.i, CTRL, 0xf, 0xf, true);
  return v + r.f;
}
__device__ __forceinline__ float red16(float v){
  v = dppadd<0xB1>(v);
  v = dppadd<0x4E>(v);
  v = dppadd<0x141>(v);
  v = dppadd<0x140>(v);
  return v;
}

__device__ __forceinline__ unsigned pack_bf16(float a, float b){
  unsigned ua = __builtin_bit_cast(unsigned, a);
  unsigned ub = __builtin_bit_cast(unsigned, b);
  ua = (ua + 0x7FFFu + ((ua>>16)&1u)) >> 16;
  ub = (ub + 0x7FFFu + ((ub>>16)&1u)) >> 16;
  return ua | (ub<<16);
}
__device__ __forceinline__ u16 bf16_1(float a){
  unsigned ua = __builtin_bit_cast(unsigned, a);
  return (u16)((ua + 0x7FFFu + ((ua>>16)&1u)) >> 16);
}

__device__ __forceinline__ void gload16(const void* g, void* l){
  __builtin_amdgcn_global_load_lds(
    (const __attribute__((address_space(1))) unsigned int*)g,
    (__attribute__((address_space(3))) unsigned int*)l, 16, 0, 0);
}

// ---------------- f32 -> bf16 convert (weights) -------------------------------
__global__ __launch_bounds__(256) void cvt_kernel(const float* __restrict__ in,
    u16* __restrict__ out) {
  size_t i = (size_t)blockIdx.x*256 + threadIdx.x;
  float4 a = ((const float4*)in)[2*i];
  float4 b = ((const float4*)in)[2*i+1];
  uint4 o = {pack_bf16(a.x,a.y), pack_bf16(a.z,a.w),
             pack_bf16(b.x,b.y), pack_bf16(b.z,b.w)};
  ((uint4*)out)[i] = o;
}

// ---------------- pack square weights into BigB rows: [W | diag(mix)W] -------
__global__ __launch_bounds__(256) void packW_kernel(const float* __restrict__ Wr,
    const float* __restrict__ Wk, const float* __restrict__ Wv,
    const float* __restrict__ xr, const float* __restrict__ xk,
    const float* __restrict__ xv, u16* __restrict__ out) {
  int which = blockIdx.y;
  const float* W   = which==0 ? Wr : (which==1 ? Wk : Wv);
  const float* mix = which==0 ? xr : (which==1 ? xk : xv);
  u16* o = out + (size_t)which*1024*BIGK;
  int n = blockIdx.x;             // 0..1023
  int c0 = threadIdx.x*8;         // 0..2040
  int ks = c0 & 1023;
  const float* src = W + (size_t)n*Cc + ks;
  float4 a = *(const float4*)src;
  float4 b = *(const float4*)(src+4);
  if (c0 >= 1024){
    float4 m0 = *(const float4*)(mix + ks);
    float4 m1 = *(const float4*)(mix + ks + 4);
    a.x*=m0.x; a.y*=m0.y; a.z*=m0.z; a.w*=m0.w;
    b.x*=m1.x; b.y*=m1.y; b.z*=m1.z; b.w*=m1.w;
  }
  uint4 ov = {pack_bf16(a.x,a.y), pack_bf16(a.z,a.w),
              pack_bf16(b.x,b.y), pack_bf16(b.z,b.w)};
  *(uint4*)(o + (size_t)n*BIGK + c0) = ov;
}

// ---------------- pack lora W1[C,D] (transposed) into BigB rows --------------
__global__ __launch_bounds__(256) void packL_kernel(const float* __restrict__ w1,
    const float* __restrict__ a1, const float* __restrict__ v1,
    const float* __restrict__ g1, const float* __restrict__ x_w,
    const float* __restrict__ x_a, const float* __restrict__ x_v,
    const float* __restrict__ x_g, u16* __restrict__ out) {
  int bid = blockIdx.x;           // 0..319
  const float* W1; const float* mix; int D, d, nbase;
  if (bid < 64)       { W1=w1; mix=x_w; D=64;  d=bid;     nbase=3072; }
  else if (bid < 128) { W1=a1; mix=x_a; D=64;  d=bid-64;  nbase=3136; }
  else if (bid < 160) { W1=v1; mix=x_v; D=32;  d=bid-128; nbase=3200; }
  else                { W1=g1; mix=x_g; D=160; d=bid-160; nbase=3232; }
  int k0 = threadIdx.x*8;
  float v[8];
  #pragma unroll
  for (int q=0;q<8;++q){
    int kk = k0+q;
    int ks = kk & 1023;
    float t = W1[(size_t)ks*D + d];
    if (kk >= 1024) t *= mix[ks];
    v[q] = t;
  }
  uint4 o = {pack_bf16(v[0],v[1]), pack_bf16(v[2],v[3]),
             pack_bf16(v[4],v[5]), pack_bf16(v[6],v[7])};
  *(uint4*)(out + (size_t)(nbase+d)*BIGK + k0) = o;
}

// --------- pack block-diagonal W2: out[n][k] bf16, n in [0,4096) k in [0,320)
__global__ __launch_bounds__(320) void packW2_kernel(const float* __restrict__ w2,
    const float* __restrict__ a2, const float* __restrict__ v2,
    const float* __restrict__ g2, u16* __restrict__ out) {
  int n = blockIdx.x; int k = threadIdx.x;
  int which = n >> 10, col = n & 1023;
  float v = 0.f;
  if (which==0)      { if (k < 64)              v = w2[(size_t)k*Cc + col]; }
  else if (which==1) { if (k >= 64 && k < 128)  v = a2[(size_t)(k-64)*Cc + col]; }
  else if (which==2) { if (k >= 128 && k < 160) v = v2[(size_t)(k-128)*Cc + col]; }
  else               { if (k >= 160)            v = g2[(size_t)(k-160)*Cc + col]; }
  out[(size_t)n*LORAK + k] = bf16_1(v);
}

// --------- act + cvt lora columns of bigOut -> loraAct bf16 [4096][320] ------
__global__ __launch_bounds__(320) void actcvt_kernel(const float* __restrict__ m,
    u16* __restrict__ loraAct) {
  int i = blockIdx.x; int cc = threadIdx.x;
  float v = m[(size_t)i*BIGN + 3072 + cc];
  if (cc < 64) v = tanhf(v);
  else if (cc >= 160) v = sgm(v);
  loraAct[(size_t)i*LORAK + cc] = bf16_1(v);
}

// ---------------- fused LN1 -> bigA = [xn | xx] bf16 -------------------------
__global__ __launch_bounds__(256) void lnmix1_kernel(const float* __restrict__ x,
    const float* __restrict__ w, const float* __restrict__ b,
    u16* __restrict__ bigA) {
  int rowg = blockIdx.x; int t = rowg & (Tt-1);
  int tid = threadIdx.x;
  size_t off = (size_t)rowg*Cc + tid*4;
  float4 vc = *(const float4*)(x + off);
  float4 vp = {0.f,0.f,0.f,0.f};
  if (t) vp = *(const float4*)(x + off - Cc);
  float sc = vc.x+vc.y+vc.z+vc.w;
  float qc = vc.x*vc.x+vc.y*vc.y+vc.z*vc.z+vc.w*vc.w;
  float sp = vp.x+vp.y+vp.z+vp.w;
  float qp = vp.x*vp.x+vp.y*vp.y+vp.z*vp.z+vp.w*vp.w;
  sc = redgrp<32>(sc); qc = redgrp<32>(qc);
  sp = redgrp<32>(sp); qp = redgrp<32>(qp);
  __shared__ float rbuf[4][4];
  int lane = tid & 63, wv = tid >> 6;
  if (lane==0){ rbuf[wv][0]=sc; rbuf[wv][1]=qc; rbuf[wv][2]=sp; rbuf[wv][3]=qp; }
  __syncthreads();
  sc = rbuf[0][0]+rbuf[1][0]+rbuf[2][0]+rbuf[3][0];
  qc = rbuf[0][1]+rbuf[1][1]+rbuf[2][1]+rbuf[3][1];
  sp = rbuf[0][2]+rbuf[1][2]+rbuf[2][2]+rbuf[3][2];
  qp = rbuf[0][3]+rbuf[1][3]+rbuf[2][3]+rbuf[3][3];
  float muc = sc*(1.0f/Cc), mup = sp*(1.0f/Cc);
  float rnc = rsqrtf(qc*(1.0f/Cc) - muc*muc + 1e-5f);
  float rnp = rsqrtf(qp*(1.0f/Cc) - mup*mup + 1e-5f);
  float4 w4 = *(const float4*)(w + tid*4);
  float4 b4 = *(const float4*)(b + tid*4);
  float vcl[4]={vc.x,vc.y,vc.z,vc.w};
  float vpl[4]={vp.x,vp.y,vp.z,vp.w};
  float wl[4]={w4.x,w4.y,w4.z,w4.w};
  float bl[4]={b4.x,b4.y,b4.z,b4.w};
  float xnc[4], xx[4];
  #pragma unroll
  for (int q=0;q<4;++q){
    xnc[q] = (vcl[q]-muc)*rnc*wl[q] + bl[q];
    float xnp = t ? ((vpl[q]-mup)*rnp*wl[q] + bl[q]) : 0.0f;
    xx[q] = xnp - xnc[q];
  }
  size_t ab = (size_t)rowg*BIGK + tid*4;
  uint2 p0 = {pack_bf16(xnc[0],xnc[1]), pack_bf16(xnc[2],xnc[3])};
  uint2 p1 = {pack_bf16(xx[0],xx[1]),   pack_bf16(xx[2],xx[3])};
  *(uint2*)(bigA + ab) = p0;
  *(uint2*)(bigA + ab + 1024) = p1;
}

// ---------------- fused LN2 + cmix -> bf16 -----------------------------------
__global__ __launch_bounds__(256) void lnmix2_kernel(const float* __restrict__ x,
    const float* __restrict__ w, const float* __restrict__ b,
    const float* __restrict__ mixk, u16* __restrict__ outb) {
  int rowg = blockIdx.x; int t = rowg & (Tt-1);
  int tid = threadIdx.x;
  size_t off = (size_t)rowg*Cc + tid*4;
  float4 vc = *(const float4*)(x + off);
  float4 vp = {0.f,0.f,0.f,0.f};
  if (t) vp = *(const float4*)(x + off - Cc);
  float sc = vc.x+vc.y+vc.z+vc.w;
  float qc = vc.x*vc.x+vc.y*vc.y+vc.z*vc.z+vc.w*vc.w;
  float sp = vp.x+vp.y+vp.z+vp.w;
  float qp = vp.x*vp.x+vp.y*vp.y+vp.z*vp.z+vp.w*vp.w;
  sc = redgrp<32>(sc); qc = redgrp<32>(qc);
  sp = redgrp<32>(sp); qp = redgrp<32>(qp);
  __shared__ float rbuf[4][4];
  int lane = tid & 63, wv = tid >> 6;
  if (lane==0){ rbuf[wv][0]=sc; rbuf[wv][1]=qc; rbuf[wv][2]=sp; rbuf[wv][3]=qp; }
  __syncthreads();
  sc = rbuf[0][0]+rbuf[1][0]+rbuf[2][0]+rbuf[3][0];
  qc = rbuf[0][1]+rbuf[1][1]+rbuf[2][1]+rbuf[3][1];
  sp = rbuf[0][2]+rbuf[1][2]+rbuf[2][2]+rbuf[3][2];
  qp = rbuf[0][3]+rbuf[1][3]+rbuf[2][3]+rbuf[3][3];
  float muc = sc*(1.0f/Cc), mup = sp*(1.0f/Cc);
  float rnc = rsqrtf(qc*(1.0f/Cc) - muc*muc + 1e-5f);
  float rnp = rsqrtf(qp*(1.0f/Cc) - mup*mup + 1e-5f);
  float4 w4 = *(const float4*)(w + tid*4);
  float4 b4 = *(const float4*)(b + tid*4);
  float4 m = *(const float4*)(mixk + tid*4);
  float vcl[4]={vc.x,vc.y,vc.z,vc.w};
  float vpl[4]={vp.x,vp.y,vp.z,vp.w};
  float wl[4]={w4.x,w4.y,w4.z,w4.w};
  float bl[4]={b4.x,b4.y,b4.z,b4.w};
  float ml[4]={m.x,m.y,m.z,m.w};
  float o[4];
  #pragma unroll
  for (int q=0;q<4;++q){
    float xnc = (vcl[q]-muc)*rnc*wl[q] + bl[q];
    float xnp = t ? ((vpl[q]-mup)*rnp*wl[q] + bl[q]) : 0.0f;
    o[q] = xnc + (xnp - xnc)*ml[q];
  }
  uint2 p = {pack_bf16(o[0],o[1]), pack_bf16(o[2],o[3])};
  *(uint2*)(outb + off) = p;
}

// ================= bf16 GEMM (m97 structure): out = A[M,K] @ W[N,K]^T ========
// MODE 0: f32 out   1: f32 out = res + acc   2: bf16 out = relu(acc)^2
template<int MODE>
__global__ __launch_bounds__(256) void gemm_bf16(const u16* __restrict__ A,
    const u16* __restrict__ W, void* __restrict__ outv,
    const float* __restrict__ res, int M, int N, int K) {
  __shared__ u16 As[2][128*64];
  __shared__ u16 Bs[2][128*64];
  int tid = threadIdx.x;
  int bm = blockIdx.y, bn = blockIdx.x;
  int wave = tid >> 6, lane = tid & 63;
  int wm = wave >> 1, wn = wave & 1;
  int srow = wave*32 + (lane>>3);
  int scol = (lane&7)*8;
  const u16* Ag = A + (size_t)(bm*128 + srow)*K + scol;
  const u16* Wg = W + (size_t)(bn*128 + srow)*K + scol;
  int nt = K >> 6;
  f32x4 acc[4][4];
  f32x4 zero = {0.f,0.f,0.f,0.f};
  #pragma unroll
  for (int i=0;i<4;++i)
    #pragma unroll
    for (int j=0;j<4;++j) acc[i][j] = zero;

  #define STAGE(buf, t) { \
    const u16* Ag2 = Ag + (size_t)(t)*64; \
    const u16* Wg2 = Wg + (size_t)(t)*64; \
    _Pragma("unroll") \
    for (int i_=0;i_<4;++i_){ \
      gload16(Ag2 + (size_t)i_*8*K, &As[buf][(wave*32+i_*8)*64]); \
      gload16(Wg2 + (size_t)i_*8*K, &Bs[buf][(wave*32+i_*8)*64]); \
    } }

  STAGE(0, 0);
  asm volatile("s_waitcnt vmcnt(0)" ::: "memory");
  __syncthreads();
  int lrow = lane & 15, lk8 = lane >> 4;
  for (int t = 0; t < nt; ++t) {
    int cur = t & 1;
    if (t+1 < nt) STAGE(cur^1, t+1);
    #pragma unroll
    for (int kk2 = 0; kk2 < 2; ++kk2) {
      bf16x8 af[4], bfr[4];
      #pragma unroll
      for (int i=0;i<4;++i)
        af[i] = *(const bf16x8*)&As[cur][(wm*64 + i*16 + lrow)*64 + kk2*32 + lk8*8];
      #pragma unroll
      for (int j=0;j<4;++j)
        bfr[j] = *(const bf16x8*)&Bs[cur][(wn*64 + j*16 + lrow)*64 + kk2*32 + lk8*8];
      #pragma unroll
      for (int i=0;i<4;++i)
        #pragma unroll
        for (int j=0;j<4;++j)
          acc[i][j] = __builtin_amdgcn_mfma_f32_16x16x32_bf16(af[i], bfr[j], acc[i][j], 0, 0, 0);
    }
    if (t+1 < nt) { asm volatile("s_waitcnt vmcnt(0)" ::: "memory"); }
    __syncthreads();
  }
  #undef STAGE
  float* outf = (float*)outv;
  u16* outb = (u16*)outv;
  int crow4 = (lane>>4)*4, ccol = lane & 15;
  #pragma unroll
  for (int i=0;i<4;++i){
    #pragma unroll
    for (int j=0;j<4;++j){
      int gr = bm*128 + wm*64 + i*16 + crow4;
      int gc = bn*128 + wn*64 + j*16 + ccol;
      #pragma unroll
      for (int q=0;q<4;++q){
        float v = acc[i][j][q];
        size_t o = (size_t)(gr+q)*N + gc;
        if (MODE==1) { v += res[o]; outf[o] = v; }
        else if (MODE==2) { v = fmaxf(v, 0.f); outb[o] = bf16_1(v*v); }
        else outf[o] = v;
      }
    }
  }
}

// ---------------- prep: dw/da/dv from dwdavg (ld 4096), k/v from bigOut ------
__global__ __launch_bounds__(256) void prep_kernel(
    const float* __restrict__ kraw, const float* __restrict__ dw,
    const float* __restrict__ da, const float* __restrict__ dv,
    const float* __restrict__ vraw, const float* __restrict__ vfirst,
    const float* __restrict__ w0, const float* __restrict__ a0,
    const float* __restrict__ v0, const float* __restrict__ k_k,
    const float* __restrict__ k_a,
    float* __restrict__ decay, float* __restrict__ kfin, float* __restrict__ vfin,
    float* __restrict__ Ak, float* __restrict__ Bk) {
  int row = blockIdx.x; int tid = threadIdx.x; int c = tid*4;
  size_t off = (size_t)row*Cc + c;
  size_t offw = (size_t)row*BIGN + c;
  size_t offd = (size_t)row*BIGW + c;
  float4 kr = *(const float4*)(kraw+offw);
  float4 vr = *(const float4*)(vraw+offw);
  float4 w4 = *(const float4*)(dw+offd);
  float4 A4 = *(const float4*)(da+offd);
  float4 V4 = *(const float4*)(dv+offd);
  float4 vf = *(const float4*)(vfirst+off);
  float4 w04 = *(const float4*)(w0+c);
  float4 a04 = *(const float4*)(a0+c);
  float4 v04 = *(const float4*)(v0+c);
  float4 kk4 = *(const float4*)(k_k+c);
  float4 ka4 = *(const float4*)(k_a+c);
  float krl[4]={kr.x,kr.y,kr.z,kr.w};
  float dwl[4]={w4.x,w4.y,w4.z,w4.w};
  float dal[4]={A4.x,A4.y,A4.z,A4.w};
  float dvl[4]={V4.x,V4.y,V4.z,V4.w};
  float vrl[4]={vr.x,vr.y,vr.z,vr.w};
  float vfl[4]={vf.x,vf.y,vf.z,vf.w};
  float w0l[4]={w04.x,w04.y,w04.z,w04.w};
  float a0l[4]={a04.x,a04.y,a04.z,a04.w};
  float v0l[4]={v04.x,v04.y,v04.z,v04.w};
  float kkl[4]={kk4.x,kk4.y,kk4.z,kk4.w};
  float kal[4]={ka4.x,ka4.y,ka4.z,ka4.w};
  float av[4], dec[4], vv[4], kp[4], kf[4];
  float ss = 0.f;
  #pragma unroll
  for (int q=0;q<4;++q){
    av[q] = sgm(a0l[q] + dal[q]);
    dec[q] = 0.60653065971263342f * sgm(w0l[q] + dwl[q]);   // exp(-softplus(-u)-0.5)
    float sv = sgm(v0l[q] + dvl[q]);
    vv[q] = vrl[q] + (vfl[q]-vrl[q])*sv;
    kp[q] = krl[q]*kkl[q];
    ss += kp[q]*kp[q];
    kf[q] = krl[q]*(1.0f + (av[q]-1.0f)*kal[q]);
  }
  ss = redgrp<8>(ss);
  float inv = 1.0f / fmaxf(sqrtf(ss), 1e-12f);
  float4 o;
  o.x=dec[0];o.y=dec[1];o.z=dec[2];o.w=dec[3];  *(float4*)(decay+off)=o;
  o.x=kf[0]; o.y=kf[1]; o.z=kf[2]; o.w=kf[3];   *(float4*)(kfin+off)=o;
  o.x=vv[0]; o.y=vv[1]; o.z=vv[2]; o.w=vv[3];   *(float4*)(vfin+off)=o;
  o.x=-kp[0]*inv; o.y=-kp[1]*inv; o.z=-kp[2]*inv; o.w=-kp[3]*inv; *(float4*)(Ak+off)=o;
  o.x=kp[0]*inv*av[0]; o.y=kp[1]*inv*av[1]; o.z=kp[2]*inv*av[2]; o.w=kp[3]*inv*av[3];
  *(float4*)(Bk+off)=o;
}

// ===== WKV-7 warmup-chunked scan =============================================
// decay <= exp(-0.5) by construction and the delta-rule factor is
// non-expansive, so state influence from >=64 steps back is < 1.4e-14 (below
// f32 noise). Chunk c of 128 steps starts from S=0 at step 128c-64 (64-step
// warmup, no y emit); chunk 0 starts exactly from S0. 512 independent blocks.
// Block: 512 threads = 8 waves; thread owns rows rg and rg+32 (4 cols each).
__global__ __launch_bounds__(512) void wkv_kernel(
    const float* __restrict__ decay, const float* __restrict__ Ak,
    const float* __restrict__ Bk, const float* __restrict__ kfin,
    const float* __restrict__ r_, const float* __restrict__ vfin,
    const float* __restrict__ S0, float* __restrict__ y) {
  __shared__ float lds[2][6][CH][64];
  int bid = blockIdx.x;
  int bh = bid & 31, c = bid >> 5;
  int bb = bh >> 4, h = bh & 15;
  int tid = threadIdx.x;
  int wave = tid >> 6, lane = tid & 63;
  int rg = tid >> 4;                  // 0..31
  int bj = tid & 15, j0 = bj*4;
  int r0 = rg, r1 = rg + 32;
  float Sa_[4] = {0.f,0.f,0.f,0.f};
  float Sb_[4] = {0.f,0.f,0.f,0.f};
  if (c == 0) {
    float4 t0 = *(const float4*)(S0 + (size_t)bh*4096 + r0*64 + j0);
    float4 t1 = *(const float4*)(S0 + (size_t)bh*4096 + r1*64 + j0);
    Sa_[0]=t0.x; Sa_[1]=t0.y; Sa_[2]=t0.z; Sa_[3]=t0.w;
    Sb_[0]=t1.x; Sb_[1]=t1.y; Sb_[2]=t1.z; Sb_[3]=t1.w;
  }
  size_t seqb = (size_t)bb*Tt;
  int t0g = (c==0) ? 0 : (c*CL - WU);
  int NPH = (c==0) ? (CL/CH) : ((CL+WU)/CH);
  int phE = (c==0) ? 0 : (WU/CH);
  int lhi = lane >> 4, llo4 = (lane & 15)*4;

  // one array's 16 step-rows: 4 x gload16 by one wave
  #define WST1(buf, stepb, arr, base, ldv) { \
    const float* gp_ = (base) + (size_t)(seqb + (size_t)(stepb) + lhi)*(ldv) + h*64 + llo4; \
    _Pragma("unroll") \
    for (int p_=0; p_<4; ++p_) \
      gload16(gp_ + (size_t)p_*4*(ldv), &lds[buf][arr][p_*4][0]); }
  #define WSTAGE(buf, stepb) { \
    if (wave==0)      { WST1(buf, stepb, 0, decay, Cc) } \
    else if (wave==1) { WST1(buf, stepb, 1, Ak, Cc) } \
    else if (wave==2) { WST1(buf, stepb, 2, Bk, Cc) } \
    else if (wave==3) { WST1(buf, stepb, 3, kfin, Cc) } \
    else if (wave==4) { WST1(buf, stepb, 4, r_, BIGN) } \
    else if (wave==5) { WST1(buf, stepb, 5, vfin, Cc) } }

  WSTAGE(0, t0g);
  asm volatile("s_waitcnt vmcnt(0)" ::: "memory");
  __syncthreads();
  for (int ph = 0; ph < NPH; ++ph) {
    int cur = ph & 1;
    if (ph+1 < NPH) WSTAGE(cur^1, t0g + (ph+1)*CH);
    bool emit = (ph >= phE);
    const float* L0 = &lds[cur][0][0][0];
    #pragma unroll
    for (int s = 0; s < CH; ++s) {
      const float* bp = L0 + s*64;
      float4 d4 = *(const float4*)(bp + 0*CH*64 + j0);
      float4 a4 = *(const float4*)(bp + 1*CH*64 + j0);
      float4 b4 = *(const float4*)(bp + 2*CH*64 + j0);
      float4 k4 = *(const float4*)(bp + 3*CH*64 + j0);
      float4 r4 = *(const float4*)(bp + 4*CH*64 + j0);
      float v0 = bp[5*CH*64 + r0];
      float v1 = bp[5*CH*64 + r1];
      Sa_[0]*=d4.x; Sa_[1]*=d4.y; Sa_[2]*=d4.z; Sa_[3]*=d4.w;
      Sb_[0]*=d4.x; Sb_[1]*=d4.y; Sb_[2]*=d4.z; Sb_[3]*=d4.w;
      float sa0 = fmaf(Sa_[0],a4.x, Sa_[1]*a4.y) + fmaf(Sa_[2],a4.z, Sa_[3]*a4.w);
      float sa1 = fmaf(Sb_[0],a4.x, Sb_[1]*a4.y) + fmaf(Sb_[2],a4.z, Sb_[3]*a4.w);
      sa0 = red16(sa0);
      sa1 = red16(sa1);
      Sa_[0]=fmaf(v0,k4.x,Sa_[0]); Sa_[1]=fmaf(v0,k4.y,Sa_[1]);
      Sa_[2]=fmaf(v0,k4.z,Sa_[2]); Sa_[3]=fmaf(v0,k4.w,Sa_[3]);
      Sa_[0]=fmaf(sa0,b4.x,Sa_[0]); Sa_[1]=fmaf(sa0,b4.y,Sa_[1]);
      Sa_[2]=fmaf(sa0,b4.z,Sa_[2]); Sa_[3]=fmaf(sa0,b4.w,Sa_[3]);
      Sb_[0]=fmaf(v1,k4.x,Sb_[0]); Sb_[1]=fmaf(v1,k4.y,Sb_[1]);
      Sb_[2]=fmaf(v1,k4.z,Sb_[2]); Sb_[3]=fmaf(v1,k4.w,Sb_[3]);
      Sb_[0]=fmaf(sa1,b4.x,Sb_[0]); Sb_[1]=fmaf(sa1,b4.y,Sb_[1]);
      Sb_[2]=fmaf(sa1,b4.z,Sb_[2]); Sb_[3]=fmaf(sa1,b4.w,Sb_[3]);
      if (emit) {
        float y0 = fmaf(Sa_[0],r4.x, Sa_[1]*r4.y) + fmaf(Sa_[2],r4.z, Sa_[3]*r4.w);
        float y1 = fmaf(Sb_[0],r4.x, Sb_[1]*r4.y) + fmaf(Sb_[2],r4.z, Sb_[3]*r4.w);
        y0 = red16(y0);
        y1 = red16(y1);
        if (bj == 0) {
          size_t yo = (seqb + (size_t)t0g + ph*CH + s)*Cc + h*64;
          y[yo + r0] = y0;
          y[yo + r1] = y1;
        }
      }
    }
    asm volatile("s_waitcnt vmcnt(0)" ::: "memory");
    __syncthreads();
  }
  #undef WSTAGE
  #undef WST1
}

// ---------------- GroupNorm(head) + r.k.r_k bonus + *g -> bf16 ---------------
__global__ __launch_bounds__(256) void gn_kernel(
    const float* __restrict__ y, const float* __restrict__ r_,
    const float* __restrict__ kfin, const float* __restrict__ vfin,
    const float* __restrict__ g_, const float* __restrict__ lnxw,
    const float* __restrict__ lnxb, const float* __restrict__ r_k,
    u16* __restrict__ Ao) {
  int row = blockIdx.x; int tid = threadIdx.x; int c = tid*4;
  size_t off = (size_t)row*Cc + c;
  float4 y4 = *(const float4*)(y+off);
  float s = y4.x+y4.y+y4.z+y4.w;
  float q = y4.x*y4.x+y4.y*y4.y+y4.z*y4.z+y4.w*y4.w;
  s = redgrp<8>(s); q = redgrp<8>(q);
  float mu = s*(1.0f/64.0f);
  float var = q*(1.0f/64.0f) - mu*mu;
  float rn = rsqrtf(var + 64e-5f);
  float4 rr = *(const float4*)(r_ + (size_t)row*BIGN + c);
  float4 kk = *(const float4*)(kfin+off);
  float4 vv = *(const float4*)(vfin+off);
  float4 gg = *(const float4*)(g_ + (size_t)row*BIGW + c);
  int h = tid >> 4; int hs = (tid & 15)*4;
  float4 rk = *(const float4*)(r_k + h*64 + hs);
  float dp = rr.x*kk.x*rk.x + rr.y*kk.y*rk.y + rr.z*kk.z*rk.z + rr.w*kk.w*rk.w;
  dp = redgrp<8>(dp);
  float4 w4 = *(const float4*)(lnxw+c);
  float4 b4 = *(const float4*)(lnxb+c);
  float o0 = (((y4.x-mu)*rn)*w4.x + b4.x + dp*vv.x) * gg.x;
  float o1 = (((y4.y-mu)*rn)*w4.y + b4.y + dp*vv.y) * gg.y;
  float o2 = (((y4.z-mu)*rn)*w4.z + b4.z + dp*vv.z) * gg.z;
  float o3 = (((y4.w-mu)*rn)*w4.w + b4.w + dp*vv.w) * gg.w;
  uint2 p = {pack_bf16(o0,o1), pack_bf16(o2,o3)};
  *(uint2*)(Ao + off) = p;
}

__global__ __launch_bounds__(256) void copy_kernel(const float* __restrict__ src,
                                                   float* __restrict__ dst) {
  size_t i = ((size_t)blockIdx.x*256 + threadIdx.x)*4;
  *(float4*)(dst+i) = *(const float4*)(src+i);
}

extern "C" void kernel_launch(void* const* d_in, const int* in_sizes, int n_in,
                              void* d_out, int out_size, void* d_ws, size_t ws_size,
                              hipStream_t stream) {
  const float* x      = (const float*)d_in[0];
  const float* vfirst = (const float*)d_in[1];
  const float* S0     = (const float*)d_in[2];
  const float* ln1w   = (const float*)d_in[3];
  const float* ln1b   = (const float*)d_in[4];
  const float* ln2w   = (const float*)d_in[5];
  const float* ln2b   = (const float*)d_in[6];
  const float* x_r    = (const float*)d_in[7];
  const float* x_w    = (const float*)d_in[8];
  const float* x_k    = (const float*)d_in[9];
  const float* x_v    = (const float*)d_in[10];
  const float* x_a    = (const float*)d_in[11];
  const float* x_g    = (const float*)d_in[12];
  const float* w0     = (const float*)d_in[13];
  const float* w1     = (const float*)d_in[14];
  const float* w2     = (const float*)d_in[15];
  const float* a0     = (const float*)d_in[16];
  const float* a1     = (const float*)d_in[17];
  const float* a2     = (const float*)d_in[18];
  const float* v0     = (const float*)d_in[19];
  const float* v1     = (const float*)d_in[20];
  const float* v2     = (const float*)d_in[21];
  const float* g1     = (const float*)d_in[22];
  const float* g2     = (const float*)d_in[23];
  const float* k_k    = (const float*)d_in[24];
  const float* k_a    = (const float*)d_in[25];
  const float* r_k    = (const float*)d_in[26];
  const float* W_r    = (const float*)d_in[27];
  const float* W_k    = (const float*)d_in[28];
  const float* W_v    = (const float*)d_in[29];
  const float* W_o    = (const float*)d_in[30];
  const float* lnxw   = (const float*)d_in[31];
  const float* lnxb   = (const float*)d_in[32];
  const float* mixk   = (const float*)d_in[33];
  const float* Wkey   = (const float*)d_in[34];
  const float* Wval   = (const float*)d_in[35];
  float* out = (float*)d_out;
  float* ws  = (float*)d_ws;
  const size_t U = (size_t)BT * Cc;
  float* u[14];
  for (int i=0;i<14;++i) u[i] = ws + i*U;

  u16* bigA   = (u16*)u[0];
  u16* BigB   = (u16*)u[1];
  float* bigOut = u[2];
  float* dwdavg = u[6];
  u16* W2blk  = (u16*)u[10];
  u16* loraAct= (u16*)u[11];
  float* Bk   = u[0];
  float* y_   = u[1];
  u16* gnb    = (u16*)u[10];
  u16* Wob    = (u16*)u[13];
  float* xo   = u[0];
  u16* Wkeyb  = (u16*)u[6];
  u16* cmb    = (u16*)u[7];
  u16* Wvalb  = (u16*)u[8];
  u16* midb   = (u16*)u[2];

  dim3 b256(256);
  packW_kernel<<<dim3(Cc,3), b256, 0, stream>>>(W_r, W_k, W_v, x_r, x_k, x_v, BigB);
  packL_kernel<<<320, b256, 0, stream>>>(w1, a1, v1, g1, x_w, x_a, x_v, x_g, BigB);
  packW2_kernel<<<BIGW, dim3(320), 0, stream>>>(w2, a2, v2, g2, W2blk);
  lnmix1_kernel<<<BT, b256, 0, stream>>>(x, ln1w, ln1b, bigA);
  gemm_bf16<0><<<dim3(BIGN/128, BT/128), b256, 0, stream>>>(bigA, BigB, bigOut, nullptr, BT, BIGN, BIGK);
  actcvt_kernel<<<BT, dim3(320), 0, stream>>>(bigOut, loraAct);
  gemm_bf16<0><<<dim3(BIGW/128, BT/128), b256, 0, stream>>>(loraAct, W2blk, dwdavg, nullptr, BT, BIGW, LORAK);
  prep_kernel<<<BT, b256, 0, stream>>>(bigOut+1024, dwdavg, dwdavg+1024, dwdavg+2048,
      bigOut+2048, vfirst, w0, a0, v0, k_k, k_a, u[10], u[11], u[12], u[13], Bk);
  wkv_kernel<<<32*(Tt/CL), dim3(512), 0, stream>>>(u[10], u[13], Bk, u[11], bigOut, u[12], S0, y_);
  cvt_kernel<<<Cc*Cc/2048, b256, 0, stream>>>(W_o, Wob);
  gn_kernel<<<BT, b256, 0, stream>>>(y_, bigOut, u[11], u[12], dwdavg+3072, lnxw, lnxb, r_k, gnb);
  gemm_bf16<1><<<dim3(Cc/128, BT/128), b256, 0, stream>>>(gnb, Wob, xo, x, BT, Cc, Cc);
  lnmix2_kernel<<<BT, b256, 0, stream>>>(xo, ln2w, ln2b, mixk, cmb);
  cvt_kernel<<<FFNd*Cc/2048, b256, 0, stream>>>(Wkey, Wkeyb);
  gemm_bf16<2><<<dim3(FFNd/128, BT/128), b256, 0, stream>>>(cmb, Wkeyb, midb, nullptr, BT, FFNd, Cc);
  cvt_kernel<<<Cc*FFNd/2048, b256, 0, stream>>>(Wval, Wvalb);
  gemm_bf16<1><<<dim3(Cc/128, BT/128), b256, 0, stream>>>(midb, Wvalb, out, xo, BT, Cc, FFNd);
  copy_kernel<<<BT*Cc/1024, b256, 0, stream>>>(vfirst, out + (size_t)BT*Cc);
}